// Round 7
// baseline (1283.212 us; speedup 1.0000x reference)
//
#include <hip/hip_runtime.h>
#include <math.h>

#define NPTS 50000
#define MN 1024
#define KK 64
#define DPT 64
#define DN 256
#define BCORR 256
#define OUTC 1024
#define OTI 100
#define NEGV (-1e4f)
#define EPSV 1e-8f
#define CAPL 512
#define CCAP 16384
#define HBLK 256   // blocks for histogram passes

// ---------------- utility ----------------
__global__ void zero_all_kernel(int* cnt_s, int* cnt_t, int* ci_t, int* ci_s,
                                float* tpout){
  int t=blockIdx.x*256+threadIdx.x;
  if (t<MN){ cnt_s[t]=0; cnt_t[t]=0; }
  if (t<BCORR){ ci_t[t]=0; ci_s[t]=0; }
  // tp (3072) + sp (3072) + cs (1024) contiguous = 7168 floats
  for (int i=t;i<OUTC*3*2+OUTC;i+=gridDim.x*256) tpout[i]=0.0f;
}

__device__ __forceinline__ float blockReduceSum256(float v, float* red){
  int t=threadIdx.x;
  red[t]=v; __syncthreads();
  #pragma unroll
  for (int s=128;s>0;s>>=1){ if(t<s) red[t]+=red[t+s]; __syncthreads(); }
  float r=red[0]; __syncthreads();
  return r;
}

// node feats: out = l2norm(x @ W^T + b); sq = sum(out^2) (for sq_dist fidelity)
__global__ __launch_bounds__(256) void node_feat_kernel(
    const float* __restrict__ x, const float* __restrict__ W,
    const float* __restrict__ bias, float* __restrict__ out, float* __restrict__ sq){
  __shared__ float xs[DN];
  __shared__ float red[256];
  int m=blockIdx.x, i=threadIdx.x;
  xs[i]=x[m*DN+i];
  __syncthreads();
  float acc=bias[i];
  const float* wr=W+(size_t)i*DN;
  for (int k=0;k<DN;k++) acc=fmaf(wr[k],xs[k],acc);
  float ssq=blockReduceSum256(acc*acc,red);
  float o=acc/sqrtf(ssq);
  out[m*DN+i]=o;
  float s2=blockReduceSum256(o*o,red);
  if(i==0) sq[m]=s2;
}

// nearest node per point (argmin over gram-trick distance, first-min tie rule)
__global__ __launch_bounds__(256) void p2n_kernel(
    const float* __restrict__ pts, const float* __restrict__ nodes, int* __restrict__ p2n){
  __shared__ float nx[MN], ny[MN], nz[MN], nn[MN];
  for (int j=threadIdx.x;j<MN;j+=256){
    float a=nodes[j*3+0], b=nodes[j*3+1], c=nodes[j*3+2];
    nx[j]=a; ny[j]=b; nz[j]=c; nn[j]=a*a+b*b+c*c;
  }
  __syncthreads();
  int id=blockIdx.x*256+threadIdx.x;
  if (id>=NPTS) return;
  float px=pts[id*3+0], py=pts[id*3+1], pz=pts[id*3+2];
  float pp=px*px+py*py+pz*pz;
  float best=3.4e38f; int bi=0;
  for (int j=0;j<MN;j++){
    float d=pp+nn[j]-2.0f*(px*nx[j]+py*ny[j]+pz*nz[j]);
    if (d<best){best=d;bi=j;}
  }
  p2n[id]=bi;
}

__global__ __launch_bounds__(256) void scatter_kernel(
    const int* __restrict__ p2n, int* __restrict__ cnt, int* __restrict__ list){
  int id=blockIdx.x*256+threadIdx.x;
  if (id>=NPTS) return;
  int n=p2n[id];
  int t=atomicAdd(&cnt[n],1);
  if (t<CAPL) list[(size_t)n*CAPL+t]=id;
}

// per-node kNN: sort assigned points by (dist asc, idx asc), keep first 64, pad NPTS
__global__ __launch_bounds__(256) void knn_kernel(
    const float* __restrict__ pts, const float* __restrict__ nodes,
    const int* __restrict__ cnt, const int* __restrict__ list, int* __restrict__ knn){
  __shared__ float ds[CAPL];
  __shared__ int is[CAPL];
  int m=blockIdx.x;
  int c=cnt[m]; if (c>CAPL) c=CAPL;
  float ax=nodes[m*3+0], ay=nodes[m*3+1], az=nodes[m*3+2];
  float nn2=ax*ax+ay*ay+az*az;
  for (int e=threadIdx.x;e<c;e+=256){
    int p=list[(size_t)m*CAPL+e];
    float px=pts[p*3+0],py=pts[p*3+1],pz=pts[p*3+2];
    float pp=px*px+py*py+pz*pz;
    ds[e]=pp+nn2-2.0f*(px*ax+py*ay+pz*az);
    is[e]=p;
  }
  for (int k=threadIdx.x;k<KK;k+=256) knn[m*KK+k]=NPTS;
  __syncthreads();
  for (int e=threadIdx.x;e<c;e+=256){
    float d=ds[e]; int p=is[e]; int r=0;
    for (int j=0;j<c;j++){
      float dj=ds[j];
      r += (dj<d || (dj==d && is[j]<p)) ? 1 : 0;
    }
    if (r<KK) knn[m*KK+r]=p;
  }
}

// coarse scores as tiled GEMM: S[i][j] = valid ? exp(-(tt_i+ss_j-2*dot)) : 0
__global__ __launch_bounds__(256) void coarse_score_kernel(
    const float* __restrict__ tf, const float* __restrict__ sf,
    const float* __restrict__ tt, const float* __restrict__ ssv,
    const int* __restrict__ cnt_t, const int* __restrict__ cnt_s, float* __restrict__ S){
  __shared__ float tas[64][64];   // [k][r]
  __shared__ float sbs[64][64];   // [k][c]
  __shared__ float tta[64], ssa[64], tva[64], sva[64];
  int bi=blockIdx.x>>4, bj=blockIdx.x&15;
  int t=threadIdx.x, r=t&63, kq=t>>6, tx=t&15, ty=t>>4;
  if (kq==0){ tta[r]=tt[bi*64+r]; tva[r]=(cnt_t[bi*64+r]>0)?1.f:0.f; }
  if (kq==1){ ssa[r]=ssv[bj*64+r]; sva[r]=(cnt_s[bj*64+r]>0)?1.f:0.f; }
  float acc[4][4]={};
  const float* ta=tf+((size_t)bi*64)*DN;
  const float* sa=sf+((size_t)bj*64)*DN;
  for (int kc=0;kc<DN;kc+=64){
    __syncthreads();
    const float* tr_=ta+(size_t)r*DN+kc+kq*16;
    const float* sr_=sa+(size_t)r*DN+kc+kq*16;
    #pragma unroll
    for (int j4=0;j4<4;j4++){
      float4 v=*(const float4*)(tr_+4*j4);
      tas[kq*16+4*j4+0][r]=v.x; tas[kq*16+4*j4+1][r]=v.y;
      tas[kq*16+4*j4+2][r]=v.z; tas[kq*16+4*j4+3][r]=v.w;
      float4 w=*(const float4*)(sr_+4*j4);
      sbs[kq*16+4*j4+0][r]=w.x; sbs[kq*16+4*j4+1][r]=w.y;
      sbs[kq*16+4*j4+2][r]=w.z; sbs[kq*16+4*j4+3][r]=w.w;
    }
    __syncthreads();
    #pragma unroll
    for (int kk=0;kk<64;kk++){
      float4 a4=*(const float4*)(&tas[kk][4*ty]);
      float4 b4=*(const float4*)(&sbs[kk][4*tx]);
      float av[4]={a4.x,a4.y,a4.z,a4.w};
      float bv[4]={b4.x,b4.y,b4.z,b4.w};
      #pragma unroll
      for (int i=0;i<4;i++)
        #pragma unroll
        for (int j=0;j<4;j++) acc[i][j]=fmaf(av[i],bv[j],acc[i][j]);
    }
  }
  __syncthreads();
  #pragma unroll
  for (int i=0;i<4;i++){
    int rr=4*ty+i;
    #pragma unroll
    for (int j=0;j<4;j++){
      int cc=4*tx+j;
      float d=tta[rr]+ssa[cc]-2.0f*acc[i][j];
      float v=expf(-d);
      S[(size_t)(bi*64+rr)*MN + bj*64+cc]=(tva[rr]>0.f && sva[cc]>0.f)? v:0.0f;
    }
  }
}

__global__ __launch_bounds__(256) void rowsum_kernel(const float* __restrict__ S, float* __restrict__ rs){
  __shared__ float red[256];
  int i=blockIdx.x;
  float a=0;
  for (int j=threadIdx.x;j<MN;j+=256) a+=S[(size_t)i*MN+j];
  float r=blockReduceSum256(a,red);
  if (threadIdx.x==0) rs[i]=r;
}
// coalesced colsum: 16 columns per block, 64B-segment reads
__global__ __launch_bounds__(256) void colsum_kernel(const float* __restrict__ S, float* __restrict__ cs){
  __shared__ float red[16][17];
  int j0=blockIdx.x*16;
  int tx=threadIdx.x&15, ty=threadIdx.x>>4;
  float a=0;
  for (int i=ty;i<MN;i+=16) a+=S[(size_t)i*MN + j0+tx];
  red[ty][tx]=a; __syncthreads();
  if (ty==0){
    float s=0;
    #pragma unroll
    for (int q=0;q<16;q++) s+=red[q][tx];
    cs[j0+tx]=s;
  }
}
// dual normalization fused with coarse histogram pass
__global__ __launch_bounds__(256) void dualnorm_hist_kernel(
    float* __restrict__ S, const float* __restrict__ rs, const float* __restrict__ cs,
    unsigned* __restrict__ partial){
  __shared__ unsigned lh[256];
  lh[threadIdx.x]=0u; __syncthreads();
  for (int idx=blockIdx.x*256+threadIdx.x; idx<MN*MN; idx+=gridDim.x*256){
    int i=idx>>10, j=idx&1023;
    float v=S[idx];
    v=(v/(rs[i]+EPSV))*(v/(cs[j]+EPSV));
    S[idx]=v;
    if (v>0.0f) atomicAdd(&lh[__float_as_uint(v)>>24],1u);
  }
  __syncthreads();
  partial[blockIdx.x*256+threadIdx.x]=lh[threadIdx.x];
}

// ---------- deterministic top-k, contention-free two-level histogram ----------
__global__ __launch_bounds__(256) void hist_coarse_kernel(
    const float* __restrict__ arr, int n, unsigned* __restrict__ partial){
  __shared__ unsigned lh[256];
  lh[threadIdx.x]=0u; __syncthreads();
  for (int i=blockIdx.x*256+threadIdx.x; i<n; i+=gridDim.x*256){
    float v=arr[i];
    if (v>0.0f) atomicAdd(&lh[__float_as_uint(v)>>24],1u);
  }
  __syncthreads();
  partial[blockIdx.x*256+threadIdx.x]=lh[threadIdx.x];
}
__global__ __launch_bounds__(256) void scan_coarse_kernel(
    const unsigned* __restrict__ partial, int nblk, int k, unsigned* __restrict__ meta){
  __shared__ unsigned h[256];
  int t=threadIdx.x;
  unsigned a=0;
  for (int i=0;i<nblk;i++) a+=partial[(size_t)i*256+t];
  h[t]=a; __syncthreads();
  if (t==0){
    unsigned cum=0; int cb=-1; unsigned above=0;
    for (int b=255;b>=0;b--){
      if (cum+h[b] >= (unsigned)k){ cb=b; above=cum; break; }
      cum+=h[b];
    }
    if (cb<0){ cb=0; above=cum-h[0]; }
    meta[2]=(unsigned)cb; meta[3]=above;
  }
}
__global__ __launch_bounds__(256) void hist_fine_kernel(
    const float* __restrict__ arr, int n, const unsigned* __restrict__ meta,
    unsigned* __restrict__ partial){
  __shared__ unsigned lh[256];
  lh[threadIdx.x]=0u; __syncthreads();
  unsigned CB=meta[2];
  for (int i=blockIdx.x*256+threadIdx.x; i<n; i+=gridDim.x*256){
    float v=arr[i];
    unsigned b=__float_as_uint(v);
    if (v>0.0f && (b>>24)==CB) atomicAdd(&lh[(b>>16)&255u],1u);
  }
  __syncthreads();
  partial[blockIdx.x*256+threadIdx.x]=lh[threadIdx.x];
}
__global__ __launch_bounds__(256) void scan_fine_kernel(
    const unsigned* __restrict__ partial, int nblk, int k, unsigned* __restrict__ meta){
  __shared__ unsigned h[256];
  int t=threadIdx.x;
  unsigned a=0;
  for (int i=0;i<nblk;i++) a+=partial[(size_t)i*256+t];
  h[t]=a; __syncthreads();
  if (t==0){
    unsigned CB=meta[2];
    unsigned cum=meta[3]; int sb=0;
    for (int b=255;b>=0;b--){
      if (cum+h[b] >= (unsigned)k){ sb=b; break; }
      cum+=h[b];
    }
    meta[0]=CB*256u+(unsigned)sb;
    meta[1]=0u;
  }
}
__global__ void compact_kernel(const float* __restrict__ arr, int n,
                               const unsigned* __restrict__ meta,
                               float* __restrict__ cv, int* __restrict__ ci,
                               unsigned* __restrict__ cnt){
  unsigned T=meta[0];
  for (int i=blockIdx.x*blockDim.x+threadIdx.x; i<n; i+=gridDim.x*blockDim.x){
    float v=arr[i];
    if (v>0.0f && (__float_as_uint(v)>>16)>=T){
      unsigned p=atomicAdd(cnt,1u);
      if (p<CCAP){ cv[p]=v; ci[p]=i; }
    }
  }
}
__global__ __launch_bounds__(256) void rank_coarse_kernel(
    const float* __restrict__ cv, const int* __restrict__ ci, const unsigned* __restrict__ meta,
    int* __restrict__ ti, int* __restrict__ si){
  int c=(int)meta[1]; if (c>CCAP) c=CCAP;
  int t=blockIdx.x*256+threadIdx.x;
  if (t>=c) return;
  float v=cv[t]; int idx=ci[t];
  int rk=0;
  for (int j=0;j<c;j++){
    float vj=cv[j]; int ij=ci[j];
    rk += (vj>v || (vj==v && ij<idx)) ? 1 : 0;
  }
  if (rk<BCORR){ ti[rk]=idx/MN; si[rk]=idx%MN; }
}
__global__ __launch_bounds__(256) void rank_fine_kernel(
    const float* __restrict__ cv, const int* __restrict__ ci, const unsigned* __restrict__ meta,
    const int* __restrict__ sel_t, const int* __restrict__ sel_s,
    const float* __restrict__ tpts, const float* __restrict__ spts,
    float* __restrict__ tp, float* __restrict__ sp, float* __restrict__ cs){
  int c=(int)meta[1]; if (c>CCAP) c=CCAP;
  int t=blockIdx.x*256+threadIdx.x;
  if (t>=c) return;
  float v=cv[t]; int idx=ci[t];
  int rk=0;
  for (int j=0;j<c;j++){
    float vj=cv[j]; int ij=ci[j];
    rk += (vj>v || (vj==v && ij<idx)) ? 1 : 0;
  }
  if (rk<OUTC){
    int b=idx>>12, r=(idx>>6)&63, cc=idx&63;
    int tpi=sel_t[b*KK+r], spi=sel_s[b*KK+cc];
    float tx=0,ty=0,tz=0,sx=0,sy=0,sz=0;
    if (tpi<NPTS){ tx=tpts[tpi*3]; ty=tpts[tpi*3+1]; tz=tpts[tpi*3+2]; }
    if (spi<NPTS){ sx=spts[spi*3]; sy=spts[spi*3+1]; sz=spts[spi*3+2]; }
    tp[rk*3+0]=tx; tp[rk*3+1]=ty; tp[rk*3+2]=tz;
    sp[rk*3+0]=sx; sp[rk*3+1]=sy; sp[rk*3+2]=sz;
    cs[rk]=v;
  }
}

// ---------- patch assembly / OT / fine ----------
// gathered point features GEMM with inlined index gather; bo==0 blocks also
// materialize sel for downstream kernels.
__global__ __launch_bounds__(256) void sel_feat_kernel(
    const int* __restrict__ cib, const int* __restrict__ knn,
    const float* __restrict__ ptf,
    const float* __restrict__ W, const float* __restrict__ bias,
    float* __restrict__ out, int* __restrict__ sel){
  __shared__ float Xs[64][64];   // [k][r]
  __shared__ float Ws[64][64];   // [k][o]
  __shared__ float pvf[64];
  int bj=blockIdx.x>>2, bo=blockIdx.x&3;
  int t=threadIdx.x, r=t&63, kq=t>>6, tx=t&15, ty=t>>4;
  int p=knn[cib[bj]*KK+r];
  if (kq==0){
    pvf[r]=(p!=NPTS)?1.f:0.f;
    if (bo==0) sel[bj*KK+r]=p;
  }
  const float* xr=ptf+(size_t)p*DPT+kq*16;
  #pragma unroll
  for (int j4=0;j4<4;j4++){
    float4 v=(p==NPTS)? make_float4(0.f,0.f,0.f,0.f) : *(const float4*)(xr+4*j4);
    Xs[kq*16+4*j4+0][r]=v.x; Xs[kq*16+4*j4+1][r]=v.y;
    Xs[kq*16+4*j4+2][r]=v.z; Xs[kq*16+4*j4+3][r]=v.w;
  }
  const float* wr=W+(size_t)(bo*64+r)*DPT+kq*16;
  #pragma unroll
  for (int j4=0;j4<4;j4++){
    float4 w=*(const float4*)(wr+4*j4);
    Ws[kq*16+4*j4+0][r]=w.x; Ws[kq*16+4*j4+1][r]=w.y;
    Ws[kq*16+4*j4+2][r]=w.z; Ws[kq*16+4*j4+3][r]=w.w;
  }
  __syncthreads();
  float acc[4][4]={};
  #pragma unroll
  for (int kk=0;kk<64;kk++){
    float4 a4=*(const float4*)(&Xs[kk][4*ty]);
    float4 w4=*(const float4*)(&Ws[kk][4*tx]);
    float av[4]={a4.x,a4.y,a4.z,a4.w};
    float wv[4]={w4.x,w4.y,w4.z,w4.w};
    #pragma unroll
    for (int i=0;i<4;i++)
      #pragma unroll
      for (int j=0;j<4;j++) acc[i][j]=fmaf(av[i],wv[j],acc[i][j]);
  }
  #pragma unroll
  for (int i=0;i<4;i++){
    int rr=4*ty+i;
    #pragma unroll
    for (int j=0;j<4;j++){
      int oo=4*tx+j;
      float v=acc[i][j]+bias[bo*64+oo];
      out[(size_t)(bj*64+rr)*DN + bo*64+oo]= (pvf[rr]>0.f)? v : 0.0f;
    }
  }
}

// OT input P (65x65) per batch as tiled GEMM (64x64x256) + dustbin/mask epilogue
__global__ __launch_bounds__(256) void pbuild_kernel(
    const float* __restrict__ ft, const float* __restrict__ fs,
    const int* __restrict__ sel_t, const int* __restrict__ sel_s,
    const float* __restrict__ alpha_p, float* __restrict__ P){
  __shared__ float tas[64][64];   // [k][r]
  __shared__ float sbs[64][64];   // [k][c]
  __shared__ float tmv[64], smv[64];
  int b=blockIdx.x, t=threadIdx.x;
  int r=t&63, kq=t>>6, tx=t&15, ty=t>>4;
  if (kq==0) tmv[r]=(sel_t[b*KK+r]!=NPTS)?1.f:0.f;
  if (kq==1) smv[r]=(sel_s[b*KK+r]!=NPTS)?1.f:0.f;
  float acc[4][4]={};
  const float* tb=ft+(size_t)b*KK*DN;
  const float* sb=fs+(size_t)b*KK*DN;
  for (int kc=0;kc<DN;kc+=64){
    __syncthreads();
    const float* tr_=tb+(size_t)r*DN+kc+kq*16;
    const float* sr_=sb+(size_t)r*DN+kc+kq*16;
    #pragma unroll
    for (int j4=0;j4<4;j4++){
      float4 v=*(const float4*)(tr_+4*j4);
      tas[kq*16+4*j4+0][r]=v.x; tas[kq*16+4*j4+1][r]=v.y;
      tas[kq*16+4*j4+2][r]=v.z; tas[kq*16+4*j4+3][r]=v.w;
      float4 w=*(const float4*)(sr_+4*j4);
      sbs[kq*16+4*j4+0][r]=w.x; sbs[kq*16+4*j4+1][r]=w.y;
      sbs[kq*16+4*j4+2][r]=w.z; sbs[kq*16+4*j4+3][r]=w.w;
    }
    __syncthreads();
    #pragma unroll
    for (int kk=0;kk<64;kk++){
      float4 a4=*(const float4*)(&tas[kk][4*ty]);
      float4 b4=*(const float4*)(&sbs[kk][4*tx]);
      float av[4]={a4.x,a4.y,a4.z,a4.w};
      float bv[4]={b4.x,b4.y,b4.z,b4.w};
      #pragma unroll
      for (int i=0;i<4;i++)
        #pragma unroll
        for (int j=0;j<4;j++) acc[i][j]=fmaf(av[i],bv[j],acc[i][j]);
    }
  }
  __syncthreads();
  float alpha=alpha_p[0];
  float* Pb=P+(size_t)b*65*65;
  #pragma unroll
  for (int i=0;i<4;i++){
    int rr=4*ty+i;
    bool tok=tmv[rr]>0.f;
    #pragma unroll
    for (int j=0;j<4;j++){
      int cc=4*tx+j;
      bool invm=(!tok)||(smv[cc]<=0.f);
      Pb[rr*65+cc]= invm ? NEGV : acc[i][j]*0.0625f;
    }
  }
  if (t<64){
    Pb[64*65+t]=(smv[t]<=0.f)? NEGV : alpha;
    Pb[t*65+64]=(tmv[t]<=0.f)? NEGV : alpha;
  }
  if (t==64) Pb[64*65+64]=alpha;
}

// Sinkhorn linear-domain, TWO batches per wave (ILP doubles to hide LDS latency
// at 1 wave/CU). Lane l holds row l + column l of Km for both batches in VGPRs.
__global__ __launch_bounds__(64,1) void ot_kernel(
    float* __restrict__ P, const int* __restrict__ sel_t, const int* __restrict__ sel_s){
  __shared__ float PsA[65*65], PsB[65*65];
  __shared__ __align__(16) float VldsA[64], PvA[64], UldsA[64], PuA[64];
  __shared__ __align__(16) float VldsB[64], PvB[64], UldsB[64], PuB[64];
  __shared__ float ufA[65], vfA[65], ufB[65], vfB[65];
  int bA=blockIdx.x*2, bB=bA+1, l=threadIdx.x;
  float* PgA=P+(size_t)bA*65*65;
  float* PgB=P+(size_t)bB*65*65;
  for (int e=l;e<65*65;e+=64){ PsA[e]=PgA[e]; PsB[e]=PgB[e]; }
  bool rvA=(sel_t[bA*KK+l]!=NPTS), cvA=(sel_s[bA*KK+l]!=NPTS);
  bool rvB=(sel_t[bB*KK+l]!=NPTS), cvB=(sel_s[bB*KK+l]!=NPTS);
  int nrA=(int)__popcll(__ballot(rvA)), ncA=(int)__popcll(__ballot(cvA));
  int nrB=(int)__popcll(__ballot(rvB)), ncB=(int)__popcll(__ballot(cvB));
  float invA=1.0f/(float)(nrA+ncA), invB=1.0f/(float)(nrB+ncB);
  float nrmA=-logf((float)(nrA+ncA)), nrmB=-logf((float)(nrB+ncB));
  float muA=invA, nuA=invA, mu64A=(float)ncA*invA, nu64A=(float)nrA*invA;
  float muB=invB, nuB=invB, mu64B=(float)ncB*invB, nu64B=(float)nrB*invB;
  __syncthreads();
  float aA[KK], bTA[KK], aB[KK], bTB[KK];
  #pragma unroll
  for (int c=0;c<KK;c++){ aA[c]=expf(PsA[l*65+c]); aB[c]=expf(PsB[l*65+c]); }
  #pragma unroll
  for (int r=0;r<KK;r++){ bTA[r]=expf(PsA[r*65+l]); bTB[r]=expf(PsB[r*65+l]); }
  float a64A=expf(PsA[l*65+64]), b64A=expf(PsA[64*65+l]), k64A=expf(PsA[64*65+64]);
  float a64B=expf(PsB[l*65+64]), b64B=expf(PsB[64*65+l]), k64B=expf(PsB[64*65+64]);
  float VA=1.0f, V64A=1.0f, UA, U64A;
  float VB=1.0f, V64B=1.0f, UB, U64B;

  for (int it=0; it<OTI; ++it){
    // ---- u-pass (both batches interleaved) ----
    VldsA[l]=VA; PvA[l]=b64A*VA;
    VldsB[l]=VB; PvB[l]=b64B*VB;
    __syncthreads();
    float sA0=0,sA1=0,sA2=0,sA3=0, dA0=0,dA1=0,dA2=0,dA3=0, zA0=0,zA1=0,zA2=0,zA3=0;
    float sB0=0,sB1=0,sB2=0,sB3=0, dB0=0,dB1=0,dB2=0,dB3=0, zB0=0,zB1=0,zB2=0,zB3=0;
    #pragma unroll
    for (int c4=0;c4<16;c4++){
      float4 va=*(const float4*)(VldsA+4*c4);
      float4 pa=*(const float4*)(PvA+4*c4);
      float4 vb=*(const float4*)(VldsB+4*c4);
      float4 pb=*(const float4*)(PvB+4*c4);
      sA0=fmaf(aA[4*c4+0],va.x,sA0); sA1=fmaf(aA[4*c4+1],va.y,sA1);
      sA2=fmaf(aA[4*c4+2],va.z,sA2); sA3=fmaf(aA[4*c4+3],va.w,sA3);
      dA0+=pa.x; dA1+=pa.y; dA2+=pa.z; dA3+=pa.w;
      zA0+=va.x; zA1+=va.y; zA2+=va.z; zA3+=va.w;
      sB0=fmaf(aB[4*c4+0],vb.x,sB0); sB1=fmaf(aB[4*c4+1],vb.y,sB1);
      sB2=fmaf(aB[4*c4+2],vb.z,sB2); sB3=fmaf(aB[4*c4+3],vb.w,sB3);
      dB0+=pb.x; dB1+=pb.y; dB2+=pb.z; dB3+=pb.w;
      zB0+=vb.x; zB1+=vb.y; zB2+=vb.z; zB3+=vb.w;
    }
    {
      float srow=(sA0+sA1)+(sA2+sA3)+a64A*V64A;
      float s64 =(dA0+dA1)+(dA2+dA3)+k64A*V64A;
      float sv  =(zA0+zA1)+(zA2+zA3)+V64A;
      UA = rvA ? (muA/srow) : (1.0f/sv);
      U64A = mu64A/s64;
    }
    {
      float srow=(sB0+sB1)+(sB2+sB3)+a64B*V64B;
      float s64 =(dB0+dB1)+(dB2+dB3)+k64B*V64B;
      float sv  =(zB0+zB1)+(zB2+zB3)+V64B;
      UB = rvB ? (muB/srow) : (1.0f/sv);
      U64B = mu64B/s64;
    }
    // ---- v-pass ----
    UldsA[l]=UA; PuA[l]=a64A*UA;
    UldsB[l]=UB; PuB[l]=a64B*UB;
    __syncthreads();
    float tA0=0,tA1=0,tA2=0,tA3=0, eA0=0,eA1=0,eA2=0,eA3=0, yA0=0,yA1=0,yA2=0,yA3=0;
    float tB0=0,tB1=0,tB2=0,tB3=0, eB0=0,eB1=0,eB2=0,eB3=0, yB0=0,yB1=0,yB2=0,yB3=0;
    #pragma unroll
    for (int r4=0;r4<16;r4++){
      float4 ua=*(const float4*)(UldsA+4*r4);
      float4 qa=*(const float4*)(PuA+4*r4);
      float4 ub=*(const float4*)(UldsB+4*r4);
      float4 qb=*(const float4*)(PuB+4*r4);
      tA0=fmaf(bTA[4*r4+0],ua.x,tA0); tA1=fmaf(bTA[4*r4+1],ua.y,tA1);
      tA2=fmaf(bTA[4*r4+2],ua.z,tA2); tA3=fmaf(bTA[4*r4+3],ua.w,tA3);
      eA0+=qa.x; eA1+=qa.y; eA2+=qa.z; eA3+=qa.w;
      yA0+=ua.x; yA1+=ua.y; yA2+=ua.z; yA3+=ua.w;
      tB0=fmaf(bTB[4*r4+0],ub.x,tB0); tB1=fmaf(bTB[4*r4+1],ub.y,tB1);
      tB2=fmaf(bTB[4*r4+2],ub.z,tB2); tB3=fmaf(bTB[4*r4+3],ub.w,tB3);
      eB0+=qb.x; eB1+=qb.y; eB2+=qb.z; eB3+=qb.w;
      yB0+=ub.x; yB1+=ub.y; yB2+=ub.z; yB3+=ub.w;
    }
    {
      float scol=(tA0+tA1)+(tA2+tA3)+b64A*U64A;
      float s64v=(eA0+eA1)+(eA2+eA3)+k64A*U64A;
      float su  =(yA0+yA1)+(yA2+yA3)+U64A;
      VA = cvA ? (nuA/scol) : (1.0f/su);
      V64A = nu64A/s64v;
    }
    {
      float scol=(tB0+tB1)+(tB2+tB3)+b64B*U64B;
      float s64v=(eB0+eB1)+(eB2+eB3)+k64B*U64B;
      float su  =(yB0+yB1)+(yB2+yB3)+U64B;
      VB = cvB ? (nuB/scol) : (1.0f/su);
      V64B = nu64B/s64v;
    }
    __syncthreads();
  }
  ufA[l]=logf(UA); vfA[l]=logf(VA); ufB[l]=logf(UB); vfB[l]=logf(VB);
  if (l==0){ ufA[64]=logf(U64A); vfA[64]=logf(V64A); ufB[64]=logf(U64B); vfB[64]=logf(V64B); }
  __syncthreads();
  for (int e=l;e<65*65;e+=64){
    int r=e/65, c=e-65*r;
    PgA[e]=PsA[e]+ufA[r]+vfA[c]-nrmA;
    PgB[e]=PsB[e]+ufB[r]+vfB[c]-nrmB;
  }
}

// fine prep fused with coarse histogram of the masked scores
__global__ __launch_bounds__(256) void fineprep_kernel(
    const float* __restrict__ P, const int* __restrict__ sel_t, const int* __restrict__ sel_s,
    float* __restrict__ smout, unsigned* __restrict__ partial){
  __shared__ float s[KK*KK];
  __shared__ unsigned long long rowm[KK], colm[KK];
  __shared__ int tmk[KK], smk[KK];
  __shared__ unsigned lh[256];
  int b=blockIdx.x, t=threadIdx.x;
  lh[t]=0u;
  const float* Pb=P+(size_t)b*65*65;
  for (int e=t;e<KK*KK;e+=256){
    int r=e>>6, c=e&63;
    s[e]=expf(Pb[r*65+c]);
  }
  if (t<KK){ tmk[t]=(sel_t[b*KK+t]!=NPTS); smk[t]=(sel_s[b*KK+t]!=NPTS); }
  __syncthreads();
  if (t<KK){
    float v1=-1,v2=-1,v3=-1; int i1=0,i2=0,i3=0;
    const float* row=s+t*KK;
    for (int c=0;c<KK;c++){ float v=row[c];
      if (v>v1){v3=v2;i3=i2;v2=v1;i2=i1;v1=v;i1=c;}
      else if (v>v2){v3=v2;i3=i2;v2=v;i2=c;}
      else if (v>v3){v3=v;i3=c;}
    }
    rowm[t]=(1ULL<<i1)|(1ULL<<i2)|(1ULL<<i3);
  } else if (t<2*KK){
    int c=t-KK;
    float v1=-1,v2=-1,v3=-1; int i1=0,i2=0,i3=0;
    for (int r=0;r<KK;r++){ float v=s[r*KK+c];
      if (v>v1){v3=v2;i3=i2;v2=v1;i2=i1;v1=v;i1=r;}
      else if (v>v2){v3=v2;i3=i2;v2=v;i2=r;}
      else if (v>v3){v3=v;i3=r;}
    }
    colm[c]=(1ULL<<i1)|(1ULL<<i2)|(1ULL<<i3);
  }
  __syncthreads();
  for (int e=t;e<KK*KK;e+=256){
    int r=e>>6, c=e&63;
    float v=s[e];
    bool keep = ((rowm[r]>>c)&1ULL) && ((colm[c]>>r)&1ULL) && (v>0.05f) && tmk[r] && smk[c];
    float o= keep? v : 0.0f;
    smout[(size_t)b*KK*KK+e]=o;
    if (o>0.0f) atomicAdd(&lh[__float_as_uint(o)>>24],1u);
  }
  __syncthreads();
  partial[b*256+t]=lh[t];
}

extern "C" void kernel_launch(void* const* d_in, const int* in_sizes, int n_in,
                              void* d_out, int out_size, void* d_ws, size_t ws_size,
                              hipStream_t stream){
  const float* src_pts=(const float*)d_in[0];
  const float* tgt_pts=(const float*)d_in[1];
  const float* src_pf =(const float*)d_in[2];
  const float* tgt_pf =(const float*)d_in[3];
  const float* src_nf =(const float*)d_in[4];
  const float* tgt_nf =(const float*)d_in[5];
  const float* src_nx =(const float*)d_in[6];
  const float* tgt_nx =(const float*)d_in[7];
  const float* cw=(const float*)d_in[8];
  const float* cb=(const float*)d_in[9];
  const float* fw=(const float*)d_in[10];
  const float* fb=(const float*)d_in[11];
  const float* alpha=(const float*)d_in[12];

  char* ws=(char*)d_ws;
  size_t off=0;
  auto A=[&](size_t bytes)->char*{
    char* p=ws+off; off+=(bytes+255)&~(size_t)255; return p; };

  float* tf    =(float*)A((size_t)MN*DN*4);
  float* sfb   =(float*)A((size_t)MN*DN*4);
  float* tt    =(float*)A(MN*4);
  float* ssv   =(float*)A(MN*4);
  int*   p2n_s =(int*)A((size_t)NPTS*4);
  int*   p2n_t =(int*)A((size_t)NPTS*4);
  int*   cnt_s =(int*)A(MN*4);
  int*   cnt_t =(int*)A(MN*4);
  int*   list_s=(int*)A((size_t)MN*CAPL*4);
  int*   list_t=(int*)A((size_t)MN*CAPL*4);
  int*   knn_s =(int*)A((size_t)MN*KK*4);
  int*   knn_t =(int*)A((size_t)MN*KK*4);
  float* Smat  =(float*)A((size_t)MN*MN*4);
  unsigned* partial=(unsigned*)A((size_t)HBLK*256*4);
  unsigned* meta=(unsigned*)A(256);
  float* cand_v=(float*)A((size_t)CCAP*4);
  int*   cand_i=(int*)A((size_t)CCAP*4);
  int*   ci_t  =(int*)A(BCORR*4);
  int*   ci_s  =(int*)A(BCORR*4);
  int*   sel_t =(int*)A((size_t)BCORR*KK*4);
  int*   sel_s =(int*)A((size_t)BCORR*KK*4);
  float* feat_t=(float*)A((size_t)BCORR*KK*DN*4);
  float* feat_s=(float*)A((size_t)BCORR*KK*DN*4);
  float* smf   =(float*)A((size_t)BCORR*KK*KK*4);
  float* rs    =(float*)A(MN*4);
  float* csum  =(float*)A(MN*4);

  float* out=(float*)d_out;
  float* msout=out;
  float* tpout=out+(size_t)BCORR*65*65;
  float* spout=tpout+(size_t)OUTC*3;
  float* csout=spout+(size_t)OUTC*3;

  const int PB=(NPTS+255)/256;

  zero_all_kernel<<<28,256,0,stream>>>(cnt_s,cnt_t,ci_t,ci_s,tpout);
  node_feat_kernel<<<MN,256,0,stream>>>(tgt_nf,cw,cb,tf,tt);
  node_feat_kernel<<<MN,256,0,stream>>>(src_nf,cw,cb,sfb,ssv);
  p2n_kernel<<<PB,256,0,stream>>>(src_pts,src_nx,p2n_s);
  p2n_kernel<<<PB,256,0,stream>>>(tgt_pts,tgt_nx,p2n_t);
  scatter_kernel<<<PB,256,0,stream>>>(p2n_s,cnt_s,list_s);
  scatter_kernel<<<PB,256,0,stream>>>(p2n_t,cnt_t,list_t);
  knn_kernel<<<MN,256,0,stream>>>(src_pts,src_nx,cnt_s,list_s,knn_s);
  knn_kernel<<<MN,256,0,stream>>>(tgt_pts,tgt_nx,cnt_t,list_t,knn_t);

  coarse_score_kernel<<<256,256,0,stream>>>(tf,sfb,tt,ssv,cnt_t,cnt_s,Smat);
  rowsum_kernel<<<MN,256,0,stream>>>(Smat,rs);
  colsum_kernel<<<64,256,0,stream>>>(Smat,csum);
  dualnorm_hist_kernel<<<HBLK,256,0,stream>>>(Smat,rs,csum,partial);

  scan_coarse_kernel<<<1,256,0,stream>>>(partial,HBLK,BCORR,meta);
  hist_fine_kernel<<<HBLK,256,0,stream>>>(Smat,MN*MN,meta,partial);
  scan_fine_kernel<<<1,256,0,stream>>>(partial,HBLK,BCORR,meta);
  compact_kernel<<<2048,256,0,stream>>>(Smat,MN*MN,meta,cand_v,cand_i,meta+1);
  rank_coarse_kernel<<<CCAP/256,256,0,stream>>>(cand_v,cand_i,meta,ci_t,ci_s);

  sel_feat_kernel<<<1024,256,0,stream>>>(ci_t,knn_t,tgt_pf,fw,fb,feat_t,sel_t);
  sel_feat_kernel<<<1024,256,0,stream>>>(ci_s,knn_s,src_pf,fw,fb,feat_s,sel_s);

  pbuild_kernel<<<BCORR,256,0,stream>>>(feat_t,feat_s,sel_t,sel_s,alpha,msout);
  ot_kernel<<<BCORR/2,64,0,stream>>>(msout,sel_t,sel_s);

  fineprep_kernel<<<BCORR,256,0,stream>>>(msout,sel_t,sel_s,smf,partial);
  scan_coarse_kernel<<<1,256,0,stream>>>(partial,BCORR,OUTC,meta);
  hist_fine_kernel<<<HBLK,256,0,stream>>>(smf,BCORR*KK*KK,meta,partial);
  scan_fine_kernel<<<1,256,0,stream>>>(partial,HBLK,OUTC,meta);
  compact_kernel<<<2048,256,0,stream>>>(smf,BCORR*KK*KK,meta,cand_v,cand_i,meta+1);
  rank_fine_kernel<<<CCAP/256,256,0,stream>>>(cand_v,cand_i,meta,sel_t,sel_s,
                                              tgt_pts,src_pts,tpout,spout,csout);
}

// Round 8
// 784.206 us; speedup vs baseline: 1.6363x; 1.6363x over previous
//
#include <hip/hip_runtime.h>
#include <math.h>

#define NPTS 50000
#define MN 1024
#define KK 64
#define DPT 64
#define DN 256
#define BCORR 256
#define OUTC 1024
#define OTI 100
#define NEGV (-1e4f)
#define EPSV 1e-8f
#define CAPL 512
#define CCAP 16384
#define HBLK 256   // blocks for histogram passes

// ---------------- utility ----------------
__global__ void zero_all_kernel(int* cnt_s, int* cnt_t, int* ci_t, int* ci_s,
                                float* tpout){
  int t=blockIdx.x*256+threadIdx.x;
  if (t<MN){ cnt_s[t]=0; cnt_t[t]=0; }
  if (t<BCORR){ ci_t[t]=0; ci_s[t]=0; }
  for (int i=t;i<OUTC*3*2+OUTC;i+=gridDim.x*256) tpout[i]=0.0f;
}

__device__ __forceinline__ float blockReduceSum256(float v, float* red){
  int t=threadIdx.x;
  red[t]=v; __syncthreads();
  #pragma unroll
  for (int s=128;s>0;s>>=1){ if(t<s) red[t]+=red[t+s]; __syncthreads(); }
  float r=red[0]; __syncthreads();
  return r;
}

// node feats: out = l2norm(x @ W^T + b); sq = sum(out^2) (for sq_dist fidelity)
__global__ __launch_bounds__(256) void node_feat_kernel(
    const float* __restrict__ x, const float* __restrict__ W,
    const float* __restrict__ bias, float* __restrict__ out, float* __restrict__ sq){
  __shared__ float xs[DN];
  __shared__ float red[256];
  int m=blockIdx.x, i=threadIdx.x;
  xs[i]=x[m*DN+i];
  __syncthreads();
  float acc=bias[i];
  const float* wr=W+(size_t)i*DN;
  for (int k=0;k<DN;k++) acc=fmaf(wr[k],xs[k],acc);
  float ssq=blockReduceSum256(acc*acc,red);
  float o=acc/sqrtf(ssq);
  out[m*DN+i]=o;
  float s2=blockReduceSum256(o*o,red);
  if(i==0) sq[m]=s2;
}

// nearest node per point; nodes packed as float4 (x,y,z,|n|^2) in LDS
__global__ __launch_bounds__(256) void p2n_kernel(
    const float* __restrict__ pts, const float* __restrict__ nodes, int* __restrict__ p2n){
  __shared__ __align__(16) float4 nd[MN];
  for (int j=threadIdx.x;j<MN;j+=256){
    float a=nodes[j*3+0], b=nodes[j*3+1], c=nodes[j*3+2];
    nd[j]=make_float4(a,b,c,a*a+b*b+c*c);
  }
  __syncthreads();
  int id=blockIdx.x*256+threadIdx.x;
  if (id>=NPTS) return;
  float px=pts[id*3+0], py=pts[id*3+1], pz=pts[id*3+2];
  float pp=px*px+py*py+pz*pz;
  float best=3.4e38f; int bi=0;
  for (int j=0;j<MN;j++){
    float4 n=nd[j];
    float d=pp+n.w-2.0f*(px*n.x+py*n.y+pz*n.z);
    if (d<best){best=d;bi=j;}
  }
  p2n[id]=bi;
}

__global__ __launch_bounds__(256) void scatter_kernel(
    const int* __restrict__ p2n, int* __restrict__ cnt, int* __restrict__ list){
  int id=blockIdx.x*256+threadIdx.x;
  if (id>=NPTS) return;
  int n=p2n[id];
  int t=atomicAdd(&cnt[n],1);
  if (t<CAPL) list[(size_t)n*CAPL+t]=id;
}

// per-node kNN: sort assigned points by (dist asc, idx asc), keep first 64, pad NPTS
__global__ __launch_bounds__(256) void knn_kernel(
    const float* __restrict__ pts, const float* __restrict__ nodes,
    const int* __restrict__ cnt, const int* __restrict__ list, int* __restrict__ knn){
  __shared__ float ds[CAPL];
  __shared__ int is[CAPL];
  int m=blockIdx.x;
  int c=cnt[m]; if (c>CAPL) c=CAPL;
  float ax=nodes[m*3+0], ay=nodes[m*3+1], az=nodes[m*3+2];
  float nn2=ax*ax+ay*ay+az*az;
  for (int e=threadIdx.x;e<c;e+=256){
    int p=list[(size_t)m*CAPL+e];
    float px=pts[p*3+0],py=pts[p*3+1],pz=pts[p*3+2];
    float pp=px*px+py*py+pz*pz;
    ds[e]=pp+nn2-2.0f*(px*ax+py*ay+pz*az);
    is[e]=p;
  }
  for (int k=threadIdx.x;k<KK;k+=256) knn[m*KK+k]=NPTS;
  __syncthreads();
  for (int e=threadIdx.x;e<c;e+=256){
    float d=ds[e]; int p=is[e]; int r=0;
    for (int j=0;j<c;j++){
      float dj=ds[j];
      r += (dj<d || (dj==d && is[j]<p)) ? 1 : 0;
    }
    if (r<KK) knn[m*KK+r]=p;
  }
}

// coarse scores as tiled GEMM
__global__ __launch_bounds__(256) void coarse_score_kernel(
    const float* __restrict__ tf, const float* __restrict__ sf,
    const float* __restrict__ tt, const float* __restrict__ ssv,
    const int* __restrict__ cnt_t, const int* __restrict__ cnt_s, float* __restrict__ S){
  __shared__ float tas[64][64];   // [k][r]
  __shared__ float sbs[64][64];   // [k][c]
  __shared__ float tta[64], ssa[64], tva[64], sva[64];
  int bi=blockIdx.x>>4, bj=blockIdx.x&15;
  int t=threadIdx.x, r=t&63, kq=t>>6, tx=t&15, ty=t>>4;
  if (kq==0){ tta[r]=tt[bi*64+r]; tva[r]=(cnt_t[bi*64+r]>0)?1.f:0.f; }
  if (kq==1){ ssa[r]=ssv[bj*64+r]; sva[r]=(cnt_s[bj*64+r]>0)?1.f:0.f; }
  float acc[4][4]={};
  const float* ta=tf+((size_t)bi*64)*DN;
  const float* sa=sf+((size_t)bj*64)*DN;
  for (int kc=0;kc<DN;kc+=64){
    __syncthreads();
    const float* tr_=ta+(size_t)r*DN+kc+kq*16;
    const float* sr_=sa+(size_t)r*DN+kc+kq*16;
    #pragma unroll
    for (int j4=0;j4<4;j4++){
      float4 v=*(const float4*)(tr_+4*j4);
      tas[kq*16+4*j4+0][r]=v.x; tas[kq*16+4*j4+1][r]=v.y;
      tas[kq*16+4*j4+2][r]=v.z; tas[kq*16+4*j4+3][r]=v.w;
      float4 w=*(const float4*)(sr_+4*j4);
      sbs[kq*16+4*j4+0][r]=w.x; sbs[kq*16+4*j4+1][r]=w.y;
      sbs[kq*16+4*j4+2][r]=w.z; sbs[kq*16+4*j4+3][r]=w.w;
    }
    __syncthreads();
    #pragma unroll
    for (int kk=0;kk<64;kk++){
      float4 a4=*(const float4*)(&tas[kk][4*ty]);
      float4 b4=*(const float4*)(&sbs[kk][4*tx]);
      float av[4]={a4.x,a4.y,a4.z,a4.w};
      float bv[4]={b4.x,b4.y,b4.z,b4.w};
      #pragma unroll
      for (int i=0;i<4;i++)
        #pragma unroll
        for (int j=0;j<4;j++) acc[i][j]=fmaf(av[i],bv[j],acc[i][j]);
    }
  }
  __syncthreads();
  #pragma unroll
  for (int i=0;i<4;i++){
    int rr=4*ty+i;
    #pragma unroll
    for (int j=0;j<4;j++){
      int cc=4*tx+j;
      float d=tta[rr]+ssa[cc]-2.0f*acc[i][j];
      float v=expf(-d);
      S[(size_t)(bi*64+rr)*MN + bj*64+cc]=(tva[rr]>0.f && sva[cc]>0.f)? v:0.0f;
    }
  }
}

__global__ __launch_bounds__(256) void rowsum_kernel(const float* __restrict__ S, float* __restrict__ rs){
  __shared__ float red[256];
  int i=blockIdx.x;
  float a=0;
  for (int j=threadIdx.x;j<MN;j+=256) a+=S[(size_t)i*MN+j];
  float r=blockReduceSum256(a,red);
  if (threadIdx.x==0) rs[i]=r;
}
__global__ __launch_bounds__(256) void colsum_kernel(const float* __restrict__ S, float* __restrict__ cs){
  __shared__ float red[16][17];
  int j0=blockIdx.x*16;
  int tx=threadIdx.x&15, ty=threadIdx.x>>4;
  float a=0;
  for (int i=ty;i<MN;i+=16) a+=S[(size_t)i*MN + j0+tx];
  red[ty][tx]=a; __syncthreads();
  if (ty==0){
    float s=0;
    #pragma unroll
    for (int q=0;q<16;q++) s+=red[q][tx];
    cs[j0+tx]=s;
  }
}
// dual normalization fused with coarse histogram pass
__global__ __launch_bounds__(256) void dualnorm_hist_kernel(
    float* __restrict__ S, const float* __restrict__ rs, const float* __restrict__ cs,
    unsigned* __restrict__ partial){
  __shared__ unsigned lh[256];
  lh[threadIdx.x]=0u; __syncthreads();
  for (int idx=blockIdx.x*256+threadIdx.x; idx<MN*MN; idx+=gridDim.x*256){
    int i=idx>>10, j=idx&1023;
    float v=S[idx];
    v=(v/(rs[i]+EPSV))*(v/(cs[j]+EPSV));
    S[idx]=v;
    if (v>0.0f) atomicAdd(&lh[__float_as_uint(v)>>24],1u);
  }
  __syncthreads();
  partial[blockIdx.x*256+threadIdx.x]=lh[threadIdx.x];
}

// ---------- deterministic top-k machinery ----------
__global__ __launch_bounds__(256) void scan_coarse_kernel(
    const unsigned* __restrict__ partial, int nblk, int k, unsigned* __restrict__ meta){
  __shared__ unsigned h[256];
  int t=threadIdx.x;
  unsigned a=0;
  for (int i=0;i<nblk;i++) a+=partial[(size_t)i*256+t];
  h[t]=a; __syncthreads();
  if (t==0){
    unsigned cum=0; int cb=-1; unsigned above=0;
    for (int b=255;b>=0;b--){
      if (cum+h[b] >= (unsigned)k){ cb=b; above=cum; break; }
      cum+=h[b];
    }
    if (cb<0){ cb=0; above=cum-h[0]; }
    meta[2]=(unsigned)cb; meta[3]=above;
  }
}
__global__ __launch_bounds__(256) void hist_fine_kernel(
    const float* __restrict__ arr, int n, const unsigned* __restrict__ meta,
    unsigned* __restrict__ partial){
  __shared__ unsigned lh[256];
  lh[threadIdx.x]=0u; __syncthreads();
  unsigned CB=meta[2];
  for (int i=blockIdx.x*256+threadIdx.x; i<n; i+=gridDim.x*256){
    float v=arr[i];
    unsigned b=__float_as_uint(v);
    if (v>0.0f && (b>>24)==CB) atomicAdd(&lh[(b>>16)&255u],1u);
  }
  __syncthreads();
  partial[blockIdx.x*256+threadIdx.x]=lh[threadIdx.x];
}
__global__ __launch_bounds__(256) void scan_fine_kernel(
    const unsigned* __restrict__ partial, int nblk, int k, unsigned* __restrict__ meta){
  __shared__ unsigned h[256];
  int t=threadIdx.x;
  unsigned a=0;
  for (int i=0;i<nblk;i++) a+=partial[(size_t)i*256+t];
  h[t]=a; __syncthreads();
  if (t==0){
    unsigned CB=meta[2];
    unsigned cum=meta[3]; int sb=0;
    for (int b=255;b>=0;b--){
      if (cum+h[b] >= (unsigned)k){ sb=b; break; }
      cum+=h[b];
    }
    meta[0]=CB*256u+(unsigned)sb;
    meta[1]=0u;
  }
}
__global__ void compact_kernel(const float* __restrict__ arr, int n,
                               const unsigned* __restrict__ meta,
                               float* __restrict__ cv, int* __restrict__ ci,
                               unsigned* __restrict__ cnt){
  unsigned T=meta[0];
  for (int i=blockIdx.x*blockDim.x+threadIdx.x; i<n; i+=gridDim.x*blockDim.x){
    float v=arr[i];
    if (v>0.0f && (__float_as_uint(v)>>16)>=T){
      unsigned p=atomicAdd(cnt,1u);
      if (p<CCAP){ cv[p]=v; ci[p]=i; }
    }
  }
}
__global__ __launch_bounds__(256) void rank_coarse_kernel(
    const float* __restrict__ cv, const int* __restrict__ ci, const unsigned* __restrict__ meta,
    int* __restrict__ ti, int* __restrict__ si){
  int c=(int)meta[1]; if (c>CCAP) c=CCAP;
  int t=blockIdx.x*256+threadIdx.x;
  if (t>=c) return;
  float v=cv[t]; int idx=ci[t];
  int rk=0;
  for (int j=0;j<c;j++){
    float vj=cv[j]; int ij=ci[j];
    rk += (vj>v || (vj==v && ij<idx)) ? 1 : 0;
  }
  if (rk<BCORR){ ti[rk]=idx/MN; si[rk]=idx%MN; }
}
__global__ __launch_bounds__(256) void rank_fine_kernel(
    const float* __restrict__ cv, const int* __restrict__ ci, const unsigned* __restrict__ meta,
    const int* __restrict__ sel_t, const int* __restrict__ sel_s,
    const float* __restrict__ tpts, const float* __restrict__ spts,
    float* __restrict__ tp, float* __restrict__ sp, float* __restrict__ cs){
  int c=(int)meta[1]; if (c>CCAP) c=CCAP;
  int t=blockIdx.x*256+threadIdx.x;
  if (t>=c) return;
  float v=cv[t]; int idx=ci[t];
  int rk=0;
  for (int j=0;j<c;j++){
    float vj=cv[j]; int ij=ci[j];
    rk += (vj>v || (vj==v && ij<idx)) ? 1 : 0;
  }
  if (rk<OUTC){
    int b=idx>>12, r=(idx>>6)&63, cc=idx&63;
    int tpi=sel_t[b*KK+r], spi=sel_s[b*KK+cc];
    float tx=0,ty=0,tz=0,sx=0,sy=0,sz=0;
    if (tpi<NPTS){ tx=tpts[tpi*3]; ty=tpts[tpi*3+1]; tz=tpts[tpi*3+2]; }
    if (spi<NPTS){ sx=spts[spi*3]; sy=spts[spi*3+1]; sz=spts[spi*3+2]; }
    tp[rk*3+0]=tx; tp[rk*3+1]=ty; tp[rk*3+2]=tz;
    sp[rk*3+0]=sx; sp[rk*3+1]=sy; sp[rk*3+2]=sz;
    cs[rk]=v;
  }
}

// ---------- patch assembly / OT / fine ----------
__global__ __launch_bounds__(256) void sel_feat_kernel(
    const int* __restrict__ cib, const int* __restrict__ knn,
    const float* __restrict__ ptf,
    const float* __restrict__ W, const float* __restrict__ bias,
    float* __restrict__ out, int* __restrict__ sel){
  __shared__ float Xs[64][64];   // [k][r]
  __shared__ float Ws[64][64];   // [k][o]
  __shared__ float pvf[64];
  int bj=blockIdx.x>>2, bo=blockIdx.x&3;
  int t=threadIdx.x, r=t&63, kq=t>>6, tx=t&15, ty=t>>4;
  int p=knn[cib[bj]*KK+r];
  if (kq==0){
    pvf[r]=(p!=NPTS)?1.f:0.f;
    if (bo==0) sel[bj*KK+r]=p;
  }
  const float* xr=ptf+(size_t)p*DPT+kq*16;
  #pragma unroll
  for (int j4=0;j4<4;j4++){
    float4 v=(p==NPTS)? make_float4(0.f,0.f,0.f,0.f) : *(const float4*)(xr+4*j4);
    Xs[kq*16+4*j4+0][r]=v.x; Xs[kq*16+4*j4+1][r]=v.y;
    Xs[kq*16+4*j4+2][r]=v.z; Xs[kq*16+4*j4+3][r]=v.w;
  }
  const float* wr=W+(size_t)(bo*64+r)*DPT+kq*16;
  #pragma unroll
  for (int j4=0;j4<4;j4++){
    float4 w=*(const float4*)(wr+4*j4);
    Ws[kq*16+4*j4+0][r]=w.x; Ws[kq*16+4*j4+1][r]=w.y;
    Ws[kq*16+4*j4+2][r]=w.z; Ws[kq*16+4*j4+3][r]=w.w;
  }
  __syncthreads();
  float acc[4][4]={};
  #pragma unroll
  for (int kk=0;kk<64;kk++){
    float4 a4=*(const float4*)(&Xs[kk][4*ty]);
    float4 w4=*(const float4*)(&Ws[kk][4*tx]);
    float av[4]={a4.x,a4.y,a4.z,a4.w};
    float wv[4]={w4.x,w4.y,w4.z,w4.w};
    #pragma unroll
    for (int i=0;i<4;i++)
      #pragma unroll
      for (int j=0;j<4;j++) acc[i][j]=fmaf(av[i],wv[j],acc[i][j]);
  }
  #pragma unroll
  for (int i=0;i<4;i++){
    int rr=4*ty+i;
    #pragma unroll
    for (int j=0;j<4;j++){
      int oo=4*tx+j;
      float v=acc[i][j]+bias[bo*64+oo];
      out[(size_t)(bj*64+rr)*DN + bo*64+oo]= (pvf[rr]>0.f)? v : 0.0f;
    }
  }
}

// OT input P (65x65) per batch as tiled GEMM + dustbin/mask epilogue
__global__ __launch_bounds__(256) void pbuild_kernel(
    const float* __restrict__ ft, const float* __restrict__ fs,
    const int* __restrict__ sel_t, const int* __restrict__ sel_s,
    const float* __restrict__ alpha_p, float* __restrict__ P){
  __shared__ float tas[64][64];
  __shared__ float sbs[64][64];
  __shared__ float tmv[64], smv[64];
  int b=blockIdx.x, t=threadIdx.x;
  int r=t&63, kq=t>>6, tx=t&15, ty=t>>4;
  if (kq==0) tmv[r]=(sel_t[b*KK+r]!=NPTS)?1.f:0.f;
  if (kq==1) smv[r]=(sel_s[b*KK+r]!=NPTS)?1.f:0.f;
  float acc[4][4]={};
  const float* tb=ft+(size_t)b*KK*DN;
  const float* sb=fs+(size_t)b*KK*DN;
  for (int kc=0;kc<DN;kc+=64){
    __syncthreads();
    const float* tr_=tb+(size_t)r*DN+kc+kq*16;
    const float* sr_=sb+(size_t)r*DN+kc+kq*16;
    #pragma unroll
    for (int j4=0;j4<4;j4++){
      float4 v=*(const float4*)(tr_+4*j4);
      tas[kq*16+4*j4+0][r]=v.x; tas[kq*16+4*j4+1][r]=v.y;
      tas[kq*16+4*j4+2][r]=v.z; tas[kq*16+4*j4+3][r]=v.w;
      float4 w=*(const float4*)(sr_+4*j4);
      sbs[kq*16+4*j4+0][r]=w.x; sbs[kq*16+4*j4+1][r]=w.y;
      sbs[kq*16+4*j4+2][r]=w.z; sbs[kq*16+4*j4+3][r]=w.w;
    }
    __syncthreads();
    #pragma unroll
    for (int kk=0;kk<64;kk++){
      float4 a4=*(const float4*)(&tas[kk][4*ty]);
      float4 b4=*(const float4*)(&sbs[kk][4*tx]);
      float av[4]={a4.x,a4.y,a4.z,a4.w};
      float bv[4]={b4.x,b4.y,b4.z,b4.w};
      #pragma unroll
      for (int i=0;i<4;i++)
        #pragma unroll
        for (int j=0;j<4;j++) acc[i][j]=fmaf(av[i],bv[j],acc[i][j]);
    }
  }
  __syncthreads();
  float alpha=alpha_p[0];
  float* Pb=P+(size_t)b*65*65;
  #pragma unroll
  for (int i=0;i<4;i++){
    int rr=4*ty+i;
    bool tok=tmv[rr]>0.f;
    #pragma unroll
    for (int j=0;j<4;j++){
      int cc=4*tx+j;
      bool invm=(!tok)||(smv[cc]<=0.f);
      Pb[rr*65+cc]= invm ? NEGV : acc[i][j]*0.0625f;
    }
  }
  if (t<64){
    Pb[64*65+t]=(smv[t]<=0.f)? NEGV : alpha;
    Pb[t*65+64]=(tmv[t]<=0.f)? NEGV : alpha;
  }
  if (t==64) Pb[64*65+64]=alpha;
}

// Sinkhorn linear-domain, 4 WAVES per batch, column-split.
// Wave w owns cols [16w,16w+16): lane l keeps Km[l][chunk] (aQ), Km[chunk][l] (bQ),
// and replicated dustbin chunks (r64Q,c64Q) in VGPRs (~64 regs, no spill).
// Half-step: per-wave partial dot (4 uniform float4 reads + 48 fma) -> LDS part ->
// barrier -> redundant combine in all waves (4 scalar reads + float4 dustbin read).
__global__ __launch_bounds__(256,1) void ot_kernel(
    float* __restrict__ P, const int* __restrict__ sel_t, const int* __restrict__ sel_s){
  __shared__ float Ps[65*65];
  __shared__ __align__(16) float part[4][72];
  __shared__ __align__(16) float part64[4];
  __shared__ __align__(16) float partsv[4];
  __shared__ __align__(16) float Vs[72];
  __shared__ __align__(16) float Us[72];
  __shared__ float ufs[65], vfs[65];
  int b=blockIdx.x, t=threadIdx.x, w=t>>6, l=t&63;
  float* Pg=P+(size_t)b*4225;
  for (int e=t;e<4225;e+=256) Ps[e]=Pg[e];
  bool rv=(sel_t[b*KK+l]!=NPTS);
  bool cv=(sel_s[b*KK+l]!=NPTS);
  int nr=(int)__popcll(__ballot(rv));
  int nc=(int)__popcll(__ballot(cv));
  float inv=1.0f/(float)(nr+nc);
  float nrm=-logf((float)(nr+nc));
  float mu_l=inv, nu_l=inv, mu64=(float)nc*inv, nu64=(float)nr*inv;
  bool anyInvR=(nr<KK), anyInvC=(nc<KK);
  if (w==0){ Vs[l]=1.0f; if(l==0) Vs[64]=1.0f; }
  __syncthreads();
  const int c0=16*w;
  float aQ[16], bQ[16], r64Q[16], c64Q[16];
  #pragma unroll
  for (int j=0;j<16;j++){
    aQ[j]  =expf(Ps[l*65+c0+j]);        // Km[l][c0+j]
    bQ[j]  =expf(Ps[(c0+j)*65+l]);      // Km[c0+j][l]
    r64Q[j]=expf(Ps[64*65+c0+j]);       // Km[64][c0+j] (wave-uniform)
    c64Q[j]=expf(Ps[(c0+j)*65+64]);     // Km[c0+j][64] (wave-uniform)
  }
  float a64=expf(Ps[l*65+64]);          // Km[l][64]
  float b64v=expf(Ps[64*65+l]);         // Km[64][l]
  float k6464=expf(Ps[64*65+64]);
  float U_l=1.0f, V_l=1.0f;

  for (int it=0; it<OTI; ++it){
    // ---- u-pass: partial row dots over this wave's column chunk ----
    float p0=0,p1=0,p2=0,p3=0, d0=0,d1=0,d2=0,d3=0, z0=0,z1=0,z2=0,z3=0;
    #pragma unroll
    for (int j4=0;j4<4;j4++){
      float4 vv=*(const float4*)(Vs+c0+4*j4);          // uniform broadcast
      p0=fmaf(aQ[4*j4+0],vv.x,p0); p1=fmaf(aQ[4*j4+1],vv.y,p1);
      p2=fmaf(aQ[4*j4+2],vv.z,p2); p3=fmaf(aQ[4*j4+3],vv.w,p3);
      d0=fmaf(r64Q[4*j4+0],vv.x,d0); d1=fmaf(r64Q[4*j4+1],vv.y,d1);
      d2=fmaf(r64Q[4*j4+2],vv.z,d2); d3=fmaf(r64Q[4*j4+3],vv.w,d3);
      z0+=vv.x; z1+=vv.y; z2+=vv.z; z3+=vv.w;
    }
    part[w][l]=(p0+p1)+(p2+p3);
    if (l==0){ part64[w]=(d0+d1)+(d2+d3); partsv[w]=(z0+z1)+(z2+z3); }
    __syncthreads();
    {
      float s=part[0][l]+part[1][l]+part[2][l]+part[3][l];
      float4 d4=*(const float4*)part64;
      float V64=Vs[64];
      float srow=s+a64*V64;
      float s64=(d4.x+d4.y)+(d4.z+d4.w)+k6464*V64;
      float U64=mu64/s64;
      if (anyInvR){
        float4 z4=*(const float4*)partsv;
        float sv=(z4.x+z4.y)+(z4.z+z4.w)+V64;
        U_l = rv ? (mu_l/srow) : (1.0f/sv);
      } else U_l = mu_l/srow;
      if (w==0){ Us[l]=U_l; if(l==0) Us[64]=U64; }
    }
    __syncthreads();
    // ---- v-pass: partial column dots over this wave's row chunk ----
    float q0=0,q1=0,q2=0,q3=0, e0=0,e1=0,e2=0,e3=0, y0=0,y1=0,y2=0,y3=0;
    #pragma unroll
    for (int j4=0;j4<4;j4++){
      float4 uu=*(const float4*)(Us+c0+4*j4);
      q0=fmaf(bQ[4*j4+0],uu.x,q0); q1=fmaf(bQ[4*j4+1],uu.y,q1);
      q2=fmaf(bQ[4*j4+2],uu.z,q2); q3=fmaf(bQ[4*j4+3],uu.w,q3);
      e0=fmaf(c64Q[4*j4+0],uu.x,e0); e1=fmaf(c64Q[4*j4+1],uu.y,e1);
      e2=fmaf(c64Q[4*j4+2],uu.z,e2); e3=fmaf(c64Q[4*j4+3],uu.w,e3);
      y0+=uu.x; y1+=uu.y; y2+=uu.z; y3+=uu.w;
    }
    part[w][l]=(q0+q1)+(q2+q3);
    if (l==0){ part64[w]=(e0+e1)+(e2+e3); partsv[w]=(y0+y1)+(y2+y3); }
    __syncthreads();
    {
      float sc=part[0][l]+part[1][l]+part[2][l]+part[3][l];
      float4 e4=*(const float4*)part64;
      float U64=Us[64];
      float scol=sc+b64v*U64;
      float s64v=(e4.x+e4.y)+(e4.z+e4.w)+k6464*U64;
      float V64=nu64/s64v;
      if (anyInvC){
        float4 y4=*(const float4*)partsv;
        float su=(y4.x+y4.y)+(y4.z+y4.w)+U64;
        V_l = cv ? (nu_l/scol) : (1.0f/su);
      } else V_l = nu_l/scol;
      if (w==0){ Vs[l]=V_l; if(l==0) Vs[64]=V64; }
    }
    __syncthreads();
  }
  if (w==0){
    ufs[l]=logf(U_l); vfs[l]=logf(V_l);
    if (l==0){ ufs[64]=logf(Us[64]); vfs[64]=logf(Vs[64]); }
  }
  __syncthreads();
  for (int e=t;e<4225;e+=256){
    int r=e/65, c=e-65*r;
    Pg[e]=Ps[e]+ufs[r]+vfs[c]-nrm;
  }
}

// fine prep fused with coarse histogram of the masked scores
__global__ __launch_bounds__(256) void fineprep_kernel(
    const float* __restrict__ P, const int* __restrict__ sel_t, const int* __restrict__ sel_s,
    float* __restrict__ smout, unsigned* __restrict__ partial){
  __shared__ float s[KK*KK];
  __shared__ unsigned long long rowm[KK], colm[KK];
  __shared__ int tmk[KK], smk[KK];
  __shared__ unsigned lh[256];
  int b=blockIdx.x, t=threadIdx.x;
  lh[t]=0u;
  const float* Pb=P+(size_t)b*65*65;
  for (int e=t;e<KK*KK;e+=256){
    int r=e>>6, c=e&63;
    s[e]=expf(Pb[r*65+c]);
  }
  if (t<KK){ tmk[t]=(sel_t[b*KK+t]!=NPTS); smk[t]=(sel_s[b*KK+t]!=NPTS); }
  __syncthreads();
  if (t<KK){
    float v1=-1,v2=-1,v3=-1; int i1=0,i2=0,i3=0;
    const float* row=s+t*KK;
    for (int c=0;c<KK;c++){ float v=row[c];
      if (v>v1){v3=v2;i3=i2;v2=v1;i2=i1;v1=v;i1=c;}
      else if (v>v2){v3=v2;i3=i2;v2=v;i2=c;}
      else if (v>v3){v3=v;i3=c;}
    }
    rowm[t]=(1ULL<<i1)|(1ULL<<i2)|(1ULL<<i3);
  } else if (t<2*KK){
    int c=t-KK;
    float v1=-1,v2=-1,v3=-1; int i1=0,i2=0,i3=0;
    for (int r=0;r<KK;r++){ float v=s[r*KK+c];
      if (v>v1){v3=v2;i3=i2;v2=v1;i2=i1;v1=v;i1=r;}
      else if (v>v2){v3=v2;i3=i2;v2=v;i2=r;}
      else if (v>v3){v3=v;i3=r;}
    }
    colm[c]=(1ULL<<i1)|(1ULL<<i2)|(1ULL<<i3);
  }
  __syncthreads();
  for (int e=t;e<KK*KK;e+=256){
    int r=e>>6, c=e&63;
    float v=s[e];
    bool keep = ((rowm[r]>>c)&1ULL) && ((colm[c]>>r)&1ULL) && (v>0.05f) && tmk[r] && smk[c];
    float o= keep? v : 0.0f;
    smout[(size_t)b*KK*KK+e]=o;
    if (o>0.0f) atomicAdd(&lh[__float_as_uint(o)>>24],1u);
  }
  __syncthreads();
  partial[b*256+t]=lh[t];
}

extern "C" void kernel_launch(void* const* d_in, const int* in_sizes, int n_in,
                              void* d_out, int out_size, void* d_ws, size_t ws_size,
                              hipStream_t stream){
  const float* src_pts=(const float*)d_in[0];
  const float* tgt_pts=(const float*)d_in[1];
  const float* src_pf =(const float*)d_in[2];
  const float* tgt_pf =(const float*)d_in[3];
  const float* src_nf =(const float*)d_in[4];
  const float* tgt_nf =(const float*)d_in[5];
  const float* src_nx =(const float*)d_in[6];
  const float* tgt_nx =(const float*)d_in[7];
  const float* cw=(const float*)d_in[8];
  const float* cb=(const float*)d_in[9];
  const float* fw=(const float*)d_in[10];
  const float* fb=(const float*)d_in[11];
  const float* alpha=(const float*)d_in[12];

  char* ws=(char*)d_ws;
  size_t off=0;
  auto A=[&](size_t bytes)->char*{
    char* p=ws+off; off+=(bytes+255)&~(size_t)255; return p; };

  float* tf    =(float*)A((size_t)MN*DN*4);
  float* sfb   =(float*)A((size_t)MN*DN*4);
  float* tt    =(float*)A(MN*4);
  float* ssv   =(float*)A(MN*4);
  int*   p2n_s =(int*)A((size_t)NPTS*4);
  int*   p2n_t =(int*)A((size_t)NPTS*4);
  int*   cnt_s =(int*)A(MN*4);
  int*   cnt_t =(int*)A(MN*4);
  int*   list_s=(int*)A((size_t)MN*CAPL*4);
  int*   list_t=(int*)A((size_t)MN*CAPL*4);
  int*   knn_s =(int*)A((size_t)MN*KK*4);
  int*   knn_t =(int*)A((size_t)MN*KK*4);
  float* Smat  =(float*)A((size_t)MN*MN*4);
  unsigned* partial=(unsigned*)A((size_t)HBLK*256*4);
  unsigned* meta=(unsigned*)A(256);
  float* cand_v=(float*)A((size_t)CCAP*4);
  int*   cand_i=(int*)A((size_t)CCAP*4);
  int*   ci_t  =(int*)A(BCORR*4);
  int*   ci_s  =(int*)A(BCORR*4);
  int*   sel_t =(int*)A((size_t)BCORR*KK*4);
  int*   sel_s =(int*)A((size_t)BCORR*KK*4);
  float* feat_t=(float*)A((size_t)BCORR*KK*DN*4);
  float* feat_s=(float*)A((size_t)BCORR*KK*DN*4);
  float* smf   =(float*)A((size_t)BCORR*KK*KK*4);
  float* rs    =(float*)A(MN*4);
  float* csum  =(float*)A(MN*4);

  float* out=(float*)d_out;
  float* msout=out;
  float* tpout=out+(size_t)BCORR*65*65;
  float* spout=tpout+(size_t)OUTC*3;
  float* csout=spout+(size_t)OUTC*3;

  const int PB=(NPTS+255)/256;

  zero_all_kernel<<<28,256,0,stream>>>(cnt_s,cnt_t,ci_t,ci_s,tpout);
  node_feat_kernel<<<MN,256,0,stream>>>(tgt_nf,cw,cb,tf,tt);
  node_feat_kernel<<<MN,256,0,stream>>>(src_nf,cw,cb,sfb,ssv);
  p2n_kernel<<<PB,256,0,stream>>>(src_pts,src_nx,p2n_s);
  p2n_kernel<<<PB,256,0,stream>>>(tgt_pts,tgt_nx,p2n_t);
  scatter_kernel<<<PB,256,0,stream>>>(p2n_s,cnt_s,list_s);
  scatter_kernel<<<PB,256,0,stream>>>(p2n_t,cnt_t,list_t);
  knn_kernel<<<MN,256,0,stream>>>(src_pts,src_nx,cnt_s,list_s,knn_s);
  knn_kernel<<<MN,256,0,stream>>>(tgt_pts,tgt_nx,cnt_t,list_t,knn_t);

  coarse_score_kernel<<<256,256,0,stream>>>(tf,sfb,tt,ssv,cnt_t,cnt_s,Smat);
  rowsum_kernel<<<MN,256,0,stream>>>(Smat,rs);
  colsum_kernel<<<64,256,0,stream>>>(Smat,csum);
  dualnorm_hist_kernel<<<HBLK,256,0,stream>>>(Smat,rs,csum,partial);

  scan_coarse_kernel<<<1,256,0,stream>>>(partial,HBLK,BCORR,meta);
  hist_fine_kernel<<<HBLK,256,0,stream>>>(Smat,MN*MN,meta,partial);
  scan_fine_kernel<<<1,256,0,stream>>>(partial,HBLK,BCORR,meta);
  compact_kernel<<<2048,256,0,stream>>>(Smat,MN*MN,meta,cand_v,cand_i,meta+1);
  rank_coarse_kernel<<<CCAP/256,256,0,stream>>>(cand_v,cand_i,meta,ci_t,ci_s);

  sel_feat_kernel<<<1024,256,0,stream>>>(ci_t,knn_t,tgt_pf,fw,fb,feat_t,sel_t);
  sel_feat_kernel<<<1024,256,0,stream>>>(ci_s,knn_s,src_pf,fw,fb,feat_s,sel_s);

  pbuild_kernel<<<BCORR,256,0,stream>>>(feat_t,feat_s,sel_t,sel_s,alpha,msout);
  ot_kernel<<<BCORR,256,0,stream>>>(msout,sel_t,sel_s);

  fineprep_kernel<<<BCORR,256,0,stream>>>(msout,sel_t,sel_s,smf,partial);
  scan_coarse_kernel<<<1,256,0,stream>>>(partial,BCORR,OUTC,meta);
  hist_fine_kernel<<<HBLK,256,0,stream>>>(smf,BCORR*KK*KK,meta,partial);
  scan_fine_kernel<<<1,256,0,stream>>>(partial,HBLK,OUTC,meta);
  compact_kernel<<<2048,256,0,stream>>>(smf,BCORR*KK*KK,meta,cand_v,cand_i,meta+1);
  rank_fine_kernel<<<CCAP/256,256,0,stream>>>(cand_v,cand_i,meta,sel_t,sel_s,
                                              tgt_pts,src_pts,tpout,spout,csout);
}

// Round 9
// 719.127 us; speedup vs baseline: 1.7844x; 1.0905x over previous
//
#include <hip/hip_runtime.h>
#include <math.h>

#define NPTS 50000
#define MN 1024
#define KK 64
#define DPT 64
#define DN 256
#define BCORR 256
#define OUTC 1024
#define OTI 100
#define NEGV (-1e4f)
#define EPSV 1e-8f
#define CAPL 512
#define CCAP 16384
#define HBLK 256   // blocks for histogram passes

// ---------------- utility ----------------
__global__ void zero_all_kernel(int* cnt_s, int* cnt_t, int* ci_t, int* ci_s,
                                float* tpout){
  int t=blockIdx.x*256+threadIdx.x;
  if (t<MN){ cnt_s[t]=0; cnt_t[t]=0; }
  if (t<BCORR){ ci_t[t]=0; ci_s[t]=0; }
  for (int i=t;i<OUTC*3*2+OUTC;i+=gridDim.x*256) tpout[i]=0.0f;
}

__device__ __forceinline__ float blockReduceSum256(float v, float* red){
  int t=threadIdx.x;
  red[t]=v; __syncthreads();
  #pragma unroll
  for (int s=128;s>0;s>>=1){ if(t<s) red[t]+=red[t+s]; __syncthreads(); }
  float r=red[0]; __syncthreads();
  return r;
}

// node feats (fused tgt+src): out = l2norm(x @ W^T + b); sq = sum(out^2)
__global__ __launch_bounds__(256) void node_feat_kernel(
    const float* __restrict__ xt, const float* __restrict__ xs_,
    const float* __restrict__ W, const float* __restrict__ bias,
    float* __restrict__ outt, float* __restrict__ outs,
    float* __restrict__ sqt, float* __restrict__ sqs){
  __shared__ float xs[DN];
  __shared__ float red[256];
  int m=blockIdx.x, i=threadIdx.x;
  const float* x=(m<MN)? xt:xs_;
  float* out=(m<MN)? outt:outs;
  float* sq=(m<MN)? sqt:sqs;
  int mm=(m<MN)? m:m-MN;
  xs[i]=x[mm*DN+i];
  __syncthreads();
  float acc=bias[i];
  const float* wr=W+(size_t)i*DN;
  for (int k=0;k<DN;k++) acc=fmaf(wr[k],xs[k],acc);
  float ssq=blockReduceSum256(acc*acc,red);
  float o=acc/sqrtf(ssq);
  out[mm*DN+i]=o;
  float s2=blockReduceSum256(o*o,red);
  if(i==0) sq[mm]=s2;
}

// nearest node per point (fused src+tgt); nodes packed float4 (x,y,z,|n|^2)
__global__ __launch_bounds__(256) void p2n_kernel(
    const float* __restrict__ pts_s, const float* __restrict__ nd_s, int* __restrict__ o_s,
    const float* __restrict__ pts_t, const float* __restrict__ nd_t, int* __restrict__ o_t,
    int pb){
  __shared__ __align__(16) float4 nd[MN];
  int which=blockIdx.x>=pb;
  const float* pts=which? pts_t:pts_s;
  const float* nodes=which? nd_t:nd_s;
  int* p2n=which? o_t:o_s;
  int blk=which? blockIdx.x-pb : blockIdx.x;
  for (int j=threadIdx.x;j<MN;j+=256){
    float a=nodes[j*3+0], b=nodes[j*3+1], c=nodes[j*3+2];
    nd[j]=make_float4(a,b,c,a*a+b*b+c*c);
  }
  __syncthreads();
  int id=blk*256+threadIdx.x;
  if (id>=NPTS) return;
  float px=pts[id*3+0], py=pts[id*3+1], pz=pts[id*3+2];
  float pp=px*px+py*py+pz*pz;
  float best=3.4e38f; int bi=0;
  for (int j=0;j<MN;j++){
    float4 n=nd[j];
    float d=pp+n.w-2.0f*(px*n.x+py*n.y+pz*n.z);
    if (d<best){best=d;bi=j;}
  }
  p2n[id]=bi;
}

__global__ __launch_bounds__(256) void scatter_kernel(
    const int* __restrict__ p_s, int* __restrict__ c_s, int* __restrict__ l_s,
    const int* __restrict__ p_t, int* __restrict__ c_t, int* __restrict__ l_t,
    int pb){
  int which=blockIdx.x>=pb;
  const int* p2n=which? p_t:p_s;
  int* cnt=which? c_t:c_s;
  int* list=which? l_t:l_s;
  int blk=which? blockIdx.x-pb : blockIdx.x;
  int id=blk*256+threadIdx.x;
  if (id>=NPTS) return;
  int n=p2n[id];
  int t=atomicAdd(&cnt[n],1);
  if (t<CAPL) list[(size_t)n*CAPL+t]=id;
}

// per-node kNN (fused src+tgt)
__global__ __launch_bounds__(256) void knn_kernel(
    const float* __restrict__ pts_s, const float* __restrict__ nd_s,
    const int* __restrict__ c_s, const int* __restrict__ l_s, int* __restrict__ k_s,
    const float* __restrict__ pts_t, const float* __restrict__ nd_t,
    const int* __restrict__ c_t, const int* __restrict__ l_t, int* __restrict__ k_t){
  __shared__ float ds[CAPL];
  __shared__ int is[CAPL];
  int which=blockIdx.x>=MN;
  const float* pts=which? pts_t:pts_s;
  const float* nodes=which? nd_t:nd_s;
  const int* cnt=which? c_t:c_s;
  const int* list=which? l_t:l_s;
  int* knn=which? k_t:k_s;
  int m=which? blockIdx.x-MN : blockIdx.x;
  int c=cnt[m]; if (c>CAPL) c=CAPL;
  float ax=nodes[m*3+0], ay=nodes[m*3+1], az=nodes[m*3+2];
  float nn2=ax*ax+ay*ay+az*az;
  for (int e=threadIdx.x;e<c;e+=256){
    int p=list[(size_t)m*CAPL+e];
    float px=pts[p*3+0],py=pts[p*3+1],pz=pts[p*3+2];
    float pp=px*px+py*py+pz*pz;
    ds[e]=pp+nn2-2.0f*(px*ax+py*ay+pz*az);
    is[e]=p;
  }
  for (int k=threadIdx.x;k<KK;k+=256) knn[m*KK+k]=NPTS;
  __syncthreads();
  for (int e=threadIdx.x;e<c;e+=256){
    float d=ds[e]; int p=is[e]; int r=0;
    for (int j=0;j<c;j++){
      float dj=ds[j];
      r += (dj<d || (dj==d && is[j]<p)) ? 1 : 0;
    }
    if (r<KK) knn[m*KK+r]=p;
  }
}

// coarse scores as tiled GEMM
__global__ __launch_bounds__(256) void coarse_score_kernel(
    const float* __restrict__ tf, const float* __restrict__ sf,
    const float* __restrict__ tt, const float* __restrict__ ssv,
    const int* __restrict__ cnt_t, const int* __restrict__ cnt_s, float* __restrict__ S){
  __shared__ float tas[64][64];   // [k][r]
  __shared__ float sbs[64][64];   // [k][c]
  __shared__ float tta[64], ssa[64], tva[64], sva[64];
  int bi=blockIdx.x>>4, bj=blockIdx.x&15;
  int t=threadIdx.x, r=t&63, kq=t>>6, tx=t&15, ty=t>>4;
  if (kq==0){ tta[r]=tt[bi*64+r]; tva[r]=(cnt_t[bi*64+r]>0)?1.f:0.f; }
  if (kq==1){ ssa[r]=ssv[bj*64+r]; sva[r]=(cnt_s[bj*64+r]>0)?1.f:0.f; }
  float acc[4][4]={};
  const float* ta=tf+((size_t)bi*64)*DN;
  const float* sa=sf+((size_t)bj*64)*DN;
  for (int kc=0;kc<DN;kc+=64){
    __syncthreads();
    const float* tr_=ta+(size_t)r*DN+kc+kq*16;
    const float* sr_=sa+(size_t)r*DN+kc+kq*16;
    #pragma unroll
    for (int j4=0;j4<4;j4++){
      float4 v=*(const float4*)(tr_+4*j4);
      tas[kq*16+4*j4+0][r]=v.x; tas[kq*16+4*j4+1][r]=v.y;
      tas[kq*16+4*j4+2][r]=v.z; tas[kq*16+4*j4+3][r]=v.w;
      float4 w=*(const float4*)(sr_+4*j4);
      sbs[kq*16+4*j4+0][r]=w.x; sbs[kq*16+4*j4+1][r]=w.y;
      sbs[kq*16+4*j4+2][r]=w.z; sbs[kq*16+4*j4+3][r]=w.w;
    }
    __syncthreads();
    #pragma unroll
    for (int kk=0;kk<64;kk++){
      float4 a4=*(const float4*)(&tas[kk][4*ty]);
      float4 b4=*(const float4*)(&sbs[kk][4*tx]);
      float av[4]={a4.x,a4.y,a4.z,a4.w};
      float bv[4]={b4.x,b4.y,b4.z,b4.w};
      #pragma unroll
      for (int i=0;i<4;i++)
        #pragma unroll
        for (int j=0;j<4;j++) acc[i][j]=fmaf(av[i],bv[j],acc[i][j]);
    }
  }
  __syncthreads();
  #pragma unroll
  for (int i=0;i<4;i++){
    int rr=4*ty+i;
    #pragma unroll
    for (int j=0;j<4;j++){
      int cc=4*tx+j;
      float d=tta[rr]+ssa[cc]-2.0f*acc[i][j];
      float v=expf(-d);
      S[(size_t)(bi*64+rr)*MN + bj*64+cc]=(tva[rr]>0.f && sva[cc]>0.f)? v:0.0f;
    }
  }
}

// fused row+col sums: blocks 0..1023 rowsum, 1024..1087 colsum(16 cols each)
__global__ __launch_bounds__(256) void sums_kernel(
    const float* __restrict__ S, float* __restrict__ rs, float* __restrict__ cs){
  __shared__ float red[256];
  __shared__ float red2[16][17];
  if (blockIdx.x<MN){
    int i=blockIdx.x;
    float a=0;
    for (int j=threadIdx.x;j<MN;j+=256) a+=S[(size_t)i*MN+j];
    float r=blockReduceSum256(a,red);
    if (threadIdx.x==0) rs[i]=r;
  } else {
    int j0=(blockIdx.x-MN)*16;
    int tx=threadIdx.x&15, ty=threadIdx.x>>4;
    float a=0;
    for (int i=ty;i<MN;i+=16) a+=S[(size_t)i*MN + j0+tx];
    red2[ty][tx]=a; __syncthreads();
    if (ty==0){
      float s=0;
      #pragma unroll
      for (int q=0;q<16;q++) s+=red2[q][tx];
      cs[j0+tx]=s;
    }
  }
}
// dual normalization fused with coarse histogram pass
__global__ __launch_bounds__(256) void dualnorm_hist_kernel(
    float* __restrict__ S, const float* __restrict__ rs, const float* __restrict__ cs,
    unsigned* __restrict__ partial){
  __shared__ unsigned lh[256];
  lh[threadIdx.x]=0u; __syncthreads();
  for (int idx=blockIdx.x*256+threadIdx.x; idx<MN*MN; idx+=gridDim.x*256){
    int i=idx>>10, j=idx&1023;
    float v=S[idx];
    v=(v/(rs[i]+EPSV))*(v/(cs[j]+EPSV));
    S[idx]=v;
    if (v>0.0f) atomicAdd(&lh[__float_as_uint(v)>>24],1u);
  }
  __syncthreads();
  partial[blockIdx.x*256+threadIdx.x]=lh[threadIdx.x];
}

// ---------- deterministic top-k machinery ----------
__global__ __launch_bounds__(256) void scan_coarse_kernel(
    const unsigned* __restrict__ partial, int nblk, int k, unsigned* __restrict__ meta){
  __shared__ unsigned h[256];
  int t=threadIdx.x;
  unsigned a=0;
  for (int i=0;i<nblk;i++) a+=partial[(size_t)i*256+t];
  h[t]=a; __syncthreads();
  if (t==0){
    unsigned cum=0; int cb=-1; unsigned above=0;
    for (int b=255;b>=0;b--){
      if (cum+h[b] >= (unsigned)k){ cb=b; above=cum; break; }
      cum+=h[b];
    }
    if (cb<0){ cb=0; above=cum-h[0]; }
    meta[2]=(unsigned)cb; meta[3]=above;
  }
}
__global__ __launch_bounds__(256) void hist_fine_kernel(
    const float* __restrict__ arr, int n, const unsigned* __restrict__ meta,
    unsigned* __restrict__ partial){
  __shared__ unsigned lh[256];
  lh[threadIdx.x]=0u; __syncthreads();
  unsigned CB=meta[2];
  for (int i=blockIdx.x*256+threadIdx.x; i<n; i+=gridDim.x*256){
    float v=arr[i];
    unsigned b=__float_as_uint(v);
    if (v>0.0f && (b>>24)==CB) atomicAdd(&lh[(b>>16)&255u],1u);
  }
  __syncthreads();
  partial[blockIdx.x*256+threadIdx.x]=lh[threadIdx.x];
}
__global__ __launch_bounds__(256) void scan_fine_kernel(
    const unsigned* __restrict__ partial, int nblk, int k, unsigned* __restrict__ meta){
  __shared__ unsigned h[256];
  int t=threadIdx.x;
  unsigned a=0;
  for (int i=0;i<nblk;i++) a+=partial[(size_t)i*256+t];
  h[t]=a; __syncthreads();
  if (t==0){
    unsigned CB=meta[2];
    unsigned cum=meta[3]; int sb=0;
    for (int b=255;b>=0;b--){
      if (cum+h[b] >= (unsigned)k){ sb=b; break; }
      cum+=h[b];
    }
    meta[0]=CB*256u+(unsigned)sb;
    meta[1]=0u;
  }
}
__global__ void compact_kernel(const float* __restrict__ arr, int n,
                               const unsigned* __restrict__ meta,
                               float* __restrict__ cv, int* __restrict__ ci,
                               unsigned* __restrict__ cnt){
  unsigned T=meta[0];
  for (int i=blockIdx.x*blockDim.x+threadIdx.x; i<n; i+=gridDim.x*blockDim.x){
    float v=arr[i];
    if (v>0.0f && (__float_as_uint(v)>>16)>=T){
      unsigned p=atomicAdd(cnt,1u);
      if (p<CCAP){ cv[p]=v; ci[p]=i; }
    }
  }
}
__global__ __launch_bounds__(256) void rank_coarse_kernel(
    const float* __restrict__ cv, const int* __restrict__ ci, const unsigned* __restrict__ meta,
    int* __restrict__ ti, int* __restrict__ si){
  int c=(int)meta[1]; if (c>CCAP) c=CCAP;
  int t=blockIdx.x*256+threadIdx.x;
  if (t>=c) return;
  float v=cv[t]; int idx=ci[t];
  int rk=0;
  for (int j=0;j<c;j++){
    float vj=cv[j]; int ij=ci[j];
    rk += (vj>v || (vj==v && ij<idx)) ? 1 : 0;
  }
  if (rk<BCORR){ ti[rk]=idx/MN; si[rk]=idx%MN; }
}
__global__ __launch_bounds__(256) void rank_fine_kernel(
    const float* __restrict__ cv, const int* __restrict__ ci, const unsigned* __restrict__ meta,
    const int* __restrict__ sel_t, const int* __restrict__ sel_s,
    const float* __restrict__ tpts, const float* __restrict__ spts,
    float* __restrict__ tp, float* __restrict__ sp, float* __restrict__ cs){
  int c=(int)meta[1]; if (c>CCAP) c=CCAP;
  int t=blockIdx.x*256+threadIdx.x;
  if (t>=c) return;
  float v=cv[t]; int idx=ci[t];
  int rk=0;
  for (int j=0;j<c;j++){
    float vj=cv[j]; int ij=ci[j];
    rk += (vj>v || (vj==v && ij<idx)) ? 1 : 0;
  }
  if (rk<OUTC){
    int b=idx>>12, r=(idx>>6)&63, cc=idx&63;
    int tpi=sel_t[b*KK+r], spi=sel_s[b*KK+cc];
    float tx=0,ty=0,tz=0,sx=0,sy=0,sz=0;
    if (tpi<NPTS){ tx=tpts[tpi*3]; ty=tpts[tpi*3+1]; tz=tpts[tpi*3+2]; }
    if (spi<NPTS){ sx=spts[spi*3]; sy=spts[spi*3+1]; sz=spts[spi*3+2]; }
    tp[rk*3+0]=tx; tp[rk*3+1]=ty; tp[rk*3+2]=tz;
    sp[rk*3+0]=sx; sp[rk*3+1]=sy; sp[rk*3+2]=sz;
    cs[rk]=v;
  }
}

// ---------- patch assembly / OT / fine ----------
// gathered point-feature GEMM (fused tgt+src); bo==0 blocks write sel.
__global__ __launch_bounds__(256) void sel_feat_kernel(
    const int* __restrict__ ci_t, const int* __restrict__ knn_t, const float* __restrict__ ptf_t,
    const int* __restrict__ ci_s, const int* __restrict__ knn_s, const float* __restrict__ ptf_s,
    const float* __restrict__ W, const float* __restrict__ bias,
    float* __restrict__ out_t, float* __restrict__ out_s,
    int* __restrict__ sel_tO, int* __restrict__ sel_sO){
  __shared__ float Xs[64][64];   // [k][r]
  __shared__ float Ws[64][64];   // [k][o]
  __shared__ float pvf[64];
  int which=blockIdx.x>=1024;
  const int* cib=which? ci_s:ci_t;
  const int* knn=which? knn_s:knn_t;
  const float* ptf=which? ptf_s:ptf_t;
  float* out=which? out_s:out_t;
  int* sel=which? sel_sO:sel_tO;
  int blk=which? blockIdx.x-1024 : blockIdx.x;
  int bj=blk>>2, bo=blk&3;
  int t=threadIdx.x, r=t&63, kq=t>>6, tx=t&15, ty=t>>4;
  int p=knn[cib[bj]*KK+r];
  if (kq==0){
    pvf[r]=(p!=NPTS)?1.f:0.f;
    if (bo==0) sel[bj*KK+r]=p;
  }
  const float* xr=ptf+(size_t)p*DPT+kq*16;
  #pragma unroll
  for (int j4=0;j4<4;j4++){
    float4 v=(p==NPTS)? make_float4(0.f,0.f,0.f,0.f) : *(const float4*)(xr+4*j4);
    Xs[kq*16+4*j4+0][r]=v.x; Xs[kq*16+4*j4+1][r]=v.y;
    Xs[kq*16+4*j4+2][r]=v.z; Xs[kq*16+4*j4+3][r]=v.w;
  }
  const float* wr=W+(size_t)(bo*64+r)*DPT+kq*16;
  #pragma unroll
  for (int j4=0;j4<4;j4++){
    float4 w=*(const float4*)(wr+4*j4);
    Ws[kq*16+4*j4+0][r]=w.x; Ws[kq*16+4*j4+1][r]=w.y;
    Ws[kq*16+4*j4+2][r]=w.z; Ws[kq*16+4*j4+3][r]=w.w;
  }
  __syncthreads();
  float acc[4][4]={};
  #pragma unroll
  for (int kk=0;kk<64;kk++){
    float4 a4=*(const float4*)(&Xs[kk][4*ty]);
    float4 w4=*(const float4*)(&Ws[kk][4*tx]);
    float av[4]={a4.x,a4.y,a4.z,a4.w};
    float wv[4]={w4.x,w4.y,w4.z,w4.w};
    #pragma unroll
    for (int i=0;i<4;i++)
      #pragma unroll
      for (int j=0;j<4;j++) acc[i][j]=fmaf(av[i],wv[j],acc[i][j]);
  }
  #pragma unroll
  for (int i=0;i<4;i++){
    int rr=4*ty+i;
    #pragma unroll
    for (int j=0;j<4;j++){
      int oo=4*tx+j;
      float v=acc[i][j]+bias[bo*64+oo];
      out[(size_t)(bj*64+rr)*DN + bo*64+oo]= (pvf[rr]>0.f)? v : 0.0f;
    }
  }
}

// OT input P (65x65) per batch as tiled GEMM + dustbin/mask epilogue
__global__ __launch_bounds__(256) void pbuild_kernel(
    const float* __restrict__ ft, const float* __restrict__ fs,
    const int* __restrict__ sel_t, const int* __restrict__ sel_s,
    const float* __restrict__ alpha_p, float* __restrict__ P){
  __shared__ float tas[64][64];
  __shared__ float sbs[64][64];
  __shared__ float tmv[64], smv[64];
  int b=blockIdx.x, t=threadIdx.x;
  int r=t&63, kq=t>>6, tx=t&15, ty=t>>4;
  if (kq==0) tmv[r]=(sel_t[b*KK+r]!=NPTS)?1.f:0.f;
  if (kq==1) smv[r]=(sel_s[b*KK+r]!=NPTS)?1.f:0.f;
  float acc[4][4]={};
  const float* tb=ft+(size_t)b*KK*DN;
  const float* sb=fs+(size_t)b*KK*DN;
  for (int kc=0;kc<DN;kc+=64){
    __syncthreads();
    const float* tr_=tb+(size_t)r*DN+kc+kq*16;
    const float* sr_=sb+(size_t)r*DN+kc+kq*16;
    #pragma unroll
    for (int j4=0;j4<4;j4++){
      float4 v=*(const float4*)(tr_+4*j4);
      tas[kq*16+4*j4+0][r]=v.x; tas[kq*16+4*j4+1][r]=v.y;
      tas[kq*16+4*j4+2][r]=v.z; tas[kq*16+4*j4+3][r]=v.w;
      float4 w=*(const float4*)(sr_+4*j4);
      sbs[kq*16+4*j4+0][r]=w.x; sbs[kq*16+4*j4+1][r]=w.y;
      sbs[kq*16+4*j4+2][r]=w.z; sbs[kq*16+4*j4+3][r]=w.w;
    }
    __syncthreads();
    #pragma unroll
    for (int kk=0;kk<64;kk++){
      float4 a4=*(const float4*)(&tas[kk][4*ty]);
      float4 b4=*(const float4*)(&sbs[kk][4*tx]);
      float av[4]={a4.x,a4.y,a4.z,a4.w};
      float bv[4]={b4.x,b4.y,b4.z,b4.w};
      #pragma unroll
      for (int i=0;i<4;i++)
        #pragma unroll
        for (int j=0;j<4;j++) acc[i][j]=fmaf(av[i],bv[j],acc[i][j]);
    }
  }
  __syncthreads();
  float alpha=alpha_p[0];
  float* Pb=P+(size_t)b*65*65;
  #pragma unroll
  for (int i=0;i<4;i++){
    int rr=4*ty+i;
    bool tok=tmv[rr]>0.f;
    #pragma unroll
    for (int j=0;j<4;j++){
      int cc=4*tx+j;
      bool invm=(!tok)||(smv[cc]<=0.f);
      Pb[rr*65+cc]= invm ? NEGV : acc[i][j]*0.0625f;
    }
  }
  if (t<64){
    Pb[64*65+t]=(smv[t]<=0.f)? NEGV : alpha;
    Pb[t*65+64]=(tmv[t]<=0.f)? NEGV : alpha;
  }
  if (t==64) Pb[64*65+64]=alpha;
}

// Sinkhorn linear-domain, 4 waves per batch, column-split, 2 barriers/iter.
// Combine is redundant per-wave, so chunk gathers use __shfl (v_readlane, no
// LDS round-trip). Partial arrays double-buffered (partU/partV) so the only
// ordering points are the two barriers after partial writes.
__global__ __launch_bounds__(256,1) void ot_kernel(
    float* __restrict__ P, const int* __restrict__ sel_t, const int* __restrict__ sel_s){
  __shared__ float Ps[4225];
  __shared__ __align__(16) float partU[4][72], partV[4][72];
  __shared__ __align__(16) float pu64[4], pusv[4], pv64[4], pvsv[4];
  __shared__ float ufs[65], vfs[65];
  int b=blockIdx.x, t=threadIdx.x, w=t>>6, l=t&63;
  float* Pg=P+(size_t)b*4225;
  for (int e=t;e<4225;e+=256) Ps[e]=Pg[e];
  bool rv=(sel_t[b*KK+l]!=NPTS);
  bool cv=(sel_s[b*KK+l]!=NPTS);
  int nr=(int)__popcll(__ballot(rv));
  int nc=(int)__popcll(__ballot(cv));
  float inv=1.0f/(float)(nr+nc);
  float nrm=-logf((float)(nr+nc));
  float mu_l=inv, nu_l=inv, mu64=(float)nc*inv, nu64=(float)nr*inv;
  bool anyInvR=(nr<KK), anyInvC=(nc<KK);
  __syncthreads();
  const int c0=16*w;
  float aQ[16], bQ[16], r64Q[16], c64Q[16];
  #pragma unroll
  for (int j=0;j<16;j++){
    aQ[j]  =expf(Ps[l*65+c0+j]);        // Km[l][c0+j]
    bQ[j]  =expf(Ps[(c0+j)*65+l]);      // Km[c0+j][l]
    r64Q[j]=expf(Ps[64*65+c0+j]);       // Km[64][c0+j]
    c64Q[j]=expf(Ps[(c0+j)*65+64]);     // Km[c0+j][64]
  }
  float a64=expf(Ps[l*65+64]);
  float b64v=expf(Ps[64*65+l]);
  float k6464=expf(Ps[4224]);
  float U_l, V_l=1.0f, U64, V64=1.0f;

  for (int it=0; it<OTI; ++it){
    // ---- u-pass: gather V chunk via readlane, partial dots, one barrier ----
    float vch[16];
    #pragma unroll
    for (int j=0;j<16;j++) vch[j]=__shfl(V_l, c0+j, 64);
    float p0=0,p1=0,p2=0,p3=0, d0=0,d1=0,d2=0,d3=0, z0=0,z1=0,z2=0,z3=0;
    #pragma unroll
    for (int j4=0;j4<4;j4++){
      p0=fmaf(aQ[4*j4+0],vch[4*j4+0],p0); p1=fmaf(aQ[4*j4+1],vch[4*j4+1],p1);
      p2=fmaf(aQ[4*j4+2],vch[4*j4+2],p2); p3=fmaf(aQ[4*j4+3],vch[4*j4+3],p3);
      d0=fmaf(r64Q[4*j4+0],vch[4*j4+0],d0); d1=fmaf(r64Q[4*j4+1],vch[4*j4+1],d1);
      d2=fmaf(r64Q[4*j4+2],vch[4*j4+2],d2); d3=fmaf(r64Q[4*j4+3],vch[4*j4+3],d3);
      z0+=vch[4*j4+0]; z1+=vch[4*j4+1]; z2+=vch[4*j4+2]; z3+=vch[4*j4+3];
    }
    partU[w][l]=(p0+p1)+(p2+p3);
    if (l==0){ pu64[w]=(d0+d1)+(d2+d3); pusv[w]=(z0+z1)+(z2+z3); }
    __syncthreads();
    {
      float s=partU[0][l]+partU[1][l]+partU[2][l]+partU[3][l];
      float4 d4=*(const float4*)pu64;
      float srow=s+a64*V64;
      float s64=(d4.x+d4.y)+(d4.z+d4.w)+k6464*V64;
      U64=mu64/s64;
      if (anyInvR){
        float4 z4=*(const float4*)pusv;
        float sv=(z4.x+z4.y)+(z4.z+z4.w)+V64;
        U_l = rv ? (mu_l/srow) : (1.0f/sv);
      } else U_l = mu_l/srow;
    }
    // ---- v-pass: gather U chunk via readlane, partial dots, one barrier ----
    float uch[16];
    #pragma unroll
    for (int j=0;j<16;j++) uch[j]=__shfl(U_l, c0+j, 64);
    float q0=0,q1=0,q2=0,q3=0, e0=0,e1=0,e2=0,e3=0, y0=0,y1=0,y2=0,y3=0;
    #pragma unroll
    for (int j4=0;j4<4;j4++){
      q0=fmaf(bQ[4*j4+0],uch[4*j4+0],q0); q1=fmaf(bQ[4*j4+1],uch[4*j4+1],q1);
      q2=fmaf(bQ[4*j4+2],uch[4*j4+2],q2); q3=fmaf(bQ[4*j4+3],uch[4*j4+3],q3);
      e0=fmaf(c64Q[4*j4+0],uch[4*j4+0],e0); e1=fmaf(c64Q[4*j4+1],uch[4*j4+1],e1);
      e2=fmaf(c64Q[4*j4+2],uch[4*j4+2],e2); e3=fmaf(c64Q[4*j4+3],uch[4*j4+3],e3);
      y0+=uch[4*j4+0]; y1+=uch[4*j4+1]; y2+=uch[4*j4+2]; y3+=uch[4*j4+3];
    }
    partV[w][l]=(q0+q1)+(q2+q3);
    if (l==0){ pv64[w]=(e0+e1)+(e2+e3); pvsv[w]=(y0+y1)+(y2+y3); }
    __syncthreads();
    {
      float sc=partV[0][l]+partV[1][l]+partV[2][l]+partV[3][l];
      float4 e4=*(const float4*)pv64;
      float scol=sc+b64v*U64;
      float s64v=(e4.x+e4.y)+(e4.z+e4.w)+k6464*U64;
      V64=nu64/s64v;
      if (anyInvC){
        float4 y4=*(const float4*)pvsv;
        float su=(y4.x+y4.y)+(y4.z+y4.w)+U64;
        V_l = cv ? (nu_l/scol) : (1.0f/su);
      } else V_l = nu_l/scol;
    }
  }
  if (w==0){
    ufs[l]=logf(U_l); vfs[l]=logf(V_l);
    if (l==0){ ufs[64]=logf(U64); vfs[64]=logf(V64); }
  }
  __syncthreads();
  for (int e=t;e<4225;e+=256){
    int r=e/65, c=e-65*r;
    Pg[e]=Ps[e]+ufs[r]+vfs[c]-nrm;
  }
}

// fine prep fused with coarse histogram of the masked scores
__global__ __launch_bounds__(256) void fineprep_kernel(
    const float* __restrict__ P, const int* __restrict__ sel_t, const int* __restrict__ sel_s,
    float* __restrict__ smout, unsigned* __restrict__ partial){
  __shared__ float s[KK*KK];
  __shared__ unsigned long long rowm[KK], colm[KK];
  __shared__ int tmk[KK], smk[KK];
  __shared__ unsigned lh[256];
  int b=blockIdx.x, t=threadIdx.x;
  lh[t]=0u;
  const float* Pb=P+(size_t)b*65*65;
  for (int e=t;e<KK*KK;e+=256){
    int r=e>>6, c=e&63;
    s[e]=expf(Pb[r*65+c]);
  }
  if (t<KK){ tmk[t]=(sel_t[b*KK+t]!=NPTS); smk[t]=(sel_s[b*KK+t]!=NPTS); }
  __syncthreads();
  if (t<KK){
    float v1=-1,v2=-1,v3=-1; int i1=0,i2=0,i3=0;
    const float* row=s+t*KK;
    for (int c=0;c<KK;c++){ float v=row[c];
      if (v>v1){v3=v2;i3=i2;v2=v1;i2=i1;v1=v;i1=c;}
      else if (v>v2){v3=v2;i3=i2;v2=v;i2=c;}
      else if (v>v3){v3=v;i3=c;}
    }
    rowm[t]=(1ULL<<i1)|(1ULL<<i2)|(1ULL<<i3);
  } else if (t<2*KK){
    int c=t-KK;
    float v1=-1,v2=-1,v3=-1; int i1=0,i2=0,i3=0;
    for (int r=0;r<KK;r++){ float v=s[r*KK+c];
      if (v>v1){v3=v2;i3=i2;v2=v1;i2=i1;v1=v;i1=r;}
      else if (v>v2){v3=v2;i3=i2;v2=v;i2=r;}
      else if (v>v3){v3=v;i3=r;}
    }
    colm[c]=(1ULL<<i1)|(1ULL<<i2)|(1ULL<<i3);
  }
  __syncthreads();
  for (int e=t;e<KK*KK;e+=256){
    int r=e>>6, c=e&63;
    float v=s[e];
    bool keep = ((rowm[r]>>c)&1ULL) && ((colm[c]>>r)&1ULL) && (v>0.05f) && tmk[r] && smk[c];
    float o= keep? v : 0.0f;
    smout[(size_t)b*KK*KK+e]=o;
    if (o>0.0f) atomicAdd(&lh[__float_as_uint(o)>>24],1u);
  }
  __syncthreads();
  partial[b*256+t]=lh[t];
}

extern "C" void kernel_launch(void* const* d_in, const int* in_sizes, int n_in,
                              void* d_out, int out_size, void* d_ws, size_t ws_size,
                              hipStream_t stream){
  const float* src_pts=(const float*)d_in[0];
  const float* tgt_pts=(const float*)d_in[1];
  const float* src_pf =(const float*)d_in[2];
  const float* tgt_pf =(const float*)d_in[3];
  const float* src_nf =(const float*)d_in[4];
  const float* tgt_nf =(const float*)d_in[5];
  const float* src_nx =(const float*)d_in[6];
  const float* tgt_nx =(const float*)d_in[7];
  const float* cw=(const float*)d_in[8];
  const float* cb=(const float*)d_in[9];
  const float* fw=(const float*)d_in[10];
  const float* fb=(const float*)d_in[11];
  const float* alpha=(const float*)d_in[12];

  char* ws=(char*)d_ws;
  size_t off=0;
  auto A=[&](size_t bytes)->char*{
    char* p=ws+off; off+=(bytes+255)&~(size_t)255; return p; };

  float* tf    =(float*)A((size_t)MN*DN*4);
  float* sfb   =(float*)A((size_t)MN*DN*4);
  float* tt    =(float*)A(MN*4);
  float* ssv   =(float*)A(MN*4);
  int*   p2n_s =(int*)A((size_t)NPTS*4);
  int*   p2n_t =(int*)A((size_t)NPTS*4);
  int*   cnt_s =(int*)A(MN*4);
  int*   cnt_t =(int*)A(MN*4);
  int*   list_s=(int*)A((size_t)MN*CAPL*4);
  int*   list_t=(int*)A((size_t)MN*CAPL*4);
  int*   knn_s =(int*)A((size_t)MN*KK*4);
  int*   knn_t =(int*)A((size_t)MN*KK*4);
  float* Smat  =(float*)A((size_t)MN*MN*4);
  unsigned* partial=(unsigned*)A((size_t)HBLK*256*4);
  unsigned* meta=(unsigned*)A(256);
  float* cand_v=(float*)A((size_t)CCAP*4);
  int*   cand_i=(int*)A((size_t)CCAP*4);
  int*   ci_t  =(int*)A(BCORR*4);
  int*   ci_s  =(int*)A(BCORR*4);
  int*   sel_t =(int*)A((size_t)BCORR*KK*4);
  int*   sel_s =(int*)A((size_t)BCORR*KK*4);
  float* feat_t=(float*)A((size_t)BCORR*KK*DN*4);
  float* feat_s=(float*)A((size_t)BCORR*KK*DN*4);
  float* smf   =(float*)A((size_t)BCORR*KK*KK*4);
  float* rs    =(float*)A(MN*4);
  float* csum  =(float*)A(MN*4);

  float* out=(float*)d_out;
  float* msout=out;
  float* tpout=out+(size_t)BCORR*65*65;
  float* spout=tpout+(size_t)OUTC*3;
  float* csout=spout+(size_t)OUTC*3;

  const int PB=(NPTS+255)/256;

  zero_all_kernel<<<28,256,0,stream>>>(cnt_s,cnt_t,ci_t,ci_s,tpout);
  node_feat_kernel<<<2*MN,256,0,stream>>>(tgt_nf,src_nf,cw,cb,tf,sfb,tt,ssv);
  p2n_kernel<<<2*PB,256,0,stream>>>(src_pts,src_nx,p2n_s,tgt_pts,tgt_nx,p2n_t,PB);
  scatter_kernel<<<2*PB,256,0,stream>>>(p2n_s,cnt_s,list_s,p2n_t,cnt_t,list_t,PB);
  knn_kernel<<<2*MN,256,0,stream>>>(src_pts,src_nx,cnt_s,list_s,knn_s,
                                    tgt_pts,tgt_nx,cnt_t,list_t,knn_t);

  coarse_score_kernel<<<256,256,0,stream>>>(tf,sfb,tt,ssv,cnt_t,cnt_s,Smat);
  sums_kernel<<<MN+64,256,0,stream>>>(Smat,rs,csum);
  dualnorm_hist_kernel<<<HBLK,256,0,stream>>>(Smat,rs,csum,partial);

  scan_coarse_kernel<<<1,256,0,stream>>>(partial,HBLK,BCORR,meta);
  hist_fine_kernel<<<HBLK,256,0,stream>>>(Smat,MN*MN,meta,partial);
  scan_fine_kernel<<<1,256,0,stream>>>(partial,HBLK,BCORR,meta);
  compact_kernel<<<2048,256,0,stream>>>(Smat,MN*MN,meta,cand_v,cand_i,meta+1);
  rank_coarse_kernel<<<CCAP/256,256,0,stream>>>(cand_v,cand_i,meta,ci_t,ci_s);

  sel_feat_kernel<<<2048,256,0,stream>>>(ci_t,knn_t,tgt_pf, ci_s,knn_s,src_pf,
                                         fw,fb,feat_t,feat_s,sel_t,sel_s);

  pbuild_kernel<<<BCORR,256,0,stream>>>(feat_t,feat_s,sel_t,sel_s,alpha,msout);
  ot_kernel<<<BCORR,256,0,stream>>>(msout,sel_t,sel_s);

  fineprep_kernel<<<BCORR,256,0,stream>>>(msout,sel_t,sel_s,smf,partial);
  scan_coarse_kernel<<<1,256,0,stream>>>(partial,BCORR,OUTC,meta);
  hist_fine_kernel<<<HBLK,256,0,stream>>>(smf,BCORR*KK*KK,meta,partial);
  scan_fine_kernel<<<1,256,0,stream>>>(partial,HBLK,OUTC,meta);
  compact_kernel<<<2048,256,0,stream>>>(smf,BCORR*KK*KK,meta,cand_v,cand_i,meta+1);
  rank_fine_kernel<<<CCAP/256,256,0,stream>>>(cand_v,cand_i,meta,sel_t,sel_s,
                                              tgt_pts,src_pts,tpout,spout,csout);
}

// Round 10
// 686.271 us; speedup vs baseline: 1.8698x; 1.0479x over previous
//
#include <hip/hip_runtime.h>
#include <math.h>

#define NPTS 50000
#define MN 1024
#define KK 64
#define DPT 64
#define DN 256
#define BCORR 256
#define OUTC 1024
#define OTI 100
#define NEGV (-1e4f)
#define EPSV 1e-8f
#define CAPL 512
#define CCAP 16384
#define HBLK 256   // blocks for histogram passes
#define RCH 2048   // rank-kernel LDS chunk

// ---------------- utility ----------------
__global__ void zero_all_kernel(int* cnt_s, int* cnt_t, int* ci_t, int* ci_s,
                                float* tpout){
  int t=blockIdx.x*256+threadIdx.x;
  if (t<MN){ cnt_s[t]=0; cnt_t[t]=0; }
  if (t<BCORR){ ci_t[t]=0; ci_s[t]=0; }
  for (int i=t;i<OUTC*3*2+OUTC;i+=gridDim.x*256) tpout[i]=0.0f;
}

__device__ __forceinline__ float blockReduceSum256(float v, float* red){
  int t=threadIdx.x;
  red[t]=v; __syncthreads();
  #pragma unroll
  for (int s=128;s>0;s>>=1){ if(t<s) red[t]+=red[t+s]; __syncthreads(); }
  float r=red[0]; __syncthreads();
  return r;
}

// node feats (fused tgt+src): out = l2norm(x @ W^T + b); sq = sum(out^2)
__global__ __launch_bounds__(256) void node_feat_kernel(
    const float* __restrict__ xt, const float* __restrict__ xs_,
    const float* __restrict__ W, const float* __restrict__ bias,
    float* __restrict__ outt, float* __restrict__ outs,
    float* __restrict__ sqt, float* __restrict__ sqs){
  __shared__ float xs[DN];
  __shared__ float red[256];
  int m=blockIdx.x, i=threadIdx.x;
  const float* x=(m<MN)? xt:xs_;
  float* out=(m<MN)? outt:outs;
  float* sq=(m<MN)? sqt:sqs;
  int mm=(m<MN)? m:m-MN;
  xs[i]=x[mm*DN+i];
  __syncthreads();
  float acc=bias[i];
  const float* wr=W+(size_t)i*DN;
  for (int k=0;k<DN;k++) acc=fmaf(wr[k],xs[k],acc);
  float ssq=blockReduceSum256(acc*acc,red);
  float o=acc/sqrtf(ssq);
  out[mm*DN+i]=o;
  float s2=blockReduceSum256(o*o,red);
  if(i==0) sq[mm]=s2;
}

// nearest node per point (fused src+tgt); nodes packed float4 (x,y,z,|n|^2)
__global__ __launch_bounds__(256) void p2n_kernel(
    const float* __restrict__ pts_s, const float* __restrict__ nd_s, int* __restrict__ o_s,
    const float* __restrict__ pts_t, const float* __restrict__ nd_t, int* __restrict__ o_t,
    int pb){
  __shared__ __align__(16) float4 nd[MN];
  int which=blockIdx.x>=pb;
  const float* pts=which? pts_t:pts_s;
  const float* nodes=which? nd_t:nd_s;
  int* p2n=which? o_t:o_s;
  int blk=which? blockIdx.x-pb : blockIdx.x;
  for (int j=threadIdx.x;j<MN;j+=256){
    float a=nodes[j*3+0], b=nodes[j*3+1], c=nodes[j*3+2];
    nd[j]=make_float4(a,b,c,a*a+b*b+c*c);
  }
  __syncthreads();
  int id=blk*256+threadIdx.x;
  if (id>=NPTS) return;
  float px=pts[id*3+0], py=pts[id*3+1], pz=pts[id*3+2];
  float pp=px*px+py*py+pz*pz;
  float best=3.4e38f; int bi=0;
  for (int j=0;j<MN;j++){
    float4 n=nd[j];
    float d=pp+n.w-2.0f*(px*n.x+py*n.y+pz*n.z);
    if (d<best){best=d;bi=j;}
  }
  p2n[id]=bi;
}

__global__ __launch_bounds__(256) void scatter_kernel(
    const int* __restrict__ p_s, int* __restrict__ c_s, int* __restrict__ l_s,
    const int* __restrict__ p_t, int* __restrict__ c_t, int* __restrict__ l_t,
    int pb){
  int which=blockIdx.x>=pb;
  const int* p2n=which? p_t:p_s;
  int* cnt=which? c_t:c_s;
  int* list=which? l_t:l_s;
  int blk=which? blockIdx.x-pb : blockIdx.x;
  int id=blk*256+threadIdx.x;
  if (id>=NPTS) return;
  int n=p2n[id];
  int t=atomicAdd(&cnt[n],1);
  if (t<CAPL) list[(size_t)n*CAPL+t]=id;
}

// per-node kNN (fused src+tgt)
__global__ __launch_bounds__(256) void knn_kernel(
    const float* __restrict__ pts_s, const float* __restrict__ nd_s,
    const int* __restrict__ c_s, const int* __restrict__ l_s, int* __restrict__ k_s,
    const float* __restrict__ pts_t, const float* __restrict__ nd_t,
    const int* __restrict__ c_t, const int* __restrict__ l_t, int* __restrict__ k_t){
  __shared__ float ds[CAPL];
  __shared__ int is[CAPL];
  int which=blockIdx.x>=MN;
  const float* pts=which? pts_t:pts_s;
  const float* nodes=which? nd_t:nd_s;
  const int* cnt=which? c_t:c_s;
  const int* list=which? l_t:l_s;
  int* knn=which? k_t:k_s;
  int m=which? blockIdx.x-MN : blockIdx.x;
  int c=cnt[m]; if (c>CAPL) c=CAPL;
  float ax=nodes[m*3+0], ay=nodes[m*3+1], az=nodes[m*3+2];
  float nn2=ax*ax+ay*ay+az*az;
  for (int e=threadIdx.x;e<c;e+=256){
    int p=list[(size_t)m*CAPL+e];
    float px=pts[p*3+0],py=pts[p*3+1],pz=pts[p*3+2];
    float pp=px*px+py*py+pz*pz;
    ds[e]=pp+nn2-2.0f*(px*ax+py*ay+pz*az);
    is[e]=p;
  }
  for (int k=threadIdx.x;k<KK;k+=256) knn[m*KK+k]=NPTS;
  __syncthreads();
  for (int e=threadIdx.x;e<c;e+=256){
    float d=ds[e]; int p=is[e]; int r=0;
    for (int j=0;j<c;j++){
      float dj=ds[j];
      r += (dj<d || (dj==d && is[j]<p)) ? 1 : 0;
    }
    if (r<KK) knn[m*KK+r]=p;
  }
}

// coarse scores as tiled GEMM
__global__ __launch_bounds__(256) void coarse_score_kernel(
    const float* __restrict__ tf, const float* __restrict__ sf,
    const float* __restrict__ tt, const float* __restrict__ ssv,
    const int* __restrict__ cnt_t, const int* __restrict__ cnt_s, float* __restrict__ S){
  __shared__ float tas[64][64];   // [k][r]
  __shared__ float sbs[64][64];   // [k][c]
  __shared__ float tta[64], ssa[64], tva[64], sva[64];
  int bi=blockIdx.x>>4, bj=blockIdx.x&15;
  int t=threadIdx.x, r=t&63, kq=t>>6, tx=t&15, ty=t>>4;
  if (kq==0){ tta[r]=tt[bi*64+r]; tva[r]=(cnt_t[bi*64+r]>0)?1.f:0.f; }
  if (kq==1){ ssa[r]=ssv[bj*64+r]; sva[r]=(cnt_s[bj*64+r]>0)?1.f:0.f; }
  float acc[4][4]={};
  const float* ta=tf+((size_t)bi*64)*DN;
  const float* sa=sf+((size_t)bj*64)*DN;
  for (int kc=0;kc<DN;kc+=64){
    __syncthreads();
    const float* tr_=ta+(size_t)r*DN+kc+kq*16;
    const float* sr_=sa+(size_t)r*DN+kc+kq*16;
    #pragma unroll
    for (int j4=0;j4<4;j4++){
      float4 v=*(const float4*)(tr_+4*j4);
      tas[kq*16+4*j4+0][r]=v.x; tas[kq*16+4*j4+1][r]=v.y;
      tas[kq*16+4*j4+2][r]=v.z; tas[kq*16+4*j4+3][r]=v.w;
      float4 w=*(const float4*)(sr_+4*j4);
      sbs[kq*16+4*j4+0][r]=w.x; sbs[kq*16+4*j4+1][r]=w.y;
      sbs[kq*16+4*j4+2][r]=w.z; sbs[kq*16+4*j4+3][r]=w.w;
    }
    __syncthreads();
    #pragma unroll
    for (int kk=0;kk<64;kk++){
      float4 a4=*(const float4*)(&tas[kk][4*ty]);
      float4 b4=*(const float4*)(&sbs[kk][4*tx]);
      float av[4]={a4.x,a4.y,a4.z,a4.w};
      float bv[4]={b4.x,b4.y,b4.z,b4.w};
      #pragma unroll
      for (int i=0;i<4;i++)
        #pragma unroll
        for (int j=0;j<4;j++) acc[i][j]=fmaf(av[i],bv[j],acc[i][j]);
    }
  }
  __syncthreads();
  #pragma unroll
  for (int i=0;i<4;i++){
    int rr=4*ty+i;
    #pragma unroll
    for (int j=0;j<4;j++){
      int cc=4*tx+j;
      float d=tta[rr]+ssa[cc]-2.0f*acc[i][j];
      float v=expf(-d);
      S[(size_t)(bi*64+rr)*MN + bj*64+cc]=(tva[rr]>0.f && sva[cc]>0.f)? v:0.0f;
    }
  }
}

// fused row+col sums
__global__ __launch_bounds__(256) void sums_kernel(
    const float* __restrict__ S, float* __restrict__ rs, float* __restrict__ cs){
  __shared__ float red[256];
  __shared__ float red2[16][17];
  if (blockIdx.x<MN){
    int i=blockIdx.x;
    float a=0;
    for (int j=threadIdx.x;j<MN;j+=256) a+=S[(size_t)i*MN+j];
    float r=blockReduceSum256(a,red);
    if (threadIdx.x==0) rs[i]=r;
  } else {
    int j0=(blockIdx.x-MN)*16;
    int tx=threadIdx.x&15, ty=threadIdx.x>>4;
    float a=0;
    for (int i=ty;i<MN;i+=16) a+=S[(size_t)i*MN + j0+tx];
    red2[ty][tx]=a; __syncthreads();
    if (ty==0){
      float s=0;
      #pragma unroll
      for (int q=0;q<16;q++) s+=red2[q][tx];
      cs[j0+tx]=s;
    }
  }
}
// dual normalization fused with L1 histogram pass
__global__ __launch_bounds__(256) void dualnorm_hist_kernel(
    float* __restrict__ S, const float* __restrict__ rs, const float* __restrict__ cs,
    unsigned* __restrict__ partial){
  __shared__ unsigned lh[256];
  lh[threadIdx.x]=0u; __syncthreads();
  for (int idx=blockIdx.x*256+threadIdx.x; idx<MN*MN; idx+=gridDim.x*256){
    int i=idx>>10, j=idx&1023;
    float v=S[idx];
    v=(v/(rs[i]+EPSV))*(v/(cs[j]+EPSV));
    S[idx]=v;
    if (v>0.0f) atomicAdd(&lh[__float_as_uint(v)>>24],1u);
  }
  __syncthreads();
  partial[blockIdx.x*256+threadIdx.x]=lh[threadIdx.x];
}

// ---------- deterministic top-k, three-level (8/16/24-bit) histogram ----------
// meta: [0]=T24 threshold, [1]=cand counter, [2]=CB(8b), [3]=above L1,
//       [4]=above L2, [5]=T16
__global__ __launch_bounds__(256) void scan_coarse_kernel(
    const unsigned* __restrict__ partial, int nblk, int k, unsigned* __restrict__ meta){
  __shared__ unsigned h[256];
  int t=threadIdx.x;
  unsigned a=0;
  for (int i=0;i<nblk;i++) a+=partial[(size_t)i*256+t];
  h[t]=a; __syncthreads();
  if (t==0){
    unsigned cum=0; int cb=-1; unsigned above=0;
    for (int b=255;b>=0;b--){
      if (cum+h[b] >= (unsigned)k){ cb=b; above=cum; break; }
      cum+=h[b];
    }
    if (cb<0){ cb=0; above=cum-h[0]; }
    meta[2]=(unsigned)cb; meta[3]=above;
  }
}
__global__ __launch_bounds__(256) void hist_fine_kernel(
    const float* __restrict__ arr, int n, const unsigned* __restrict__ meta,
    unsigned* __restrict__ partial){
  __shared__ unsigned lh[256];
  lh[threadIdx.x]=0u; __syncthreads();
  unsigned CB=meta[2];
  for (int i=blockIdx.x*256+threadIdx.x; i<n; i+=gridDim.x*256){
    float v=arr[i];
    unsigned b=__float_as_uint(v);
    if (v>0.0f && (b>>24)==CB) atomicAdd(&lh[(b>>16)&255u],1u);
  }
  __syncthreads();
  partial[blockIdx.x*256+threadIdx.x]=lh[threadIdx.x];
}
__global__ __launch_bounds__(256) void scan_fine_kernel(
    const unsigned* __restrict__ partial, int nblk, int k, unsigned* __restrict__ meta){
  __shared__ unsigned h[256];
  int t=threadIdx.x;
  unsigned a=0;
  for (int i=0;i<nblk;i++) a+=partial[(size_t)i*256+t];
  h[t]=a; __syncthreads();
  if (t==0){
    unsigned cum=meta[3]; int sb=0;
    for (int b=255;b>=0;b--){
      if (cum+h[b] >= (unsigned)k){ sb=b; break; }
      cum+=h[b];
    }
    meta[5]=meta[2]*256u+(unsigned)sb;   // T16
    meta[4]=cum;                          // count strictly above T16 bucket
  }
}
__global__ __launch_bounds__(256) void hist_fine2_kernel(
    const float* __restrict__ arr, int n, const unsigned* __restrict__ meta,
    unsigned* __restrict__ partial){
  __shared__ unsigned lh[256];
  lh[threadIdx.x]=0u; __syncthreads();
  unsigned T16=meta[5];
  for (int i=blockIdx.x*256+threadIdx.x; i<n; i+=gridDim.x*256){
    float v=arr[i];
    unsigned b=__float_as_uint(v);
    if (v>0.0f && (b>>16)==T16) atomicAdd(&lh[(b>>8)&255u],1u);
  }
  __syncthreads();
  partial[blockIdx.x*256+threadIdx.x]=lh[threadIdx.x];
}
__global__ __launch_bounds__(256) void scan_fine2_kernel(
    const unsigned* __restrict__ partial, int nblk, int k, unsigned* __restrict__ meta){
  __shared__ unsigned h[256];
  int t=threadIdx.x;
  unsigned a=0;
  for (int i=0;i<nblk;i++) a+=partial[(size_t)i*256+t];
  h[t]=a; __syncthreads();
  if (t==0){
    unsigned cum=meta[4]; int sb=0;
    for (int b=255;b>=0;b--){
      if (cum+h[b] >= (unsigned)k){ sb=b; break; }
      cum+=h[b];
    }
    meta[0]=meta[5]*256u+(unsigned)sb;   // T24
    meta[1]=0u;
  }
}
__global__ void compact_kernel(const float* __restrict__ arr, int n,
                               const unsigned* __restrict__ meta,
                               float* __restrict__ cv, int* __restrict__ ci,
                               unsigned* __restrict__ cnt){
  unsigned T=meta[0];
  for (int i=blockIdx.x*blockDim.x+threadIdx.x; i<n; i+=gridDim.x*blockDim.x){
    float v=arr[i];
    if (v>0.0f && (__float_as_uint(v)>>8)>=T){
      unsigned p=atomicAdd(cnt,1u);
      if (p<CCAP){ cv[p]=v; ci[p]=i; }
    }
  }
}
// LDS-tiled exact rank (value desc, index asc)
__global__ __launch_bounds__(256) void rank_coarse_kernel(
    const float* __restrict__ cv, const int* __restrict__ ci, const unsigned* __restrict__ meta,
    int* __restrict__ ti, int* __restrict__ si){
  __shared__ __align__(16) float scv[RCH];
  __shared__ __align__(16) int sci[RCH];
  int c=(int)meta[1]; if (c>CCAP) c=CCAP;
  int t=blockIdx.x*256+threadIdx.x;
  bool act=(t<c);
  float v=0.0f; int idx=0;
  if (act){ v=cv[t]; idx=ci[t]; }
  int rk=0;
  for (int base=0;base<c;base+=RCH){
    int lim=min(RCH,c-base);
    __syncthreads();
    for (int j=threadIdx.x;j<lim;j+=256){ scv[j]=cv[base+j]; sci[j]=ci[base+j]; }
    __syncthreads();
    if (act){
      int j=0;
      for (;j+4<=lim;j+=4){
        float4 v4=*(const float4*)(scv+j);
        int4 i4=*(const int4*)(sci+j);
        rk += (v4.x>v||(v4.x==v&&i4.x<idx))?1:0;
        rk += (v4.y>v||(v4.y==v&&i4.y<idx))?1:0;
        rk += (v4.z>v||(v4.z==v&&i4.z<idx))?1:0;
        rk += (v4.w>v||(v4.w==v&&i4.w<idx))?1:0;
      }
      for (;j<lim;j++) rk += (scv[j]>v||(scv[j]==v&&sci[j]<idx))?1:0;
    }
  }
  if (act && rk<BCORR){ ti[rk]=idx/MN; si[rk]=idx%MN; }
}
__global__ __launch_bounds__(256) void rank_fine_kernel(
    const float* __restrict__ cv, const int* __restrict__ ci, const unsigned* __restrict__ meta,
    const int* __restrict__ sel_t, const int* __restrict__ sel_s,
    const float* __restrict__ tpts, const float* __restrict__ spts,
    float* __restrict__ tp, float* __restrict__ sp, float* __restrict__ cs){
  __shared__ __align__(16) float scv[RCH];
  __shared__ __align__(16) int sci[RCH];
  int c=(int)meta[1]; if (c>CCAP) c=CCAP;
  int t=blockIdx.x*256+threadIdx.x;
  bool act=(t<c);
  float v=0.0f; int idx=0;
  if (act){ v=cv[t]; idx=ci[t]; }
  int rk=0;
  for (int base=0;base<c;base+=RCH){
    int lim=min(RCH,c-base);
    __syncthreads();
    for (int j=threadIdx.x;j<lim;j+=256){ scv[j]=cv[base+j]; sci[j]=ci[base+j]; }
    __syncthreads();
    if (act){
      int j=0;
      for (;j+4<=lim;j+=4){
        float4 v4=*(const float4*)(scv+j);
        int4 i4=*(const int4*)(sci+j);
        rk += (v4.x>v||(v4.x==v&&i4.x<idx))?1:0;
        rk += (v4.y>v||(v4.y==v&&i4.y<idx))?1:0;
        rk += (v4.z>v||(v4.z==v&&i4.z<idx))?1:0;
        rk += (v4.w>v||(v4.w==v&&i4.w<idx))?1:0;
      }
      for (;j<lim;j++) rk += (scv[j]>v||(scv[j]==v&&sci[j]<idx))?1:0;
    }
  }
  if (act && rk<OUTC){
    int b=idx>>12, r=(idx>>6)&63, cc=idx&63;
    int tpi=sel_t[b*KK+r], spi=sel_s[b*KK+cc];
    float tx=0,ty=0,tz=0,sx=0,sy=0,sz=0;
    if (tpi<NPTS){ tx=tpts[tpi*3]; ty=tpts[tpi*3+1]; tz=tpts[tpi*3+2]; }
    if (spi<NPTS){ sx=spts[spi*3]; sy=spts[spi*3+1]; sz=spts[spi*3+2]; }
    tp[rk*3+0]=tx; tp[rk*3+1]=ty; tp[rk*3+2]=tz;
    sp[rk*3+0]=sx; sp[rk*3+1]=sy; sp[rk*3+2]=sz;
    cs[rk]=v;
  }
}

// ---------- patch assembly / OT / fine ----------
__global__ __launch_bounds__(256) void sel_feat_kernel(
    const int* __restrict__ ci_t, const int* __restrict__ knn_t, const float* __restrict__ ptf_t,
    const int* __restrict__ ci_s, const int* __restrict__ knn_s, const float* __restrict__ ptf_s,
    const float* __restrict__ W, const float* __restrict__ bias,
    float* __restrict__ out_t, float* __restrict__ out_s,
    int* __restrict__ sel_tO, int* __restrict__ sel_sO){
  __shared__ float Xs[64][64];   // [k][r]
  __shared__ float Ws[64][64];   // [k][o]
  __shared__ float pvf[64];
  int which=blockIdx.x>=1024;
  const int* cib=which? ci_s:ci_t;
  const int* knn=which? knn_s:knn_t;
  const float* ptf=which? ptf_s:ptf_t;
  float* out=which? out_s:out_t;
  int* sel=which? sel_sO:sel_tO;
  int blk=which? blockIdx.x-1024 : blockIdx.x;
  int bj=blk>>2, bo=blk&3;
  int t=threadIdx.x, r=t&63, kq=t>>6, tx=t&15, ty=t>>4;
  int p=knn[cib[bj]*KK+r];
  if (kq==0){
    pvf[r]=(p!=NPTS)?1.f:0.f;
    if (bo==0) sel[bj*KK+r]=p;
  }
  const float* xr=ptf+(size_t)p*DPT+kq*16;
  #pragma unroll
  for (int j4=0;j4<4;j4++){
    float4 v=(p==NPTS)? make_float4(0.f,0.f,0.f,0.f) : *(const float4*)(xr+4*j4);
    Xs[kq*16+4*j4+0][r]=v.x; Xs[kq*16+4*j4+1][r]=v.y;
    Xs[kq*16+4*j4+2][r]=v.z; Xs[kq*16+4*j4+3][r]=v.w;
  }
  const float* wr=W+(size_t)(bo*64+r)*DPT+kq*16;
  #pragma unroll
  for (int j4=0;j4<4;j4++){
    float4 w=*(const float4*)(wr+4*j4);
    Ws[kq*16+4*j4+0][r]=w.x; Ws[kq*16+4*j4+1][r]=w.y;
    Ws[kq*16+4*j4+2][r]=w.z; Ws[kq*16+4*j4+3][r]=w.w;
  }
  __syncthreads();
  float acc[4][4]={};
  #pragma unroll
  for (int kk=0;kk<64;kk++){
    float4 a4=*(const float4*)(&Xs[kk][4*ty]);
    float4 w4=*(const float4*)(&Ws[kk][4*tx]);
    float av[4]={a4.x,a4.y,a4.z,a4.w};
    float wv[4]={w4.x,w4.y,w4.z,w4.w};
    #pragma unroll
    for (int i=0;i<4;i++)
      #pragma unroll
      for (int j=0;j<4;j++) acc[i][j]=fmaf(av[i],wv[j],acc[i][j]);
  }
  #pragma unroll
  for (int i=0;i<4;i++){
    int rr=4*ty+i;
    #pragma unroll
    for (int j=0;j<4;j++){
      int oo=4*tx+j;
      float v=acc[i][j]+bias[bo*64+oo];
      out[(size_t)(bj*64+rr)*DN + bo*64+oo]= (pvf[rr]>0.f)? v : 0.0f;
    }
  }
}

// OT input P (65x65) per batch as tiled GEMM + dustbin/mask epilogue
__global__ __launch_bounds__(256) void pbuild_kernel(
    const float* __restrict__ ft, const float* __restrict__ fs,
    const int* __restrict__ sel_t, const int* __restrict__ sel_s,
    const float* __restrict__ alpha_p, float* __restrict__ P){
  __shared__ float tas[64][64];
  __shared__ float sbs[64][64];
  __shared__ float tmv[64], smv[64];
  int b=blockIdx.x, t=threadIdx.x;
  int r=t&63, kq=t>>6, tx=t&15, ty=t>>4;
  if (kq==0) tmv[r]=(sel_t[b*KK+r]!=NPTS)?1.f:0.f;
  if (kq==1) smv[r]=(sel_s[b*KK+r]!=NPTS)?1.f:0.f;
  float acc[4][4]={};
  const float* tb=ft+(size_t)b*KK*DN;
  const float* sb=fs+(size_t)b*KK*DN;
  for (int kc=0;kc<DN;kc+=64){
    __syncthreads();
    const float* tr_=tb+(size_t)r*DN+kc+kq*16;
    const float* sr_=sb+(size_t)r*DN+kc+kq*16;
    #pragma unroll
    for (int j4=0;j4<4;j4++){
      float4 v=*(const float4*)(tr_+4*j4);
      tas[kq*16+4*j4+0][r]=v.x; tas[kq*16+4*j4+1][r]=v.y;
      tas[kq*16+4*j4+2][r]=v.z; tas[kq*16+4*j4+3][r]=v.w;
      float4 w=*(const float4*)(sr_+4*j4);
      sbs[kq*16+4*j4+0][r]=w.x; sbs[kq*16+4*j4+1][r]=w.y;
      sbs[kq*16+4*j4+2][r]=w.z; sbs[kq*16+4*j4+3][r]=w.w;
    }
    __syncthreads();
    #pragma unroll
    for (int kk=0;kk<64;kk++){
      float4 a4=*(const float4*)(&tas[kk][4*ty]);
      float4 b4=*(const float4*)(&sbs[kk][4*tx]);
      float av[4]={a4.x,a4.y,a4.z,a4.w};
      float bv[4]={b4.x,b4.y,b4.z,b4.w};
      #pragma unroll
      for (int i=0;i<4;i++)
        #pragma unroll
        for (int j=0;j<4;j++) acc[i][j]=fmaf(av[i],bv[j],acc[i][j]);
    }
  }
  __syncthreads();
  float alpha=alpha_p[0];
  float* Pb=P+(size_t)b*65*65;
  #pragma unroll
  for (int i=0;i<4;i++){
    int rr=4*ty+i;
    bool tok=tmv[rr]>0.f;
    #pragma unroll
    for (int j=0;j<4;j++){
      int cc=4*tx+j;
      bool invm=(!tok)||(smv[cc]<=0.f);
      Pb[rr*65+cc]= invm ? NEGV : acc[i][j]*0.0625f;
    }
  }
  if (t<64){
    Pb[64*65+t]=(smv[t]<=0.f)? NEGV : alpha;
    Pb[t*65+64]=(tmv[t]<=0.f)? NEGV : alpha;
  }
  if (t==64) Pb[64*65+64]=alpha;
}

// Sinkhorn linear-domain, 4 waves per batch, column-split, 2 barriers/iter.
__global__ __launch_bounds__(256,1) void ot_kernel(
    float* __restrict__ P, const int* __restrict__ sel_t, const int* __restrict__ sel_s){
  __shared__ float Ps[4225];
  __shared__ __align__(16) float partU[4][72], partV[4][72];
  __shared__ __align__(16) float pu64[4], pusv[4], pv64[4], pvsv[4];
  __shared__ float ufs[65], vfs[65];
  int b=blockIdx.x, t=threadIdx.x, w=t>>6, l=t&63;
  float* Pg=P+(size_t)b*4225;
  for (int e=t;e<4225;e+=256) Ps[e]=Pg[e];
  bool rv=(sel_t[b*KK+l]!=NPTS);
  bool cv=(sel_s[b*KK+l]!=NPTS);
  int nr=(int)__popcll(__ballot(rv));
  int nc=(int)__popcll(__ballot(cv));
  float inv=1.0f/(float)(nr+nc);
  float nrm=-logf((float)(nr+nc));
  float mu_l=inv, nu_l=inv, mu64=(float)nc*inv, nu64=(float)nr*inv;
  bool anyInvR=(nr<KK), anyInvC=(nc<KK);
  __syncthreads();
  const int c0=16*w;
  float aQ[16], bQ[16], r64Q[16], c64Q[16];
  #pragma unroll
  for (int j=0;j<16;j++){
    aQ[j]  =expf(Ps[l*65+c0+j]);
    bQ[j]  =expf(Ps[(c0+j)*65+l]);
    r64Q[j]=expf(Ps[64*65+c0+j]);
    c64Q[j]=expf(Ps[(c0+j)*65+64]);
  }
  float a64=expf(Ps[l*65+64]);
  float b64v=expf(Ps[64*65+l]);
  float k6464=expf(Ps[4224]);
  float U_l, V_l=1.0f, U64, V64=1.0f;

  for (int it=0; it<OTI; ++it){
    float vch[16];
    #pragma unroll
    for (int j=0;j<16;j++) vch[j]=__shfl(V_l, c0+j, 64);
    float p0=0,p1=0,p2=0,p3=0, d0=0,d1=0,d2=0,d3=0, z0=0,z1=0,z2=0,z3=0;
    #pragma unroll
    for (int j4=0;j4<4;j4++){
      p0=fmaf(aQ[4*j4+0],vch[4*j4+0],p0); p1=fmaf(aQ[4*j4+1],vch[4*j4+1],p1);
      p2=fmaf(aQ[4*j4+2],vch[4*j4+2],p2); p3=fmaf(aQ[4*j4+3],vch[4*j4+3],p3);
      d0=fmaf(r64Q[4*j4+0],vch[4*j4+0],d0); d1=fmaf(r64Q[4*j4+1],vch[4*j4+1],d1);
      d2=fmaf(r64Q[4*j4+2],vch[4*j4+2],d2); d3=fmaf(r64Q[4*j4+3],vch[4*j4+3],d3);
      z0+=vch[4*j4+0]; z1+=vch[4*j4+1]; z2+=vch[4*j4+2]; z3+=vch[4*j4+3];
    }
    partU[w][l]=(p0+p1)+(p2+p3);
    if (l==0){ pu64[w]=(d0+d1)+(d2+d3); pusv[w]=(z0+z1)+(z2+z3); }
    __syncthreads();
    {
      float s=partU[0][l]+partU[1][l]+partU[2][l]+partU[3][l];
      float4 d4=*(const float4*)pu64;
      float srow=s+a64*V64;
      float s64=(d4.x+d4.y)+(d4.z+d4.w)+k6464*V64;
      U64=mu64/s64;
      if (anyInvR){
        float4 z4=*(const float4*)pusv;
        float sv=(z4.x+z4.y)+(z4.z+z4.w)+V64;
        U_l = rv ? (mu_l/srow) : (1.0f/sv);
      } else U_l = mu_l/srow;
    }
    float uch[16];
    #pragma unroll
    for (int j=0;j<16;j++) uch[j]=__shfl(U_l, c0+j, 64);
    float q0=0,q1=0,q2=0,q3=0, e0=0,e1=0,e2=0,e3=0, y0=0,y1=0,y2=0,y3=0;
    #pragma unroll
    for (int j4=0;j4<4;j4++){
      q0=fmaf(bQ[4*j4+0],uch[4*j4+0],q0); q1=fmaf(bQ[4*j4+1],uch[4*j4+1],q1);
      q2=fmaf(bQ[4*j4+2],uch[4*j4+2],q2); q3=fmaf(bQ[4*j4+3],uch[4*j4+3],q3);
      e0=fmaf(c64Q[4*j4+0],uch[4*j4+0],e0); e1=fmaf(c64Q[4*j4+1],uch[4*j4+1],e1);
      e2=fmaf(c64Q[4*j4+2],uch[4*j4+2],e2); e3=fmaf(c64Q[4*j4+3],uch[4*j4+3],e3);
      y0+=uch[4*j4+0]; y1+=uch[4*j4+1]; y2+=uch[4*j4+2]; y3+=uch[4*j4+3];
    }
    partV[w][l]=(q0+q1)+(q2+q3);
    if (l==0){ pv64[w]=(e0+e1)+(e2+e3); pvsv[w]=(y0+y1)+(y2+y3); }
    __syncthreads();
    {
      float sc=partV[0][l]+partV[1][l]+partV[2][l]+partV[3][l];
      float4 e4=*(const float4*)pv64;
      float scol=sc+b64v*U64;
      float s64v=(e4.x+e4.y)+(e4.z+e4.w)+k6464*U64;
      V64=nu64/s64v;
      if (anyInvC){
        float4 y4=*(const float4*)pvsv;
        float su=(y4.x+y4.y)+(y4.z+y4.w)+U64;
        V_l = cv ? (nu_l/scol) : (1.0f/su);
      } else V_l = nu_l/scol;
    }
  }
  if (w==0){
    ufs[l]=logf(U_l); vfs[l]=logf(V_l);
    if (l==0){ ufs[64]=logf(U64); vfs[64]=logf(V64); }
  }
  __syncthreads();
  for (int e=t;e<4225;e+=256){
    int r=e/65, c=e-65*r;
    Pg[e]=Ps[e]+ufs[r]+vfs[c]-nrm;
  }
}

// fine prep fused with L1 histogram of the masked scores
__global__ __launch_bounds__(256) void fineprep_kernel(
    const float* __restrict__ P, const int* __restrict__ sel_t, const int* __restrict__ sel_s,
    float* __restrict__ smout, unsigned* __restrict__ partial){
  __shared__ float s[KK*KK];
  __shared__ unsigned long long rowm[KK], colm[KK];
  __shared__ int tmk[KK], smk[KK];
  __shared__ unsigned lh[256];
  int b=blockIdx.x, t=threadIdx.x;
  lh[t]=0u;
  const float* Pb=P+(size_t)b*65*65;
  for (int e=t;e<KK*KK;e+=256){
    int r=e>>6, c=e&63;
    s[e]=expf(Pb[r*65+c]);
  }
  if (t<KK){ tmk[t]=(sel_t[b*KK+t]!=NPTS); smk[t]=(sel_s[b*KK+t]!=NPTS); }
  __syncthreads();
  if (t<KK){
    float v1=-1,v2=-1,v3=-1; int i1=0,i2=0,i3=0;
    const float* row=s+t*KK;
    for (int c=0;c<KK;c++){ float v=row[c];
      if (v>v1){v3=v2;i3=i2;v2=v1;i2=i1;v1=v;i1=c;}
      else if (v>v2){v3=v2;i3=i2;v2=v;i2=c;}
      else if (v>v3){v3=v;i3=c;}
    }
    rowm[t]=(1ULL<<i1)|(1ULL<<i2)|(1ULL<<i3);
  } else if (t<2*KK){
    int c=t-KK;
    float v1=-1,v2=-1,v3=-1; int i1=0,i2=0,i3=0;
    for (int r=0;r<KK;r++){ float v=s[r*KK+c];
      if (v>v1){v3=v2;i3=i2;v2=v1;i2=i1;v1=v;i1=r;}
      else if (v>v2){v3=v2;i3=i2;v2=v;i2=r;}
      else if (v>v3){v3=v;i3=r;}
    }
    colm[c]=(1ULL<<i1)|(1ULL<<i2)|(1ULL<<i3);
  }
  __syncthreads();
  for (int e=t;e<KK*KK;e+=256){
    int r=e>>6, c=e&63;
    float v=s[e];
    bool keep = ((rowm[r]>>c)&1ULL) && ((colm[c]>>r)&1ULL) && (v>0.05f) && tmk[r] && smk[c];
    float o= keep? v : 0.0f;
    smout[(size_t)b*KK*KK+e]=o;
    if (o>0.0f) atomicAdd(&lh[__float_as_uint(o)>>24],1u);
  }
  __syncthreads();
  partial[b*256+t]=lh[t];
}

extern "C" void kernel_launch(void* const* d_in, const int* in_sizes, int n_in,
                              void* d_out, int out_size, void* d_ws, size_t ws_size,
                              hipStream_t stream){
  const float* src_pts=(const float*)d_in[0];
  const float* tgt_pts=(const float*)d_in[1];
  const float* src_pf =(const float*)d_in[2];
  const float* tgt_pf =(const float*)d_in[3];
  const float* src_nf =(const float*)d_in[4];
  const float* tgt_nf =(const float*)d_in[5];
  const float* src_nx =(const float*)d_in[6];
  const float* tgt_nx =(const float*)d_in[7];
  const float* cw=(const float*)d_in[8];
  const float* cb=(const float*)d_in[9];
  const float* fw=(const float*)d_in[10];
  const float* fb=(const float*)d_in[11];
  const float* alpha=(const float*)d_in[12];

  char* ws=(char*)d_ws;
  size_t off=0;
  auto A=[&](size_t bytes)->char*{
    char* p=ws+off; off+=(bytes+255)&~(size_t)255; return p; };

  float* tf    =(float*)A((size_t)MN*DN*4);
  float* sfb   =(float*)A((size_t)MN*DN*4);
  float* tt    =(float*)A(MN*4);
  float* ssv   =(float*)A(MN*4);
  int*   p2n_s =(int*)A((size_t)NPTS*4);
  int*   p2n_t =(int*)A((size_t)NPTS*4);
  int*   cnt_s =(int*)A(MN*4);
  int*   cnt_t =(int*)A(MN*4);
  int*   list_s=(int*)A((size_t)MN*CAPL*4);
  int*   list_t=(int*)A((size_t)MN*CAPL*4);
  int*   knn_s =(int*)A((size_t)MN*KK*4);
  int*   knn_t =(int*)A((size_t)MN*KK*4);
  float* Smat  =(float*)A((size_t)MN*MN*4);
  unsigned* partial=(unsigned*)A((size_t)HBLK*256*4);
  unsigned* meta=(unsigned*)A(256);
  float* cand_v=(float*)A((size_t)CCAP*4);
  int*   cand_i=(int*)A((size_t)CCAP*4);
  int*   ci_t  =(int*)A(BCORR*4);
  int*   ci_s  =(int*)A(BCORR*4);
  int*   sel_t =(int*)A((size_t)BCORR*KK*4);
  int*   sel_s =(int*)A((size_t)BCORR*KK*4);
  float* feat_t=(float*)A((size_t)BCORR*KK*DN*4);
  float* feat_s=(float*)A((size_t)BCORR*KK*DN*4);
  float* smf   =(float*)A((size_t)BCORR*KK*KK*4);
  float* rs    =(float*)A(MN*4);
  float* csum  =(float*)A(MN*4);

  float* out=(float*)d_out;
  float* msout=out;
  float* tpout=out+(size_t)BCORR*65*65;
  float* spout=tpout+(size_t)OUTC*3;
  float* csout=spout+(size_t)OUTC*3;

  const int PB=(NPTS+255)/256;

  zero_all_kernel<<<28,256,0,stream>>>(cnt_s,cnt_t,ci_t,ci_s,tpout);
  node_feat_kernel<<<2*MN,256,0,stream>>>(tgt_nf,src_nf,cw,cb,tf,sfb,tt,ssv);
  p2n_kernel<<<2*PB,256,0,stream>>>(src_pts,src_nx,p2n_s,tgt_pts,tgt_nx,p2n_t,PB);
  scatter_kernel<<<2*PB,256,0,stream>>>(p2n_s,cnt_s,list_s,p2n_t,cnt_t,list_t,PB);
  knn_kernel<<<2*MN,256,0,stream>>>(src_pts,src_nx,cnt_s,list_s,knn_s,
                                    tgt_pts,tgt_nx,cnt_t,list_t,knn_t);

  coarse_score_kernel<<<256,256,0,stream>>>(tf,sfb,tt,ssv,cnt_t,cnt_s,Smat);
  sums_kernel<<<MN+64,256,0,stream>>>(Smat,rs,csum);
  dualnorm_hist_kernel<<<HBLK,256,0,stream>>>(Smat,rs,csum,partial);

  scan_coarse_kernel<<<1,256,0,stream>>>(partial,HBLK,BCORR,meta);
  hist_fine_kernel<<<HBLK,256,0,stream>>>(Smat,MN*MN,meta,partial);
  scan_fine_kernel<<<1,256,0,stream>>>(partial,HBLK,BCORR,meta);
  hist_fine2_kernel<<<HBLK,256,0,stream>>>(Smat,MN*MN,meta,partial);
  scan_fine2_kernel<<<1,256,0,stream>>>(partial,HBLK,BCORR,meta);
  compact_kernel<<<2048,256,0,stream>>>(Smat,MN*MN,meta,cand_v,cand_i,meta+1);
  rank_coarse_kernel<<<CCAP/256,256,0,stream>>>(cand_v,cand_i,meta,ci_t,ci_s);

  sel_feat_kernel<<<2048,256,0,stream>>>(ci_t,knn_t,tgt_pf, ci_s,knn_s,src_pf,
                                         fw,fb,feat_t,feat_s,sel_t,sel_s);

  pbuild_kernel<<<BCORR,256,0,stream>>>(feat_t,feat_s,sel_t,sel_s,alpha,msout);
  ot_kernel<<<BCORR,256,0,stream>>>(msout,sel_t,sel_s);

  fineprep_kernel<<<BCORR,256,0,stream>>>(msout,sel_t,sel_s,smf,partial);
  scan_coarse_kernel<<<1,256,0,stream>>>(partial,BCORR,OUTC,meta);
  hist_fine_kernel<<<HBLK,256,0,stream>>>(smf,BCORR*KK*KK,meta,partial);
  scan_fine_kernel<<<1,256,0,stream>>>(partial,HBLK,OUTC,meta);
  hist_fine2_kernel<<<HBLK,256,0,stream>>>(smf,BCORR*KK*KK,meta,partial);
  scan_fine2_kernel<<<1,256,0,stream>>>(partial,HBLK,OUTC,meta);
  compact_kernel<<<2048,256,0,stream>>>(smf,BCORR*KK*KK,meta,cand_v,cand_i,meta+1);
  rank_fine_kernel<<<CCAP/256,256,0,stream>>>(cand_v,cand_i,meta,sel_t,sel_s,
                                              tgt_pts,src_pts,tpout,spout,csout);
}

// Round 11
// 673.444 us; speedup vs baseline: 1.9054x; 1.0190x over previous
//
#include <hip/hip_runtime.h>
#include <math.h>

#define NPTS 50000
#define MN 1024
#define KK 64
#define DPT 64
#define DN 256
#define BCORR 256
#define OUTC 1024
#define OTI 100
#define NEGV (-1e4f)
#define EPSV 1e-8f
#define CAPL 512
#define CCAP 16384
#define HBLK 256   // blocks for histogram passes
#define RCH 2048   // rank-kernel LDS chunk

// ---------------- utility ----------------
__global__ void zero_all_kernel(int* cnt_s, int* cnt_t, int* ci_t, int* ci_s,
                                float* tpout){
  int t=blockIdx.x*256+threadIdx.x;
  if (t<MN){ cnt_s[t]=0; cnt_t[t]=0; }
  if (t<BCORR){ ci_t[t]=0; ci_s[t]=0; }
  for (int i=t;i<OUTC*3*2+OUTC;i+=gridDim.x*256) tpout[i]=0.0f;
}

__device__ __forceinline__ float blockReduceSum256(float v, float* red){
  int t=threadIdx.x;
  red[t]=v; __syncthreads();
  #pragma unroll
  for (int s=128;s>0;s>>=1){ if(t<s) red[t]+=red[t+s]; __syncthreads(); }
  float r=red[0]; __syncthreads();
  return r;
}

// node feats (fused tgt+src): out = l2norm(x @ W^T + b); sq = sum(out^2)
__global__ __launch_bounds__(256) void node_feat_kernel(
    const float* __restrict__ xt, const float* __restrict__ xs_,
    const float* __restrict__ W, const float* __restrict__ bias,
    float* __restrict__ outt, float* __restrict__ outs,
    float* __restrict__ sqt, float* __restrict__ sqs){
  __shared__ float xs[DN];
  __shared__ float red[256];
  int m=blockIdx.x, i=threadIdx.x;
  const float* x=(m<MN)? xt:xs_;
  float* out=(m<MN)? outt:outs;
  float* sq=(m<MN)? sqt:sqs;
  int mm=(m<MN)? m:m-MN;
  xs[i]=x[mm*DN+i];
  __syncthreads();
  float acc=bias[i];
  const float* wr=W+(size_t)i*DN;
  for (int k=0;k<DN;k++) acc=fmaf(wr[k],xs[k],acc);
  float ssq=blockReduceSum256(acc*acc,red);
  float o=acc/sqrtf(ssq);
  out[mm*DN+i]=o;
  float s2=blockReduceSum256(o*o,red);
  if(i==0) sq[mm]=s2;
}

// nearest node per point (fused src+tgt); nodes packed float4 (x,y,z,|n|^2)
__global__ __launch_bounds__(256) void p2n_kernel(
    const float* __restrict__ pts_s, const float* __restrict__ nd_s, int* __restrict__ o_s,
    const float* __restrict__ pts_t, const float* __restrict__ nd_t, int* __restrict__ o_t,
    int pb){
  __shared__ __align__(16) float4 nd[MN];
  int which=blockIdx.x>=pb;
  const float* pts=which? pts_t:pts_s;
  const float* nodes=which? nd_t:nd_s;
  int* p2n=which? o_t:o_s;
  int blk=which? blockIdx.x-pb : blockIdx.x;
  for (int j=threadIdx.x;j<MN;j+=256){
    float a=nodes[j*3+0], b=nodes[j*3+1], c=nodes[j*3+2];
    nd[j]=make_float4(a,b,c,a*a+b*b+c*c);
  }
  __syncthreads();
  int id=blk*256+threadIdx.x;
  if (id>=NPTS) return;
  float px=pts[id*3+0], py=pts[id*3+1], pz=pts[id*3+2];
  float pp=px*px+py*py+pz*pz;
  float best=3.4e38f; int bi=0;
  for (int j=0;j<MN;j++){
    float4 n=nd[j];
    float d=pp+n.w-2.0f*(px*n.x+py*n.y+pz*n.z);
    if (d<best){best=d;bi=j;}
  }
  p2n[id]=bi;
}

__global__ __launch_bounds__(256) void scatter_kernel(
    const int* __restrict__ p_s, int* __restrict__ c_s, int* __restrict__ l_s,
    const int* __restrict__ p_t, int* __restrict__ c_t, int* __restrict__ l_t,
    int pb){
  int which=blockIdx.x>=pb;
  const int* p2n=which? p_t:p_s;
  int* cnt=which? c_t:c_s;
  int* list=which? l_t:l_s;
  int blk=which? blockIdx.x-pb : blockIdx.x;
  int id=blk*256+threadIdx.x;
  if (id>=NPTS) return;
  int n=p2n[id];
  int t=atomicAdd(&cnt[n],1);
  if (t<CAPL) list[(size_t)n*CAPL+t]=id;
}

// per-node kNN (fused src+tgt)
__global__ __launch_bounds__(256) void knn_kernel(
    const float* __restrict__ pts_s, const float* __restrict__ nd_s,
    const int* __restrict__ c_s, const int* __restrict__ l_s, int* __restrict__ k_s,
    const float* __restrict__ pts_t, const float* __restrict__ nd_t,
    const int* __restrict__ c_t, const int* __restrict__ l_t, int* __restrict__ k_t){
  __shared__ float ds[CAPL];
  __shared__ int is[CAPL];
  int which=blockIdx.x>=MN;
  const float* pts=which? pts_t:pts_s;
  const float* nodes=which? nd_t:nd_s;
  const int* cnt=which? c_t:c_s;
  const int* list=which? l_t:l_s;
  int* knn=which? k_t:k_s;
  int m=which? blockIdx.x-MN : blockIdx.x;
  int c=cnt[m]; if (c>CAPL) c=CAPL;
  float ax=nodes[m*3+0], ay=nodes[m*3+1], az=nodes[m*3+2];
  float nn2=ax*ax+ay*ay+az*az;
  for (int e=threadIdx.x;e<c;e+=256){
    int p=list[(size_t)m*CAPL+e];
    float px=pts[p*3+0],py=pts[p*3+1],pz=pts[p*3+2];
    float pp=px*px+py*py+pz*pz;
    ds[e]=pp+nn2-2.0f*(px*ax+py*ay+pz*az);
    is[e]=p;
  }
  for (int k=threadIdx.x;k<KK;k+=256) knn[m*KK+k]=NPTS;
  __syncthreads();
  for (int e=threadIdx.x;e<c;e+=256){
    float d=ds[e]; int p=is[e]; int r=0;
    for (int j=0;j<c;j++){
      float dj=ds[j];
      r += (dj<d || (dj==d && is[j]<p)) ? 1 : 0;
    }
    if (r<KK) knn[m*KK+r]=p;
  }
}

// coarse scores as tiled GEMM
__global__ __launch_bounds__(256) void coarse_score_kernel(
    const float* __restrict__ tf, const float* __restrict__ sf,
    const float* __restrict__ tt, const float* __restrict__ ssv,
    const int* __restrict__ cnt_t, const int* __restrict__ cnt_s, float* __restrict__ S){
  __shared__ float tas[64][64];   // [k][r]
  __shared__ float sbs[64][64];   // [k][c]
  __shared__ float tta[64], ssa[64], tva[64], sva[64];
  int bi=blockIdx.x>>4, bj=blockIdx.x&15;
  int t=threadIdx.x, r=t&63, kq=t>>6, tx=t&15, ty=t>>4;
  if (kq==0){ tta[r]=tt[bi*64+r]; tva[r]=(cnt_t[bi*64+r]>0)?1.f:0.f; }
  if (kq==1){ ssa[r]=ssv[bj*64+r]; sva[r]=(cnt_s[bj*64+r]>0)?1.f:0.f; }
  float acc[4][4]={};
  const float* ta=tf+((size_t)bi*64)*DN;
  const float* sa=sf+((size_t)bj*64)*DN;
  for (int kc=0;kc<DN;kc+=64){
    __syncthreads();
    const float* tr_=ta+(size_t)r*DN+kc+kq*16;
    const float* sr_=sa+(size_t)r*DN+kc+kq*16;
    #pragma unroll
    for (int j4=0;j4<4;j4++){
      float4 v=*(const float4*)(tr_+4*j4);
      tas[kq*16+4*j4+0][r]=v.x; tas[kq*16+4*j4+1][r]=v.y;
      tas[kq*16+4*j4+2][r]=v.z; tas[kq*16+4*j4+3][r]=v.w;
      float4 w=*(const float4*)(sr_+4*j4);
      sbs[kq*16+4*j4+0][r]=w.x; sbs[kq*16+4*j4+1][r]=w.y;
      sbs[kq*16+4*j4+2][r]=w.z; sbs[kq*16+4*j4+3][r]=w.w;
    }
    __syncthreads();
    #pragma unroll
    for (int kk=0;kk<64;kk++){
      float4 a4=*(const float4*)(&tas[kk][4*ty]);
      float4 b4=*(const float4*)(&sbs[kk][4*tx]);
      float av[4]={a4.x,a4.y,a4.z,a4.w};
      float bv[4]={b4.x,b4.y,b4.z,b4.w};
      #pragma unroll
      for (int i=0;i<4;i++)
        #pragma unroll
        for (int j=0;j<4;j++) acc[i][j]=fmaf(av[i],bv[j],acc[i][j]);
    }
  }
  __syncthreads();
  #pragma unroll
  for (int i=0;i<4;i++){
    int rr=4*ty+i;
    #pragma unroll
    for (int j=0;j<4;j++){
      int cc=4*tx+j;
      float d=tta[rr]+ssa[cc]-2.0f*acc[i][j];
      float v=expf(-d);
      S[(size_t)(bi*64+rr)*MN + bj*64+cc]=(tva[rr]>0.f && sva[cc]>0.f)? v:0.0f;
    }
  }
}

// fused row+col sums
__global__ __launch_bounds__(256) void sums_kernel(
    const float* __restrict__ S, float* __restrict__ rs, float* __restrict__ cs){
  __shared__ float red[256];
  __shared__ float red2[16][17];
  if (blockIdx.x<MN){
    int i=blockIdx.x;
    float a=0;
    for (int j=threadIdx.x;j<MN;j+=256) a+=S[(size_t)i*MN+j];
    float r=blockReduceSum256(a,red);
    if (threadIdx.x==0) rs[i]=r;
  } else {
    int j0=(blockIdx.x-MN)*16;
    int tx=threadIdx.x&15, ty=threadIdx.x>>4;
    float a=0;
    for (int i=ty;i<MN;i+=16) a+=S[(size_t)i*MN + j0+tx];
    red2[ty][tx]=a; __syncthreads();
    if (ty==0){
      float s=0;
      #pragma unroll
      for (int q=0;q<16;q++) s+=red2[q][tx];
      cs[j0+tx]=s;
    }
  }
}
// dual normalization fused with L1 histogram pass
__global__ __launch_bounds__(256) void dualnorm_hist_kernel(
    float* __restrict__ S, const float* __restrict__ rs, const float* __restrict__ cs,
    unsigned* __restrict__ partial){
  __shared__ unsigned lh[256];
  lh[threadIdx.x]=0u; __syncthreads();
  for (int idx=blockIdx.x*256+threadIdx.x; idx<MN*MN; idx+=gridDim.x*256){
    int i=idx>>10, j=idx&1023;
    float v=S[idx];
    v=(v/(rs[i]+EPSV))*(v/(cs[j]+EPSV));
    S[idx]=v;
    if (v>0.0f) atomicAdd(&lh[__float_as_uint(v)>>24],1u);
  }
  __syncthreads();
  partial[blockIdx.x*256+threadIdx.x]=lh[threadIdx.x];
}

// ---------- deterministic top-k, three-level (8/16/24-bit) histogram ----------
// meta: [0]=T24 threshold, [1]=cand counter, [2]=CB(8b), [3]=above L1,
//       [4]=above L2, [5]=T16
__global__ __launch_bounds__(256) void scan_coarse_kernel(
    const unsigned* __restrict__ partial, int nblk, int k, unsigned* __restrict__ meta){
  __shared__ unsigned h[256];
  int t=threadIdx.x;
  unsigned a=0;
  for (int i=0;i<nblk;i++) a+=partial[(size_t)i*256+t];
  h[t]=a; __syncthreads();
  if (t==0){
    unsigned cum=0; int cb=-1; unsigned above=0;
    for (int b=255;b>=0;b--){
      if (cum+h[b] >= (unsigned)k){ cb=b; above=cum; break; }
      cum+=h[b];
    }
    if (cb<0){ cb=0; above=cum-h[0]; }
    meta[2]=(unsigned)cb; meta[3]=above;
  }
}
__global__ __launch_bounds__(256) void hist_fine_kernel(
    const float* __restrict__ arr, int n, const unsigned* __restrict__ meta,
    unsigned* __restrict__ partial){
  __shared__ unsigned lh[256];
  lh[threadIdx.x]=0u; __syncthreads();
  unsigned CB=meta[2];
  for (int i=blockIdx.x*256+threadIdx.x; i<n; i+=gridDim.x*256){
    float v=arr[i];
    unsigned b=__float_as_uint(v);
    if (v>0.0f && (b>>24)==CB) atomicAdd(&lh[(b>>16)&255u],1u);
  }
  __syncthreads();
  partial[blockIdx.x*256+threadIdx.x]=lh[threadIdx.x];
}
__global__ __launch_bounds__(256) void scan_fine_kernel(
    const unsigned* __restrict__ partial, int nblk, int k, unsigned* __restrict__ meta){
  __shared__ unsigned h[256];
  int t=threadIdx.x;
  unsigned a=0;
  for (int i=0;i<nblk;i++) a+=partial[(size_t)i*256+t];
  h[t]=a; __syncthreads();
  if (t==0){
    unsigned cum=meta[3]; int sb=0;
    for (int b=255;b>=0;b--){
      if (cum+h[b] >= (unsigned)k){ sb=b; break; }
      cum+=h[b];
    }
    meta[5]=meta[2]*256u+(unsigned)sb;   // T16
    meta[4]=cum;                          // count strictly above T16 bucket
  }
}
__global__ __launch_bounds__(256) void hist_fine2_kernel(
    const float* __restrict__ arr, int n, const unsigned* __restrict__ meta,
    unsigned* __restrict__ partial){
  __shared__ unsigned lh[256];
  lh[threadIdx.x]=0u; __syncthreads();
  unsigned T16=meta[5];
  for (int i=blockIdx.x*256+threadIdx.x; i<n; i+=gridDim.x*256){
    float v=arr[i];
    unsigned b=__float_as_uint(v);
    if (v>0.0f && (b>>16)==T16) atomicAdd(&lh[(b>>8)&255u],1u);
  }
  __syncthreads();
  partial[blockIdx.x*256+threadIdx.x]=lh[threadIdx.x];
}
__global__ __launch_bounds__(256) void scan_fine2_kernel(
    const unsigned* __restrict__ partial, int nblk, int k, unsigned* __restrict__ meta){
  __shared__ unsigned h[256];
  int t=threadIdx.x;
  unsigned a=0;
  for (int i=0;i<nblk;i++) a+=partial[(size_t)i*256+t];
  h[t]=a; __syncthreads();
  if (t==0){
    unsigned cum=meta[4]; int sb=0;
    for (int b=255;b>=0;b--){
      if (cum+h[b] >= (unsigned)k){ sb=b; break; }
      cum+=h[b];
    }
    meta[0]=meta[5]*256u+(unsigned)sb;   // T24
    meta[1]=0u;
  }
}
__global__ void compact_kernel(const float* __restrict__ arr, int n,
                               const unsigned* __restrict__ meta,
                               float* __restrict__ cv, int* __restrict__ ci,
                               unsigned* __restrict__ cnt){
  unsigned T=meta[0];
  for (int i=blockIdx.x*blockDim.x+threadIdx.x; i<n; i+=gridDim.x*blockDim.x){
    float v=arr[i];
    if (v>0.0f && (__float_as_uint(v)>>8)>=T){
      unsigned p=atomicAdd(cnt,1u);
      if (p<CCAP){ cv[p]=v; ci[p]=i; }
    }
  }
}
// LDS-tiled exact rank (value desc, index asc)
__global__ __launch_bounds__(256) void rank_coarse_kernel(
    const float* __restrict__ cv, const int* __restrict__ ci, const unsigned* __restrict__ meta,
    int* __restrict__ ti, int* __restrict__ si){
  __shared__ __align__(16) float scv[RCH];
  __shared__ __align__(16) int sci[RCH];
  int c=(int)meta[1]; if (c>CCAP) c=CCAP;
  int t=blockIdx.x*256+threadIdx.x;
  bool act=(t<c);
  float v=0.0f; int idx=0;
  if (act){ v=cv[t]; idx=ci[t]; }
  int rk=0;
  for (int base=0;base<c;base+=RCH){
    int lim=min(RCH,c-base);
    __syncthreads();
    for (int j=threadIdx.x;j<lim;j+=256){ scv[j]=cv[base+j]; sci[j]=ci[base+j]; }
    __syncthreads();
    if (act){
      int j=0;
      for (;j+4<=lim;j+=4){
        float4 v4=*(const float4*)(scv+j);
        int4 i4=*(const int4*)(sci+j);
        rk += (v4.x>v||(v4.x==v&&i4.x<idx))?1:0;
        rk += (v4.y>v||(v4.y==v&&i4.y<idx))?1:0;
        rk += (v4.z>v||(v4.z==v&&i4.z<idx))?1:0;
        rk += (v4.w>v||(v4.w==v&&i4.w<idx))?1:0;
      }
      for (;j<lim;j++) rk += (scv[j]>v||(scv[j]==v&&sci[j]<idx))?1:0;
    }
  }
  if (act && rk<BCORR){ ti[rk]=idx/MN; si[rk]=idx%MN; }
}
__global__ __launch_bounds__(256) void rank_fine_kernel(
    const float* __restrict__ cv, const int* __restrict__ ci, const unsigned* __restrict__ meta,
    const int* __restrict__ sel_t, const int* __restrict__ sel_s,
    const float* __restrict__ tpts, const float* __restrict__ spts,
    float* __restrict__ tp, float* __restrict__ sp, float* __restrict__ cs){
  __shared__ __align__(16) float scv[RCH];
  __shared__ __align__(16) int sci[RCH];
  int c=(int)meta[1]; if (c>CCAP) c=CCAP;
  int t=blockIdx.x*256+threadIdx.x;
  bool act=(t<c);
  float v=0.0f; int idx=0;
  if (act){ v=cv[t]; idx=ci[t]; }
  int rk=0;
  for (int base=0;base<c;base+=RCH){
    int lim=min(RCH,c-base);
    __syncthreads();
    for (int j=threadIdx.x;j<lim;j+=256){ scv[j]=cv[base+j]; sci[j]=ci[base+j]; }
    __syncthreads();
    if (act){
      int j=0;
      for (;j+4<=lim;j+=4){
        float4 v4=*(const float4*)(scv+j);
        int4 i4=*(const int4*)(sci+j);
        rk += (v4.x>v||(v4.x==v&&i4.x<idx))?1:0;
        rk += (v4.y>v||(v4.y==v&&i4.y<idx))?1:0;
        rk += (v4.z>v||(v4.z==v&&i4.z<idx))?1:0;
        rk += (v4.w>v||(v4.w==v&&i4.w<idx))?1:0;
      }
      for (;j<lim;j++) rk += (scv[j]>v||(scv[j]==v&&sci[j]<idx))?1:0;
    }
  }
  if (act && rk<OUTC){
    int b=idx>>12, r=(idx>>6)&63, cc=idx&63;
    int tpi=sel_t[b*KK+r], spi=sel_s[b*KK+cc];
    float tx=0,ty=0,tz=0,sx=0,sy=0,sz=0;
    if (tpi<NPTS){ tx=tpts[tpi*3]; ty=tpts[tpi*3+1]; tz=tpts[tpi*3+2]; }
    if (spi<NPTS){ sx=spts[spi*3]; sy=spts[spi*3+1]; sz=spts[spi*3+2]; }
    tp[rk*3+0]=tx; tp[rk*3+1]=ty; tp[rk*3+2]=tz;
    sp[rk*3+0]=sx; sp[rk*3+1]=sy; sp[rk*3+2]=sz;
    cs[rk]=v;
  }
}

// ---------- patch assembly / OT / fine ----------
__global__ __launch_bounds__(256) void sel_feat_kernel(
    const int* __restrict__ ci_t, const int* __restrict__ knn_t, const float* __restrict__ ptf_t,
    const int* __restrict__ ci_s, const int* __restrict__ knn_s, const float* __restrict__ ptf_s,
    const float* __restrict__ W, const float* __restrict__ bias,
    float* __restrict__ out_t, float* __restrict__ out_s,
    int* __restrict__ sel_tO, int* __restrict__ sel_sO){
  __shared__ float Xs[64][64];   // [k][r]
  __shared__ float Ws[64][64];   // [k][o]
  __shared__ float pvf[64];
  int which=blockIdx.x>=1024;
  const int* cib=which? ci_s:ci_t;
  const int* knn=which? knn_s:knn_t;
  const float* ptf=which? ptf_s:ptf_t;
  float* out=which? out_s:out_t;
  int* sel=which? sel_sO:sel_tO;
  int blk=which? blockIdx.x-1024 : blockIdx.x;
  int bj=blk>>2, bo=blk&3;
  int t=threadIdx.x, r=t&63, kq=t>>6, tx=t&15, ty=t>>4;
  int p=knn[cib[bj]*KK+r];
  if (kq==0){
    pvf[r]=(p!=NPTS)?1.f:0.f;
    if (bo==0) sel[bj*KK+r]=p;
  }
  const float* xr=ptf+(size_t)p*DPT+kq*16;
  #pragma unroll
  for (int j4=0;j4<4;j4++){
    float4 v=(p==NPTS)? make_float4(0.f,0.f,0.f,0.f) : *(const float4*)(xr+4*j4);
    Xs[kq*16+4*j4+0][r]=v.x; Xs[kq*16+4*j4+1][r]=v.y;
    Xs[kq*16+4*j4+2][r]=v.z; Xs[kq*16+4*j4+3][r]=v.w;
  }
  const float* wr=W+(size_t)(bo*64+r)*DPT+kq*16;
  #pragma unroll
  for (int j4=0;j4<4;j4++){
    float4 w=*(const float4*)(wr+4*j4);
    Ws[kq*16+4*j4+0][r]=w.x; Ws[kq*16+4*j4+1][r]=w.y;
    Ws[kq*16+4*j4+2][r]=w.z; Ws[kq*16+4*j4+3][r]=w.w;
  }
  __syncthreads();
  float acc[4][4]={};
  #pragma unroll
  for (int kk=0;kk<64;kk++){
    float4 a4=*(const float4*)(&Xs[kk][4*ty]);
    float4 w4=*(const float4*)(&Ws[kk][4*tx]);
    float av[4]={a4.x,a4.y,a4.z,a4.w};
    float wv[4]={w4.x,w4.y,w4.z,w4.w};
    #pragma unroll
    for (int i=0;i<4;i++)
      #pragma unroll
      for (int j=0;j<4;j++) acc[i][j]=fmaf(av[i],wv[j],acc[i][j]);
  }
  #pragma unroll
  for (int i=0;i<4;i++){
    int rr=4*ty+i;
    #pragma unroll
    for (int j=0;j<4;j++){
      int oo=4*tx+j;
      float v=acc[i][j]+bias[bo*64+oo];
      out[(size_t)(bj*64+rr)*DN + bo*64+oo]= (pvf[rr]>0.f)? v : 0.0f;
    }
  }
}

// OT input P (65x65) per batch as tiled GEMM + dustbin/mask epilogue
__global__ __launch_bounds__(256) void pbuild_kernel(
    const float* __restrict__ ft, const float* __restrict__ fs,
    const int* __restrict__ sel_t, const int* __restrict__ sel_s,
    const float* __restrict__ alpha_p, float* __restrict__ P){
  __shared__ float tas[64][64];
  __shared__ float sbs[64][64];
  __shared__ float tmv[64], smv[64];
  int b=blockIdx.x, t=threadIdx.x;
  int r=t&63, kq=t>>6, tx=t&15, ty=t>>4;
  if (kq==0) tmv[r]=(sel_t[b*KK+r]!=NPTS)?1.f:0.f;
  if (kq==1) smv[r]=(sel_s[b*KK+r]!=NPTS)?1.f:0.f;
  float acc[4][4]={};
  const float* tb=ft+(size_t)b*KK*DN;
  const float* sb=fs+(size_t)b*KK*DN;
  for (int kc=0;kc<DN;kc+=64){
    __syncthreads();
    const float* tr_=tb+(size_t)r*DN+kc+kq*16;
    const float* sr_=sb+(size_t)r*DN+kc+kq*16;
    #pragma unroll
    for (int j4=0;j4<4;j4++){
      float4 v=*(const float4*)(tr_+4*j4);
      tas[kq*16+4*j4+0][r]=v.x; tas[kq*16+4*j4+1][r]=v.y;
      tas[kq*16+4*j4+2][r]=v.z; tas[kq*16+4*j4+3][r]=v.w;
      float4 w=*(const float4*)(sr_+4*j4);
      sbs[kq*16+4*j4+0][r]=w.x; sbs[kq*16+4*j4+1][r]=w.y;
      sbs[kq*16+4*j4+2][r]=w.z; sbs[kq*16+4*j4+3][r]=w.w;
    }
    __syncthreads();
    #pragma unroll
    for (int kk=0;kk<64;kk++){
      float4 a4=*(const float4*)(&tas[kk][4*ty]);
      float4 b4=*(const float4*)(&sbs[kk][4*tx]);
      float av[4]={a4.x,a4.y,a4.z,a4.w};
      float bv[4]={b4.x,b4.y,b4.z,b4.w};
      #pragma unroll
      for (int i=0;i<4;i++)
        #pragma unroll
        for (int j=0;j<4;j++) acc[i][j]=fmaf(av[i],bv[j],acc[i][j]);
    }
  }
  __syncthreads();
  float alpha=alpha_p[0];
  float* Pb=P+(size_t)b*65*65;
  #pragma unroll
  for (int i=0;i<4;i++){
    int rr=4*ty+i;
    bool tok=tmv[rr]>0.f;
    #pragma unroll
    for (int j=0;j<4;j++){
      int cc=4*tx+j;
      bool invm=(!tok)||(smv[cc]<=0.f);
      Pb[rr*65+cc]= invm ? NEGV : acc[i][j]*0.0625f;
    }
  }
  if (t<64){
    Pb[64*65+t]=(smv[t]<=0.f)? NEGV : alpha;
    Pb[t*65+64]=(tmv[t]<=0.f)? NEGV : alpha;
  }
  if (t==64) Pb[64*65+64]=alpha;
}

// Sinkhorn linear-domain, 4 waves per batch, column-split, 2 barriers/iter.
// Chunk broadcasts via per-wave PRIVATE LDS copies (UsW/VsW[w]) — same-wave
// write->read, no barrier, no ds_bpermute. Bitwise-exact early exit: once
// U,V,U64,V64 are bit-identical to the previous iteration, all remaining
// iterations are no-ops, so breaking reproduces the 100-iter result exactly.
__global__ __launch_bounds__(256,1) void ot_kernel(
    float* __restrict__ P, const int* __restrict__ sel_t, const int* __restrict__ sel_s){
  __shared__ float Ps[4225];
  __shared__ __align__(16) float partU[4][72], partV[4][72];
  __shared__ __align__(16) float pu64[4], pusv[4], pv64[4], pvsv[4];
  __shared__ __align__(16) float UsW[4][72], VsW[4][72];
  __shared__ float ufs[65], vfs[65];
  int b=blockIdx.x, t=threadIdx.x, w=t>>6, l=t&63;
  float* Pg=P+(size_t)b*4225;
  for (int e=t;e<4225;e+=256) Ps[e]=Pg[e];
  bool rv=(sel_t[b*KK+l]!=NPTS);
  bool cv=(sel_s[b*KK+l]!=NPTS);
  int nr=(int)__popcll(__ballot(rv));
  int nc=(int)__popcll(__ballot(cv));
  float inv=1.0f/(float)(nr+nc);
  float nrm=-logf((float)(nr+nc));
  float mu_l=inv, nu_l=inv, mu64=(float)nc*inv, nu64=(float)nr*inv;
  bool anyInvR=(nr<KK), anyInvC=(nc<KK);
  VsW[w][l]=1.0f;                       // own-wave copy; no barrier needed
  __syncthreads();
  const int c0=16*w;
  float aQ[16], bQ[16], r64Q[16], c64Q[16];
  #pragma unroll
  for (int j=0;j<16;j++){
    aQ[j]  =expf(Ps[l*65+c0+j]);
    bQ[j]  =expf(Ps[(c0+j)*65+l]);
    r64Q[j]=expf(Ps[64*65+c0+j]);
    c64Q[j]=expf(Ps[(c0+j)*65+64]);
  }
  float a64=expf(Ps[l*65+64]);
  float b64v=expf(Ps[64*65+l]);
  float k6464=expf(Ps[4224]);
  float U_l, V_l=1.0f, U64, V64=1.0f;
  unsigned Upb=0xFFFFFFFFu, Vpb=0xFFFFFFFFu, U64pb=0xFFFFFFFFu, V64pb=0xFFFFFFFFu;

  for (int it=0; it<OTI; ++it){
    // ---- u-pass: V chunk from own-wave LDS copy ----
    float p0=0,p1=0,p2=0,p3=0, d0=0,d1=0,d2=0,d3=0, z0=0,z1=0,z2=0,z3=0;
    #pragma unroll
    for (int j4=0;j4<4;j4++){
      float4 vv=*(const float4*)(&VsW[w][4*j4+ (c0&63)]);  // uniform broadcast
      p0=fmaf(aQ[4*j4+0],vv.x,p0); p1=fmaf(aQ[4*j4+1],vv.y,p1);
      p2=fmaf(aQ[4*j4+2],vv.z,p2); p3=fmaf(aQ[4*j4+3],vv.w,p3);
      d0=fmaf(r64Q[4*j4+0],vv.x,d0); d1=fmaf(r64Q[4*j4+1],vv.y,d1);
      d2=fmaf(r64Q[4*j4+2],vv.z,d2); d3=fmaf(r64Q[4*j4+3],vv.w,d3);
      z0+=vv.x; z1+=vv.y; z2+=vv.z; z3+=vv.w;
    }
    partU[w][l]=(p0+p1)+(p2+p3);
    if (l==0){ pu64[w]=(d0+d1)+(d2+d3); pusv[w]=(z0+z1)+(z2+z3); }
    __syncthreads();
    {
      float s=partU[0][l]+partU[1][l]+partU[2][l]+partU[3][l];
      float4 d4=*(const float4*)pu64;
      float srow=s+a64*V64;
      float s64=(d4.x+d4.y)+(d4.z+d4.w)+k6464*V64;
      U64=mu64/s64;
      if (anyInvR){
        float4 z4=*(const float4*)pusv;
        float sv=(z4.x+z4.y)+(z4.z+z4.w)+V64;
        U_l = rv ? (mu_l/srow) : (1.0f/sv);
      } else U_l = mu_l/srow;
      UsW[w][l]=U_l;                    // own-wave copy for v-pass
    }
    // ---- v-pass: U chunk from own-wave LDS copy ----
    float q0=0,q1=0,q2=0,q3=0, e0=0,e1=0,e2=0,e3=0, y0=0,y1=0,y2=0,y3=0;
    #pragma unroll
    for (int j4=0;j4<4;j4++){
      float4 uu=*(const float4*)(&UsW[w][4*j4+ (c0&63)]);
      q0=fmaf(bQ[4*j4+0],uu.x,q0); q1=fmaf(bQ[4*j4+1],uu.y,q1);
      q2=fmaf(bQ[4*j4+2],uu.z,q2); q3=fmaf(bQ[4*j4+3],uu.w,q3);
      e0=fmaf(c64Q[4*j4+0],uu.x,e0); e1=fmaf(c64Q[4*j4+1],uu.y,e1);
      e2=fmaf(c64Q[4*j4+2],uu.z,e2); e3=fmaf(c64Q[4*j4+3],uu.w,e3);
      y0+=uu.x; y1+=uu.y; y2+=uu.z; y3+=uu.w;
    }
    partV[w][l]=(q0+q1)+(q2+q3);
    if (l==0){ pv64[w]=(e0+e1)+(e2+e3); pvsv[w]=(y0+y1)+(y2+y3); }
    __syncthreads();
    {
      float sc=partV[0][l]+partV[1][l]+partV[2][l]+partV[3][l];
      float4 e4=*(const float4*)pv64;
      float scol=sc+b64v*U64;
      float s64v=(e4.x+e4.y)+(e4.z+e4.w)+k6464*U64;
      V64=nu64/s64v;
      if (anyInvC){
        float4 y4=*(const float4*)pvsv;
        float su=(y4.x+y4.y)+(y4.z+y4.w)+U64;
        V_l = cv ? (nu_l/scol) : (1.0f/su);
      } else V_l = nu_l/scol;
      VsW[w][l]=V_l;                    // own-wave copy for next u-pass
    }
    // ---- bitwise-exact convergence (uniform across waves) ----
    unsigned Ub=__float_as_uint(U_l), Vb=__float_as_uint(V_l);
    unsigned U64b=__float_as_uint(U64), V64b=__float_as_uint(V64);
    bool same=(Ub==Upb)&&(Vb==Vpb)&&(U64b==U64pb)&&(V64b==V64pb);
    Upb=Ub; Vpb=Vb; U64pb=U64b; V64pb=V64b;
    if (__ballot(same)==~0ULL) break;
  }
  if (w==0){
    ufs[l]=logf(U_l); vfs[l]=logf(V_l);
    if (l==0){ ufs[64]=logf(U64); vfs[64]=logf(V64); }
  }
  __syncthreads();
  for (int e=t;e<4225;e+=256){
    int r=e/65, c=e-65*r;
    Pg[e]=Ps[e]+ufs[r]+vfs[c]-nrm;
  }
}

// fine prep fused with L1 histogram of the masked scores
__global__ __launch_bounds__(256) void fineprep_kernel(
    const float* __restrict__ P, const int* __restrict__ sel_t, const int* __restrict__ sel_s,
    float* __restrict__ smout, unsigned* __restrict__ partial){
  __shared__ float s[KK*KK];
  __shared__ unsigned long long rowm[KK], colm[KK];
  __shared__ int tmk[KK], smk[KK];
  __shared__ unsigned lh[256];
  int b=blockIdx.x, t=threadIdx.x;
  lh[t]=0u;
  const float* Pb=P+(size_t)b*65*65;
  for (int e=t;e<KK*KK;e+=256){
    int r=e>>6, c=e&63;
    s[e]=expf(Pb[r*65+c]);
  }
  if (t<KK){ tmk[t]=(sel_t[b*KK+t]!=NPTS); smk[t]=(sel_s[b*KK+t]!=NPTS); }
  __syncthreads();
  if (t<KK){
    float v1=-1,v2=-1,v3=-1; int i1=0,i2=0,i3=0;
    const float* row=s+t*KK;
    for (int c=0;c<KK;c++){ float v=row[c];
      if (v>v1){v3=v2;i3=i2;v2=v1;i2=i1;v1=v;i1=c;}
      else if (v>v2){v3=v2;i3=i2;v2=v;i2=c;}
      else if (v>v3){v3=v;i3=c;}
    }
    rowm[t]=(1ULL<<i1)|(1ULL<<i2)|(1ULL<<i3);
  } else if (t<2*KK){
    int c=t-KK;
    float v1=-1,v2=-1,v3=-1; int i1=0,i2=0,i3=0;
    for (int r=0;r<KK;r++){ float v=s[r*KK+c];
      if (v>v1){v3=v2;i3=i2;v2=v1;i2=i1;v1=v;i1=r;}
      else if (v>v2){v3=v2;i3=i2;v2=v;i2=r;}
      else if (v>v3){v3=v;i3=r;}
    }
    colm[c]=(1ULL<<i1)|(1ULL<<i2)|(1ULL<<i3);
  }
  __syncthreads();
  for (int e=t;e<KK*KK;e+=256){
    int r=e>>6, c=e&63;
    float v=s[e];
    bool keep = ((rowm[r]>>c)&1ULL) && ((colm[c]>>r)&1ULL) && (v>0.05f) && tmk[r] && smk[c];
    float o= keep? v : 0.0f;
    smout[(size_t)b*KK*KK+e]=o;
    if (o>0.0f) atomicAdd(&lh[__float_as_uint(o)>>24],1u);
  }
  __syncthreads();
  partial[b*256+t]=lh[t];
}

extern "C" void kernel_launch(void* const* d_in, const int* in_sizes, int n_in,
                              void* d_out, int out_size, void* d_ws, size_t ws_size,
                              hipStream_t stream){
  const float* src_pts=(const float*)d_in[0];
  const float* tgt_pts=(const float*)d_in[1];
  const float* src_pf =(const float*)d_in[2];
  const float* tgt_pf =(const float*)d_in[3];
  const float* src_nf =(const float*)d_in[4];
  const float* tgt_nf =(const float*)d_in[5];
  const float* src_nx =(const float*)d_in[6];
  const float* tgt_nx =(const float*)d_in[7];
  const float* cw=(const float*)d_in[8];
  const float* cb=(const float*)d_in[9];
  const float* fw=(const float*)d_in[10];
  const float* fb=(const float*)d_in[11];
  const float* alpha=(const float*)d_in[12];

  char* ws=(char*)d_ws;
  size_t off=0;
  auto A=[&](size_t bytes)->char*{
    char* p=ws+off; off+=(bytes+255)&~(size_t)255; return p; };

  float* tf    =(float*)A((size_t)MN*DN*4);
  float* sfb   =(float*)A((size_t)MN*DN*4);
  float* tt    =(float*)A(MN*4);
  float* ssv   =(float*)A(MN*4);
  int*   p2n_s =(int*)A((size_t)NPTS*4);
  int*   p2n_t =(int*)A((size_t)NPTS*4);
  int*   cnt_s =(int*)A(MN*4);
  int*   cnt_t =(int*)A(MN*4);
  int*   list_s=(int*)A((size_t)MN*CAPL*4);
  int*   list_t=(int*)A((size_t)MN*CAPL*4);
  int*   knn_s =(int*)A((size_t)MN*KK*4);
  int*   knn_t =(int*)A((size_t)MN*KK*4);
  float* Smat  =(float*)A((size_t)MN*MN*4);
  unsigned* partial=(unsigned*)A((size_t)HBLK*256*4);
  unsigned* meta=(unsigned*)A(256);
  float* cand_v=(float*)A((size_t)CCAP*4);
  int*   cand_i=(int*)A((size_t)CCAP*4);
  int*   ci_t  =(int*)A(BCORR*4);
  int*   ci_s  =(int*)A(BCORR*4);
  int*   sel_t =(int*)A((size_t)BCORR*KK*4);
  int*   sel_s =(int*)A((size_t)BCORR*KK*4);
  float* feat_t=(float*)A((size_t)BCORR*KK*DN*4);
  float* feat_s=(float*)A((size_t)BCORR*KK*DN*4);
  float* smf   =(float*)A((size_t)BCORR*KK*KK*4);
  float* rs    =(float*)A(MN*4);
  float* csum  =(float*)A(MN*4);

  float* out=(float*)d_out;
  float* msout=out;
  float* tpout=out+(size_t)BCORR*65*65;
  float* spout=tpout+(size_t)OUTC*3;
  float* csout=spout+(size_t)OUTC*3;

  const int PB=(NPTS+255)/256;

  zero_all_kernel<<<28,256,0,stream>>>(cnt_s,cnt_t,ci_t,ci_s,tpout);
  node_feat_kernel<<<2*MN,256,0,stream>>>(tgt_nf,src_nf,cw,cb,tf,sfb,tt,ssv);
  p2n_kernel<<<2*PB,256,0,stream>>>(src_pts,src_nx,p2n_s,tgt_pts,tgt_nx,p2n_t,PB);
  scatter_kernel<<<2*PB,256,0,stream>>>(p2n_s,cnt_s,list_s,p2n_t,cnt_t,list_t,PB);
  knn_kernel<<<2*MN,256,0,stream>>>(src_pts,src_nx,cnt_s,list_s,knn_s,
                                    tgt_pts,tgt_nx,cnt_t,list_t,knn_t);

  coarse_score_kernel<<<256,256,0,stream>>>(tf,sfb,tt,ssv,cnt_t,cnt_s,Smat);
  sums_kernel<<<MN+64,256,0,stream>>>(Smat,rs,csum);
  dualnorm_hist_kernel<<<HBLK,256,0,stream>>>(Smat,rs,csum,partial);

  scan_coarse_kernel<<<1,256,0,stream>>>(partial,HBLK,BCORR,meta);
  hist_fine_kernel<<<HBLK,256,0,stream>>>(Smat,MN*MN,meta,partial);
  scan_fine_kernel<<<1,256,0,stream>>>(partial,HBLK,BCORR,meta);
  hist_fine2_kernel<<<HBLK,256,0,stream>>>(Smat,MN*MN,meta,partial);
  scan_fine2_kernel<<<1,256,0,stream>>>(partial,HBLK,BCORR,meta);
  compact_kernel<<<2048,256,0,stream>>>(Smat,MN*MN,meta,cand_v,cand_i,meta+1);
  rank_coarse_kernel<<<CCAP/256,256,0,stream>>>(cand_v,cand_i,meta,ci_t,ci_s);

  sel_feat_kernel<<<2048,256,0,stream>>>(ci_t,knn_t,tgt_pf, ci_s,knn_s,src_pf,
                                         fw,fb,feat_t,feat_s,sel_t,sel_s);

  pbuild_kernel<<<BCORR,256,0,stream>>>(feat_t,feat_s,sel_t,sel_s,alpha,msout);
  ot_kernel<<<BCORR,256,0,stream>>>(msout,sel_t,sel_s);

  fineprep_kernel<<<BCORR,256,0,stream>>>(msout,sel_t,sel_s,smf,partial);
  scan_coarse_kernel<<<1,256,0,stream>>>(partial,BCORR,OUTC,meta);
  hist_fine_kernel<<<HBLK,256,0,stream>>>(smf,BCORR*KK*KK,meta,partial);
  scan_fine_kernel<<<1,256,0,stream>>>(partial,HBLK,OUTC,meta);
  hist_fine2_kernel<<<HBLK,256,0,stream>>>(smf,BCORR*KK*KK,meta,partial);
  scan_fine2_kernel<<<1,256,0,stream>>>(partial,HBLK,OUTC,meta);
  compact_kernel<<<2048,256,0,stream>>>(smf,BCORR*KK*KK,meta,cand_v,cand_i,meta+1);
  rank_fine_kernel<<<CCAP/256,256,0,stream>>>(cand_v,cand_i,meta,sel_t,sel_s,
                                              tgt_pts,src_pts,tpout,spout,csout);
}

// Round 12
// 583.699 us; speedup vs baseline: 2.1984x; 1.1538x over previous
//
#include <hip/hip_runtime.h>
#include <math.h>

#define NPTS 50000
#define MN 1024
#define KK 64
#define DPT 64
#define DN 256
#define BCORR 256
#define OUTC 1024
#define OTI 100
#define NEGV (-1e4f)
#define EPSV 1e-8f
#define CAPL 512
#define CCAP 16384
#define HBLK 256   // blocks for histogram passes (and partial-buffer depth)
#define RCH 2048   // rank-kernel LDS chunk

// ---------------- utility ----------------
__global__ void zero_all_kernel(int* cnt_s, int* cnt_t, int* ci_t, int* ci_s,
                                float* tpout){
  int t=blockIdx.x*256+threadIdx.x;
  if (t<MN){ cnt_s[t]=0; cnt_t[t]=0; }
  if (t<BCORR){ ci_t[t]=0; ci_s[t]=0; }
  for (int i=t;i<OUTC*3*2+OUTC;i+=gridDim.x*256) tpout[i]=0.0f;
}

__device__ __forceinline__ float blockReduceSum256(float v, float* red){
  int t=threadIdx.x;
  red[t]=v; __syncthreads();
  #pragma unroll
  for (int s=128;s>0;s>>=1){ if(t<s) red[t]+=red[t+s]; __syncthreads(); }
  float r=red[0]; __syncthreads();
  return r;
}

// node feats (fused tgt+src): out = l2norm(x @ W^T + b); sq = sum(out^2)
__global__ __launch_bounds__(256) void node_feat_kernel(
    const float* __restrict__ xt, const float* __restrict__ xs_,
    const float* __restrict__ W, const float* __restrict__ bias,
    float* __restrict__ outt, float* __restrict__ outs,
    float* __restrict__ sqt, float* __restrict__ sqs){
  __shared__ float xs[DN];
  __shared__ float red[256];
  int m=blockIdx.x, i=threadIdx.x;
  const float* x=(m<MN)? xt:xs_;
  float* out=(m<MN)? outt:outs;
  float* sq=(m<MN)? sqt:sqs;
  int mm=(m<MN)? m:m-MN;
  xs[i]=x[mm*DN+i];
  __syncthreads();
  float acc=bias[i];
  const float* wr=W+(size_t)i*DN;
  for (int k=0;k<DN;k++) acc=fmaf(wr[k],xs[k],acc);
  float ssq=blockReduceSum256(acc*acc,red);
  float o=acc/sqrtf(ssq);
  out[mm*DN+i]=o;
  float s2=blockReduceSum256(o*o,red);
  if(i==0) sq[mm]=s2;
}

// nearest node per point (fused src+tgt); nodes packed float4 (x,y,z,|n|^2)
__global__ __launch_bounds__(256) void p2n_kernel(
    const float* __restrict__ pts_s, const float* __restrict__ nd_s, int* __restrict__ o_s,
    const float* __restrict__ pts_t, const float* __restrict__ nd_t, int* __restrict__ o_t,
    int pb){
  __shared__ __align__(16) float4 nd[MN];
  int which=blockIdx.x>=pb;
  const float* pts=which? pts_t:pts_s;
  const float* nodes=which? nd_t:nd_s;
  int* p2n=which? o_t:o_s;
  int blk=which? blockIdx.x-pb : blockIdx.x;
  for (int j=threadIdx.x;j<MN;j+=256){
    float a=nodes[j*3+0], b=nodes[j*3+1], c=nodes[j*3+2];
    nd[j]=make_float4(a,b,c,a*a+b*b+c*c);
  }
  __syncthreads();
  int id=blk*256+threadIdx.x;
  if (id>=NPTS) return;
  float px=pts[id*3+0], py=pts[id*3+1], pz=pts[id*3+2];
  float pp=px*px+py*py+pz*pz;
  float best=3.4e38f; int bi=0;
  for (int j=0;j<MN;j++){
    float4 n=nd[j];
    float d=pp+n.w-2.0f*(px*n.x+py*n.y+pz*n.z);
    if (d<best){best=d;bi=j;}
  }
  p2n[id]=bi;
}

__global__ __launch_bounds__(256) void scatter_kernel(
    const int* __restrict__ p_s, int* __restrict__ c_s, int* __restrict__ l_s,
    const int* __restrict__ p_t, int* __restrict__ c_t, int* __restrict__ l_t,
    int pb){
  int which=blockIdx.x>=pb;
  const int* p2n=which? p_t:p_s;
  int* cnt=which? c_t:c_s;
  int* list=which? l_t:l_s;
  int blk=which? blockIdx.x-pb : blockIdx.x;
  int id=blk*256+threadIdx.x;
  if (id>=NPTS) return;
  int n=p2n[id];
  int t=atomicAdd(&cnt[n],1);
  if (t<CAPL) list[(size_t)n*CAPL+t]=id;
}

// per-node kNN (fused src+tgt)
__global__ __launch_bounds__(256) void knn_kernel(
    const float* __restrict__ pts_s, const float* __restrict__ nd_s,
    const int* __restrict__ c_s, const int* __restrict__ l_s, int* __restrict__ k_s,
    const float* __restrict__ pts_t, const float* __restrict__ nd_t,
    const int* __restrict__ c_t, const int* __restrict__ l_t, int* __restrict__ k_t){
  __shared__ float ds[CAPL];
  __shared__ int is[CAPL];
  int which=blockIdx.x>=MN;
  const float* pts=which? pts_t:pts_s;
  const float* nodes=which? nd_t:nd_s;
  const int* cnt=which? c_t:c_s;
  const int* list=which? l_t:l_s;
  int* knn=which? k_t:k_s;
  int m=which? blockIdx.x-MN : blockIdx.x;
  int c=cnt[m]; if (c>CAPL) c=CAPL;
  float ax=nodes[m*3+0], ay=nodes[m*3+1], az=nodes[m*3+2];
  float nn2=ax*ax+ay*ay+az*az;
  for (int e=threadIdx.x;e<c;e+=256){
    int p=list[(size_t)m*CAPL+e];
    float px=pts[p*3+0],py=pts[p*3+1],pz=pts[p*3+2];
    float pp=px*px+py*py+pz*pz;
    ds[e]=pp+nn2-2.0f*(px*ax+py*ay+pz*az);
    is[e]=p;
  }
  for (int k=threadIdx.x;k<KK;k+=256) knn[m*KK+k]=NPTS;
  __syncthreads();
  for (int e=threadIdx.x;e<c;e+=256){
    float d=ds[e]; int p=is[e]; int r=0;
    for (int j=0;j<c;j++){
      float dj=ds[j];
      r += (dj<d || (dj==d && is[j]<p)) ? 1 : 0;
    }
    if (r<KK) knn[m*KK+r]=p;
  }
}

// coarse scores as tiled GEMM
__global__ __launch_bounds__(256) void coarse_score_kernel(
    const float* __restrict__ tf, const float* __restrict__ sf,
    const float* __restrict__ tt, const float* __restrict__ ssv,
    const int* __restrict__ cnt_t, const int* __restrict__ cnt_s, float* __restrict__ S){
  __shared__ float tas[64][64];   // [k][r]
  __shared__ float sbs[64][64];   // [k][c]
  __shared__ float tta[64], ssa[64], tva[64], sva[64];
  int bi=blockIdx.x>>4, bj=blockIdx.x&15;
  int t=threadIdx.x, r=t&63, kq=t>>6, tx=t&15, ty=t>>4;
  if (kq==0){ tta[r]=tt[bi*64+r]; tva[r]=(cnt_t[bi*64+r]>0)?1.f:0.f; }
  if (kq==1){ ssa[r]=ssv[bj*64+r]; sva[r]=(cnt_s[bj*64+r]>0)?1.f:0.f; }
  float acc[4][4]={};
  const float* ta=tf+((size_t)bi*64)*DN;
  const float* sa=sf+((size_t)bj*64)*DN;
  for (int kc=0;kc<DN;kc+=64){
    __syncthreads();
    const float* tr_=ta+(size_t)r*DN+kc+kq*16;
    const float* sr_=sa+(size_t)r*DN+kc+kq*16;
    #pragma unroll
    for (int j4=0;j4<4;j4++){
      float4 v=*(const float4*)(tr_+4*j4);
      tas[kq*16+4*j4+0][r]=v.x; tas[kq*16+4*j4+1][r]=v.y;
      tas[kq*16+4*j4+2][r]=v.z; tas[kq*16+4*j4+3][r]=v.w;
      float4 w=*(const float4*)(sr_+4*j4);
      sbs[kq*16+4*j4+0][r]=w.x; sbs[kq*16+4*j4+1][r]=w.y;
      sbs[kq*16+4*j4+2][r]=w.z; sbs[kq*16+4*j4+3][r]=w.w;
    }
    __syncthreads();
    #pragma unroll
    for (int kk=0;kk<64;kk++){
      float4 a4=*(const float4*)(&tas[kk][4*ty]);
      float4 b4=*(const float4*)(&sbs[kk][4*tx]);
      float av[4]={a4.x,a4.y,a4.z,a4.w};
      float bv[4]={b4.x,b4.y,b4.z,b4.w};
      #pragma unroll
      for (int i=0;i<4;i++)
        #pragma unroll
        for (int j=0;j<4;j++) acc[i][j]=fmaf(av[i],bv[j],acc[i][j]);
    }
  }
  __syncthreads();
  #pragma unroll
  for (int i=0;i<4;i++){
    int rr=4*ty+i;
    #pragma unroll
    for (int j=0;j<4;j++){
      int cc=4*tx+j;
      float d=tta[rr]+ssa[cc]-2.0f*acc[i][j];
      float v=expf(-d);
      S[(size_t)(bi*64+rr)*MN + bj*64+cc]=(tva[rr]>0.f && sva[cc]>0.f)? v:0.0f;
    }
  }
}

// fused row+col sums
__global__ __launch_bounds__(256) void sums_kernel(
    const float* __restrict__ S, float* __restrict__ rs, float* __restrict__ cs){
  __shared__ float red[256];
  __shared__ float red2[16][17];
  if (blockIdx.x<MN){
    int i=blockIdx.x;
    float a=0;
    for (int j=threadIdx.x;j<MN;j+=256) a+=S[(size_t)i*MN+j];
    float r=blockReduceSum256(a,red);
    if (threadIdx.x==0) rs[i]=r;
  } else {
    int j0=(blockIdx.x-MN)*16;
    int tx=threadIdx.x&15, ty=threadIdx.x>>4;
    float a=0;
    for (int i=ty;i<MN;i+=16) a+=S[(size_t)i*MN + j0+tx];
    red2[ty][tx]=a; __syncthreads();
    if (ty==0){
      float s=0;
      #pragma unroll
      for (int q=0;q<16;q++) s+=red2[q][tx];
      cs[j0+tx]=s;
    }
  }
}
// dual normalization fused with L1 histogram pass -> partial1
__global__ __launch_bounds__(256) void dualnorm_hist_kernel(
    float* __restrict__ S, const float* __restrict__ rs, const float* __restrict__ cs,
    unsigned* __restrict__ partial1){
  __shared__ unsigned lh[256];
  lh[threadIdx.x]=0u; __syncthreads();
  for (int idx=blockIdx.x*256+threadIdx.x; idx<MN*MN; idx+=gridDim.x*256){
    int i=idx>>10, j=idx&1023;
    float v=S[idx];
    v=(v/(rs[i]+EPSV))*(v/(cs[j]+EPSV));
    S[idx]=v;
    if (v>0.0f) atomicAdd(&lh[__float_as_uint(v)>>24],1u);
  }
  __syncthreads();
  partial1[blockIdx.x*256+threadIdx.x]=lh[threadIdx.x];
}

// ---------- deterministic top-k, three-level histogram (scans fused) ----------
// scan helper: scans h[255..0], returns bucket where cum reaches k (or -1),
// *outcum = count strictly above that bucket (or start+sum if no hit).
__device__ __forceinline__ int scan_top(const unsigned* h, int k, unsigned start,
                                        unsigned* outcum){
  unsigned cum=start;
  for (int b=255;b>=0;b--){
    if (cum+h[b] >= (unsigned)k){ *outcum=cum; return b; }
    cum+=h[b];
  }
  *outcum=cum;
  return -1;
}
__device__ __forceinline__ void sum_partials(const unsigned* __restrict__ p,
                                             unsigned* h, int t){
  unsigned a=0;
  for (int i=0;i<HBLK;i++) a+=p[(size_t)i*256+t];
  h[t]=a;
}

// L2 histogram; per-block inline L1 scan
__global__ __launch_bounds__(256) void hist_fine_kernel(
    const float* __restrict__ arr, int n, int k,
    const unsigned* __restrict__ p1, unsigned* __restrict__ p2){
  __shared__ unsigned h[256];
  __shared__ unsigned lh[256];
  __shared__ unsigned cbS;
  int t=threadIdx.x;
  lh[t]=0u;
  sum_partials(p1,h,t);
  __syncthreads();
  if (t==0){
    unsigned ab; int cb=scan_top(h,k,0u,&ab);
    if (cb<0) cb=0;
    cbS=(unsigned)cb;
  }
  __syncthreads();
  unsigned CB=cbS;
  for (int i=blockIdx.x*256+t; i<n; i+=gridDim.x*256){
    float v=arr[i];
    unsigned b=__float_as_uint(v);
    if (v>0.0f && (b>>24)==CB) atomicAdd(&lh[(b>>16)&255u],1u);
  }
  __syncthreads();
  p2[blockIdx.x*256+t]=lh[t];
}
// L3 histogram; per-block inline L1+L2 scans; block0 resets cand counter
__global__ __launch_bounds__(256) void hist_fine2_kernel(
    const float* __restrict__ arr, int n, int k,
    const unsigned* __restrict__ p1, const unsigned* __restrict__ p2,
    unsigned* __restrict__ p3, unsigned* __restrict__ cnt){
  __shared__ unsigned h[256];
  __shared__ unsigned lh[256];
  __shared__ unsigned t16S;
  int t=threadIdx.x;
  if (blockIdx.x==0 && t==0) *cnt=0u;
  lh[t]=0u;
  sum_partials(p1,h,t);
  __syncthreads();
  __shared__ unsigned cbS, ab1S;
  if (t==0){
    unsigned ab; int cb=scan_top(h,k,0u,&ab);
    if (cb<0){ cb=0; ab=ab-h[0]; }
    cbS=(unsigned)cb; ab1S=ab;
  }
  __syncthreads();
  sum_partials(p2,h,t);
  __syncthreads();
  if (t==0){
    unsigned ab2; int sb=scan_top(h,k,ab1S,&ab2);
    if (sb<0) sb=0;
    t16S=cbS*256u+(unsigned)sb;
  }
  __syncthreads();
  unsigned T16=t16S;
  for (int i=blockIdx.x*256+t; i<n; i+=gridDim.x*256){
    float v=arr[i];
    unsigned b=__float_as_uint(v);
    if (v>0.0f && (b>>16)==T16) atomicAdd(&lh[(b>>8)&255u],1u);
  }
  __syncthreads();
  p3[blockIdx.x*256+t]=lh[t];
}
// compact with inline L1+L2+L3 scans (grid-stride, 256 blocks)
__global__ __launch_bounds__(256) void compact_kernel(
    const float* __restrict__ arr, int n, int k,
    const unsigned* __restrict__ p1, const unsigned* __restrict__ p2,
    const unsigned* __restrict__ p3,
    float* __restrict__ cv, int* __restrict__ ci, unsigned* __restrict__ cnt){
  __shared__ unsigned h[256];
  __shared__ unsigned cbS, ab1S, t16S, ab2S, t24S;
  int t=threadIdx.x;
  sum_partials(p1,h,t);
  __syncthreads();
  if (t==0){
    unsigned ab; int cb=scan_top(h,k,0u,&ab);
    if (cb<0){ cb=0; ab=ab-h[0]; }
    cbS=(unsigned)cb; ab1S=ab;
  }
  __syncthreads();
  sum_partials(p2,h,t);
  __syncthreads();
  if (t==0){
    unsigned ab2; int sb=scan_top(h,k,ab1S,&ab2);
    if (sb<0) sb=0;
    t16S=cbS*256u+(unsigned)sb; ab2S=ab2;
  }
  __syncthreads();
  sum_partials(p3,h,t);
  __syncthreads();
  if (t==0){
    unsigned ab3; int sb=scan_top(h,k,ab2S,&ab3);
    if (sb<0) sb=0;
    t24S=t16S*256u+(unsigned)sb;
  }
  __syncthreads();
  unsigned T=t24S;
  for (int i=blockIdx.x*256+t; i<n; i+=gridDim.x*256){
    float v=arr[i];
    if (v>0.0f && (__float_as_uint(v)>>8)>=T){
      unsigned p=atomicAdd(cnt,1u);
      if (p<CCAP){ cv[p]=v; ci[p]=i; }
    }
  }
}
// LDS-tiled exact rank (value desc, index asc)
__global__ __launch_bounds__(256) void rank_coarse_kernel(
    const float* __restrict__ cv, const int* __restrict__ ci, const unsigned* __restrict__ meta,
    int* __restrict__ ti, int* __restrict__ si){
  __shared__ __align__(16) float scv[RCH];
  __shared__ __align__(16) int sci[RCH];
  int c=(int)meta[1]; if (c>CCAP) c=CCAP;
  int t=blockIdx.x*256+threadIdx.x;
  bool act=(t<c);
  float v=0.0f; int idx=0;
  if (act){ v=cv[t]; idx=ci[t]; }
  int rk=0;
  for (int base=0;base<c;base+=RCH){
    int lim=min(RCH,c-base);
    __syncthreads();
    for (int j=threadIdx.x;j<lim;j+=256){ scv[j]=cv[base+j]; sci[j]=ci[base+j]; }
    __syncthreads();
    if (act){
      int j=0;
      for (;j+4<=lim;j+=4){
        float4 v4=*(const float4*)(scv+j);
        int4 i4=*(const int4*)(sci+j);
        rk += (v4.x>v||(v4.x==v&&i4.x<idx))?1:0;
        rk += (v4.y>v||(v4.y==v&&i4.y<idx))?1:0;
        rk += (v4.z>v||(v4.z==v&&i4.z<idx))?1:0;
        rk += (v4.w>v||(v4.w==v&&i4.w<idx))?1:0;
      }
      for (;j<lim;j++) rk += (scv[j]>v||(scv[j]==v&&sci[j]<idx))?1:0;
    }
  }
  if (act && rk<BCORR){ ti[rk]=idx/MN; si[rk]=idx%MN; }
}
__global__ __launch_bounds__(256) void rank_fine_kernel(
    const float* __restrict__ cv, const int* __restrict__ ci, const unsigned* __restrict__ meta,
    const int* __restrict__ sel_t, const int* __restrict__ sel_s,
    const float* __restrict__ tpts, const float* __restrict__ spts,
    float* __restrict__ tp, float* __restrict__ sp, float* __restrict__ cs){
  __shared__ __align__(16) float scv[RCH];
  __shared__ __align__(16) int sci[RCH];
  int c=(int)meta[1]; if (c>CCAP) c=CCAP;
  int t=blockIdx.x*256+threadIdx.x;
  bool act=(t<c);
  float v=0.0f; int idx=0;
  if (act){ v=cv[t]; idx=ci[t]; }
  int rk=0;
  for (int base=0;base<c;base+=RCH){
    int lim=min(RCH,c-base);
    __syncthreads();
    for (int j=threadIdx.x;j<lim;j+=256){ scv[j]=cv[base+j]; sci[j]=ci[base+j]; }
    __syncthreads();
    if (act){
      int j=0;
      for (;j+4<=lim;j+=4){
        float4 v4=*(const float4*)(scv+j);
        int4 i4=*(const int4*)(sci+j);
        rk += (v4.x>v||(v4.x==v&&i4.x<idx))?1:0;
        rk += (v4.y>v||(v4.y==v&&i4.y<idx))?1:0;
        rk += (v4.z>v||(v4.z==v&&i4.z<idx))?1:0;
        rk += (v4.w>v||(v4.w==v&&i4.w<idx))?1:0;
      }
      for (;j<lim;j++) rk += (scv[j]>v||(scv[j]==v&&sci[j]<idx))?1:0;
    }
  }
  if (act && rk<OUTC){
    int b=idx>>12, r=(idx>>6)&63, cc=idx&63;
    int tpi=sel_t[b*KK+r], spi=sel_s[b*KK+cc];
    float tx=0,ty=0,tz=0,sx=0,sy=0,sz=0;
    if (tpi<NPTS){ tx=tpts[tpi*3]; ty=tpts[tpi*3+1]; tz=tpts[tpi*3+2]; }
    if (spi<NPTS){ sx=spts[spi*3]; sy=spts[spi*3+1]; sz=spts[spi*3+2]; }
    tp[rk*3+0]=tx; tp[rk*3+1]=ty; tp[rk*3+2]=tz;
    sp[rk*3+0]=sx; sp[rk*3+1]=sy; sp[rk*3+2]=sz;
    cs[rk]=v;
  }
}

// ---------- patch assembly / OT / fine ----------
__global__ __launch_bounds__(256) void sel_feat_kernel(
    const int* __restrict__ ci_t, const int* __restrict__ knn_t, const float* __restrict__ ptf_t,
    const int* __restrict__ ci_s, const int* __restrict__ knn_s, const float* __restrict__ ptf_s,
    const float* __restrict__ W, const float* __restrict__ bias,
    float* __restrict__ out_t, float* __restrict__ out_s,
    int* __restrict__ sel_tO, int* __restrict__ sel_sO){
  __shared__ float Xs[64][64];   // [k][r]
  __shared__ float Ws[64][64];   // [k][o]
  __shared__ float pvf[64];
  int which=blockIdx.x>=1024;
  const int* cib=which? ci_s:ci_t;
  const int* knn=which? knn_s:knn_t;
  const float* ptf=which? ptf_s:ptf_t;
  float* out=which? out_s:out_t;
  int* sel=which? sel_sO:sel_tO;
  int blk=which? blockIdx.x-1024 : blockIdx.x;
  int bj=blk>>2, bo=blk&3;
  int t=threadIdx.x, r=t&63, kq=t>>6, tx=t&15, ty=t>>4;
  int p=knn[cib[bj]*KK+r];
  if (kq==0){
    pvf[r]=(p!=NPTS)?1.f:0.f;
    if (bo==0) sel[bj*KK+r]=p;
  }
  const float* xr=ptf+(size_t)p*DPT+kq*16;
  #pragma unroll
  for (int j4=0;j4<4;j4++){
    float4 v=(p==NPTS)? make_float4(0.f,0.f,0.f,0.f) : *(const float4*)(xr+4*j4);
    Xs[kq*16+4*j4+0][r]=v.x; Xs[kq*16+4*j4+1][r]=v.y;
    Xs[kq*16+4*j4+2][r]=v.z; Xs[kq*16+4*j4+3][r]=v.w;
  }
  const float* wr=W+(size_t)(bo*64+r)*DPT+kq*16;
  #pragma unroll
  for (int j4=0;j4<4;j4++){
    float4 w=*(const float4*)(wr+4*j4);
    Ws[kq*16+4*j4+0][r]=w.x; Ws[kq*16+4*j4+1][r]=w.y;
    Ws[kq*16+4*j4+2][r]=w.z; Ws[kq*16+4*j4+3][r]=w.w;
  }
  __syncthreads();
  float acc[4][4]={};
  #pragma unroll
  for (int kk=0;kk<64;kk++){
    float4 a4=*(const float4*)(&Xs[kk][4*ty]);
    float4 w4=*(const float4*)(&Ws[kk][4*tx]);
    float av[4]={a4.x,a4.y,a4.z,a4.w};
    float wv[4]={w4.x,w4.y,w4.z,w4.w};
    #pragma unroll
    for (int i=0;i<4;i++)
      #pragma unroll
      for (int j=0;j<4;j++) acc[i][j]=fmaf(av[i],wv[j],acc[i][j]);
  }
  #pragma unroll
  for (int i=0;i<4;i++){
    int rr=4*ty+i;
    #pragma unroll
    for (int j=0;j<4;j++){
      int oo=4*tx+j;
      float v=acc[i][j]+bias[bo*64+oo];
      out[(size_t)(bj*64+rr)*DN + bo*64+oo]= (pvf[rr]>0.f)? v : 0.0f;
    }
  }
}

// OT input P (65x65) per batch as tiled GEMM + dustbin/mask epilogue
__global__ __launch_bounds__(256) void pbuild_kernel(
    const float* __restrict__ ft, const float* __restrict__ fs,
    const int* __restrict__ sel_t, const int* __restrict__ sel_s,
    const float* __restrict__ alpha_p, float* __restrict__ P){
  __shared__ float tas[64][64];
  __shared__ float sbs[64][64];
  __shared__ float tmv[64], smv[64];
  int b=blockIdx.x, t=threadIdx.x;
  int r=t&63, kq=t>>6, tx=t&15, ty=t>>4;
  if (kq==0) tmv[r]=(sel_t[b*KK+r]!=NPTS)?1.f:0.f;
  if (kq==1) smv[r]=(sel_s[b*KK+r]!=NPTS)?1.f:0.f;
  float acc[4][4]={};
  const float* tb=ft+(size_t)b*KK*DN;
  const float* sb=fs+(size_t)b*KK*DN;
  for (int kc=0;kc<DN;kc+=64){
    __syncthreads();
    const float* tr_=tb+(size_t)r*DN+kc+kq*16;
    const float* sr_=sb+(size_t)r*DN+kc+kq*16;
    #pragma unroll
    for (int j4=0;j4<4;j4++){
      float4 v=*(const float4*)(tr_+4*j4);
      tas[kq*16+4*j4+0][r]=v.x; tas[kq*16+4*j4+1][r]=v.y;
      tas[kq*16+4*j4+2][r]=v.z; tas[kq*16+4*j4+3][r]=v.w;
      float4 w=*(const float4*)(sr_+4*j4);
      sbs[kq*16+4*j4+0][r]=w.x; sbs[kq*16+4*j4+1][r]=w.y;
      sbs[kq*16+4*j4+2][r]=w.z; sbs[kq*16+4*j4+3][r]=w.w;
    }
    __syncthreads();
    #pragma unroll
    for (int kk=0;kk<64;kk++){
      float4 a4=*(const float4*)(&tas[kk][4*ty]);
      float4 b4=*(const float4*)(&sbs[kk][4*tx]);
      float av[4]={a4.x,a4.y,a4.z,a4.w};
      float bv[4]={b4.x,b4.y,b4.z,b4.w};
      #pragma unroll
      for (int i=0;i<4;i++)
        #pragma unroll
        for (int j=0;j<4;j++) acc[i][j]=fmaf(av[i],bv[j],acc[i][j]);
    }
  }
  __syncthreads();
  float alpha=alpha_p[0];
  float* Pb=P+(size_t)b*65*65;
  #pragma unroll
  for (int i=0;i<4;i++){
    int rr=4*ty+i;
    bool tok=tmv[rr]>0.f;
    #pragma unroll
    for (int j=0;j<4;j++){
      int cc=4*tx+j;
      bool invm=(!tok)||(smv[cc]<=0.f);
      Pb[rr*65+cc]= invm ? NEGV : acc[i][j]*0.0625f;
    }
  }
  if (t<64){
    Pb[64*65+t]=(smv[t]<=0.f)? NEGV : alpha;
    Pb[t*65+64]=(tmv[t]<=0.f)? NEGV : alpha;
  }
  if (t==64) Pb[64*65+64]=alpha;
}

// Sinkhorn linear-domain, 4 waves per batch, column-split, 2 barriers/iter.
// Chunk broadcasts via v_readlane (SALU, wave-uniform index) — no LDS, no
// bpermute. Bitwise-exact early exit handles fixed points AND period-2 limit
// cycles (break only at the parity that reproduces state(OTI-1) exactly).
__global__ __launch_bounds__(256,1) void ot_kernel(
    float* __restrict__ P, const int* __restrict__ sel_t, const int* __restrict__ sel_s){
  __shared__ float Ps[4225];
  __shared__ __align__(16) float partU[4][72], partV[4][72];
  __shared__ __align__(16) float pu64[4], pusv[4], pv64[4], pvsv[4];
  __shared__ float ufs[65], vfs[65];
  int b=blockIdx.x, t=threadIdx.x, w=t>>6, l=t&63;
  float* Pg=P+(size_t)b*4225;
  for (int e=t;e<4225;e+=256) Ps[e]=Pg[e];
  bool rv=(sel_t[b*KK+l]!=NPTS);
  bool cv=(sel_s[b*KK+l]!=NPTS);
  int nr=(int)__popcll(__ballot(rv));
  int nc=(int)__popcll(__ballot(cv));
  float inv=1.0f/(float)(nr+nc);
  float nrm=-logf((float)(nr+nc));
  float mu_l=inv, nu_l=inv, mu64=(float)nc*inv, nu64=(float)nr*inv;
  bool anyInvR=(nr<KK), anyInvC=(nc<KK);
  __syncthreads();
  const int c0=16*w;
  float aQ[16], bQ[16], r64Q[16], c64Q[16];
  #pragma unroll
  for (int j=0;j<16;j++){
    aQ[j]  =expf(Ps[l*65+c0+j]);
    bQ[j]  =expf(Ps[(c0+j)*65+l]);
    r64Q[j]=expf(Ps[64*65+c0+j]);
    c64Q[j]=expf(Ps[(c0+j)*65+64]);
  }
  float a64=expf(Ps[l*65+64]);
  float b64v=expf(Ps[64*65+l]);
  float k6464=expf(Ps[4224]);
  float U_l, V_l=1.0f, U64, V64=1.0f;
  unsigned p1U=0,p1V=0,p1a=0,p1b=0, p2U=0,p2V=0,p2a=0,p2b=0;

  for (int it=0; it<OTI; ++it){
    // ---- u-pass: V chunk via readlane (SALU broadcast) ----
    float p0=0,p1f=0,p2f=0,p3=0, d0=0,d1=0,d2=0,d3=0, z0=0,z1=0,z2=0,z3=0;
    #pragma unroll
    for (int j4=0;j4<4;j4++){
      float v0=__int_as_float(__builtin_amdgcn_readlane(__float_as_int(V_l), c0+4*j4+0));
      float v1=__int_as_float(__builtin_amdgcn_readlane(__float_as_int(V_l), c0+4*j4+1));
      float v2=__int_as_float(__builtin_amdgcn_readlane(__float_as_int(V_l), c0+4*j4+2));
      float v3=__int_as_float(__builtin_amdgcn_readlane(__float_as_int(V_l), c0+4*j4+3));
      p0=fmaf(aQ[4*j4+0],v0,p0); p1f=fmaf(aQ[4*j4+1],v1,p1f);
      p2f=fmaf(aQ[4*j4+2],v2,p2f); p3=fmaf(aQ[4*j4+3],v3,p3);
      d0=fmaf(r64Q[4*j4+0],v0,d0); d1=fmaf(r64Q[4*j4+1],v1,d1);
      d2=fmaf(r64Q[4*j4+2],v2,d2); d3=fmaf(r64Q[4*j4+3],v3,d3);
      z0+=v0; z1+=v1; z2+=v2; z3+=v3;
    }
    partU[w][l]=(p0+p1f)+(p2f+p3);
    if (l==0){ pu64[w]=(d0+d1)+(d2+d3); pusv[w]=(z0+z1)+(z2+z3); }
    __syncthreads();
    {
      float s=partU[0][l]+partU[1][l]+partU[2][l]+partU[3][l];
      float4 d4=*(const float4*)pu64;
      float srow=s+a64*V64;
      float s64=(d4.x+d4.y)+(d4.z+d4.w)+k6464*V64;
      U64=mu64/s64;
      if (anyInvR){
        float4 z4=*(const float4*)pusv;
        float sv=(z4.x+z4.y)+(z4.z+z4.w)+V64;
        U_l = rv ? (mu_l/srow) : (1.0f/sv);
      } else U_l = mu_l/srow;
    }
    // ---- v-pass: U chunk via readlane ----
    float q0=0,q1=0,q2=0,q3=0, e0=0,e1=0,e2=0,e3=0, y0=0,y1=0,y2=0,y3=0;
    #pragma unroll
    for (int j4=0;j4<4;j4++){
      float u0=__int_as_float(__builtin_amdgcn_readlane(__float_as_int(U_l), c0+4*j4+0));
      float u1=__int_as_float(__builtin_amdgcn_readlane(__float_as_int(U_l), c0+4*j4+1));
      float u2=__int_as_float(__builtin_amdgcn_readlane(__float_as_int(U_l), c0+4*j4+2));
      float u3=__int_as_float(__builtin_amdgcn_readlane(__float_as_int(U_l), c0+4*j4+3));
      q0=fmaf(bQ[4*j4+0],u0,q0); q1=fmaf(bQ[4*j4+1],u1,q1);
      q2=fmaf(bQ[4*j4+2],u2,q2); q3=fmaf(bQ[4*j4+3],u3,q3);
      e0=fmaf(c64Q[4*j4+0],u0,e0); e1=fmaf(c64Q[4*j4+1],u1,e1);
      e2=fmaf(c64Q[4*j4+2],u2,e2); e3=fmaf(c64Q[4*j4+3],u3,e3);
      y0+=u0; y1+=u1; y2+=u2; y3+=u3;
    }
    partV[w][l]=(q0+q1)+(q2+q3);
    if (l==0){ pv64[w]=(e0+e1)+(e2+e3); pvsv[w]=(y0+y1)+(y2+y3); }
    __syncthreads();
    {
      float sc=partV[0][l]+partV[1][l]+partV[2][l]+partV[3][l];
      float4 e4=*(const float4*)pv64;
      float scol=sc+b64v*U64;
      float s64v=(e4.x+e4.y)+(e4.z+e4.w)+k6464*U64;
      V64=nu64/s64v;
      if (anyInvC){
        float4 y4=*(const float4*)pvsv;
        float su=(y4.x+y4.y)+(y4.z+y4.w)+U64;
        V_l = cv ? (nu_l/scol) : (1.0f/su);
      } else V_l = nu_l/scol;
    }
    // ---- bitwise-exact convergence (fixed point or period-2) ----
    unsigned cU=__float_as_uint(U_l), cVb=__float_as_uint(V_l);
    unsigned ca=__float_as_uint(U64), cb2=__float_as_uint(V64);
    bool e1s=(it>=1)&&(cU==p1U)&&(cVb==p1V)&&(ca==p1a)&&(cb2==p1b);
    bool e2s=(it>=2)&&(cU==p2U)&&(cVb==p2V)&&(ca==p2a)&&(cb2==p2b);
    unsigned long long b1=__ballot(e1s);
    unsigned long long b2=__ballot(e2s);
    p2U=p1U; p2V=p1V; p2a=p1a; p2b=p1b;
    p1U=cU; p1V=cVb; p1a=ca; p1b=cb2;
    if (b1==~0ULL) break;
    if (b2==~0ULL && (((OTI-1-it)&1)==0)) break;
  }
  if (w==0){
    ufs[l]=logf(U_l); vfs[l]=logf(V_l);
    if (l==0){ ufs[64]=logf(U64); vfs[64]=logf(V64); }
  }
  __syncthreads();
  for (int e=t;e<4225;e+=256){
    int r=e/65, c=e-65*r;
    Pg[e]=Ps[e]+ufs[r]+vfs[c]-nrm;
  }
}

// fine prep fused with L1 histogram of the masked scores -> partial1
__global__ __launch_bounds__(256) void fineprep_kernel(
    const float* __restrict__ P, const int* __restrict__ sel_t, const int* __restrict__ sel_s,
    float* __restrict__ smout, unsigned* __restrict__ partial1){
  __shared__ float s[KK*KK];
  __shared__ unsigned long long rowm[KK], colm[KK];
  __shared__ int tmk[KK], smk[KK];
  __shared__ unsigned lh[256];
  int b=blockIdx.x, t=threadIdx.x;
  lh[t]=0u;
  const float* Pb=P+(size_t)b*65*65;
  for (int e=t;e<KK*KK;e+=256){
    int r=e>>6, c=e&63;
    s[e]=expf(Pb[r*65+c]);
  }
  if (t<KK){ tmk[t]=(sel_t[b*KK+t]!=NPTS); smk[t]=(sel_s[b*KK+t]!=NPTS); }
  __syncthreads();
  if (t<KK){
    float v1=-1,v2=-1,v3=-1; int i1=0,i2=0,i3=0;
    const float* row=s+t*KK;
    for (int c=0;c<KK;c++){ float v=row[c];
      if (v>v1){v3=v2;i3=i2;v2=v1;i2=i1;v1=v;i1=c;}
      else if (v>v2){v3=v2;i3=i2;v2=v;i2=c;}
      else if (v>v3){v3=v;i3=c;}
    }
    rowm[t]=(1ULL<<i1)|(1ULL<<i2)|(1ULL<<i3);
  } else if (t<2*KK){
    int c=t-KK;
    float v1=-1,v2=-1,v3=-1; int i1=0,i2=0,i3=0;
    for (int r=0;r<KK;r++){ float v=s[r*KK+c];
      if (v>v1){v3=v2;i3=i2;v2=v1;i2=i1;v1=v;i1=r;}
      else if (v>v2){v3=v2;i3=i2;v2=v;i2=r;}
      else if (v>v3){v3=v;i3=r;}
    }
    colm[c]=(1ULL<<i1)|(1ULL<<i2)|(1ULL<<i3);
  }
  __syncthreads();
  for (int e=t;e<KK*KK;e+=256){
    int r=e>>6, c=e&63;
    float v=s[e];
    bool keep = ((rowm[r]>>c)&1ULL) && ((colm[c]>>r)&1ULL) && (v>0.05f) && tmk[r] && smk[c];
    float o= keep? v : 0.0f;
    smout[(size_t)b*KK*KK+e]=o;
    if (o>0.0f) atomicAdd(&lh[__float_as_uint(o)>>24],1u);
  }
  __syncthreads();
  partial1[b*256+t]=lh[t];
}

extern "C" void kernel_launch(void* const* d_in, const int* in_sizes, int n_in,
                              void* d_out, int out_size, void* d_ws, size_t ws_size,
                              hipStream_t stream){
  const float* src_pts=(const float*)d_in[0];
  const float* tgt_pts=(const float*)d_in[1];
  const float* src_pf =(const float*)d_in[2];
  const float* tgt_pf =(const float*)d_in[3];
  const float* src_nf =(const float*)d_in[4];
  const float* tgt_nf =(const float*)d_in[5];
  const float* src_nx =(const float*)d_in[6];
  const float* tgt_nx =(const float*)d_in[7];
  const float* cw=(const float*)d_in[8];
  const float* cb=(const float*)d_in[9];
  const float* fw=(const float*)d_in[10];
  const float* fb=(const float*)d_in[11];
  const float* alpha=(const float*)d_in[12];

  char* ws=(char*)d_ws;
  size_t off=0;
  auto A=[&](size_t bytes)->char*{
    char* p=ws+off; off+=(bytes+255)&~(size_t)255; return p; };

  float* tf    =(float*)A((size_t)MN*DN*4);
  float* sfb   =(float*)A((size_t)MN*DN*4);
  float* tt    =(float*)A(MN*4);
  float* ssv   =(float*)A(MN*4);
  int*   p2n_s =(int*)A((size_t)NPTS*4);
  int*   p2n_t =(int*)A((size_t)NPTS*4);
  int*   cnt_s =(int*)A(MN*4);
  int*   cnt_t =(int*)A(MN*4);
  int*   list_s=(int*)A((size_t)MN*CAPL*4);
  int*   list_t=(int*)A((size_t)MN*CAPL*4);
  int*   knn_s =(int*)A((size_t)MN*KK*4);
  int*   knn_t =(int*)A((size_t)MN*KK*4);
  float* Smat  =(float*)A((size_t)MN*MN*4);
  unsigned* partial1=(unsigned*)A((size_t)HBLK*256*4);
  unsigned* partial2=(unsigned*)A((size_t)HBLK*256*4);
  unsigned* partial3=(unsigned*)A((size_t)HBLK*256*4);
  unsigned* meta=(unsigned*)A(256);
  float* cand_v=(float*)A((size_t)CCAP*4);
  int*   cand_i=(int*)A((size_t)CCAP*4);
  int*   ci_t  =(int*)A(BCORR*4);
  int*   ci_s  =(int*)A(BCORR*4);
  int*   sel_t =(int*)A((size_t)BCORR*KK*4);
  int*   sel_s =(int*)A((size_t)BCORR*KK*4);
  float* feat_t=(float*)A((size_t)BCORR*KK*DN*4);
  float* feat_s=(float*)A((size_t)BCORR*KK*DN*4);
  float* smf   =(float*)A((size_t)BCORR*KK*KK*4);
  float* rs    =(float*)A(MN*4);
  float* csum  =(float*)A(MN*4);

  float* out=(float*)d_out;
  float* msout=out;
  float* tpout=out+(size_t)BCORR*65*65;
  float* spout=tpout+(size_t)OUTC*3;
  float* csout=spout+(size_t)OUTC*3;

  const int PB=(NPTS+255)/256;

  zero_all_kernel<<<28,256,0,stream>>>(cnt_s,cnt_t,ci_t,ci_s,tpout);
  node_feat_kernel<<<2*MN,256,0,stream>>>(tgt_nf,src_nf,cw,cb,tf,sfb,tt,ssv);
  p2n_kernel<<<2*PB,256,0,stream>>>(src_pts,src_nx,p2n_s,tgt_pts,tgt_nx,p2n_t,PB);
  scatter_kernel<<<2*PB,256,0,stream>>>(p2n_s,cnt_s,list_s,p2n_t,cnt_t,list_t,PB);
  knn_kernel<<<2*MN,256,0,stream>>>(src_pts,src_nx,cnt_s,list_s,knn_s,
                                    tgt_pts,tgt_nx,cnt_t,list_t,knn_t);

  coarse_score_kernel<<<256,256,0,stream>>>(tf,sfb,tt,ssv,cnt_t,cnt_s,Smat);
  sums_kernel<<<MN+64,256,0,stream>>>(Smat,rs,csum);
  dualnorm_hist_kernel<<<HBLK,256,0,stream>>>(Smat,rs,csum,partial1);

  hist_fine_kernel<<<HBLK,256,0,stream>>>(Smat,MN*MN,BCORR,partial1,partial2);
  hist_fine2_kernel<<<HBLK,256,0,stream>>>(Smat,MN*MN,BCORR,partial1,partial2,partial3,meta+1);
  compact_kernel<<<256,256,0,stream>>>(Smat,MN*MN,BCORR,partial1,partial2,partial3,
                                       cand_v,cand_i,meta+1);
  rank_coarse_kernel<<<CCAP/256,256,0,stream>>>(cand_v,cand_i,meta,ci_t,ci_s);

  sel_feat_kernel<<<2048,256,0,stream>>>(ci_t,knn_t,tgt_pf, ci_s,knn_s,src_pf,
                                         fw,fb,feat_t,feat_s,sel_t,sel_s);

  pbuild_kernel<<<BCORR,256,0,stream>>>(feat_t,feat_s,sel_t,sel_s,alpha,msout);
  ot_kernel<<<BCORR,256,0,stream>>>(msout,sel_t,sel_s);

  fineprep_kernel<<<BCORR,256,0,stream>>>(msout,sel_t,sel_s,smf,partial1);
  hist_fine_kernel<<<HBLK,256,0,stream>>>(smf,BCORR*KK*KK,OUTC,partial1,partial2);
  hist_fine2_kernel<<<HBLK,256,0,stream>>>(smf,BCORR*KK*KK,OUTC,partial1,partial2,partial3,meta+1);
  compact_kernel<<<256,256,0,stream>>>(smf,BCORR*KK*KK,OUTC,partial1,partial2,partial3,
                                       cand_v,cand_i,meta+1);
  rank_fine_kernel<<<CCAP/256,256,0,stream>>>(cand_v,cand_i,meta,sel_t,sel_s,
                                              tgt_pts,src_pts,tpout,spout,csout);
}